// Round 1
// baseline (468.175 us; speedup 1.0000x reference)
//
#include <hip/hip_runtime.h>

#define SEQ 2048
#define DIM 512
#define NBATCH 32
#define NH 16
#define HDIM 32
#define NCLS 2

typedef __attribute__((ext_vector_type(8))) short short8;
typedef __attribute__((ext_vector_type(8))) unsigned short ushort8;
typedef __attribute__((ext_vector_type(4))) float f32x4;

__device__ __forceinline__ float b2f(unsigned short u){
  union { unsigned int i; float f; } v; v.i = ((unsigned int)u) << 16; return v.f;
}
__device__ __forceinline__ unsigned short f2b(float f){
  unsigned int x = __float_as_uint(f);
  unsigned int r = (x + 0x7fffu + ((x >> 16) & 1u)) >> 16;
  return (unsigned short)r;
}
__device__ __forceinline__ void gload16(const void* g, void* l){
  __builtin_amdgcn_global_load_lds((const __attribute__((address_space(1))) void*)g,
                                   (__attribute__((address_space(3))) void*)l, 16, 0, 0);
}

// ---------------- K0: combined mexican-hat kernel ksum[19][512] ----------------
__global__ __launch_bounds__(256) void wavelet_kernel(const float* __restrict__ w1,
    const float* __restrict__ w2, const float* __restrict__ w3, float* __restrict__ ksum){
  int d = blockIdx.x * 256 + threadIdx.x;           // 0..511
  const float C = 0.86732501f;                      // 2/(3^0.5 * pi^0.25)
  float acc[19];
  #pragma unroll
  for (int i = 0; i < 19; ++i) acc[i] = 0.f;
  const float* waves[3] = { w1, w2, w3 };
  for (int t = 0; t < 3; ++t){
    float scale = waves[t][d];
    float shift = waves[t][DIM + d];
    float inv = 1.f / scale;
    float amp = C * rsqrtf(fabsf(scale));
    #pragma unroll
    for (int i = 0; i < 19; ++i){
      float u = ((float)(i - 9) - shift) * inv;
      acc[i] += amp * (1.f - u * u) * expf(-0.5f * u * u);
    }
  }
  #pragma unroll
  for (int i = 0; i < 19; ++i) ksum[i * DIM + d] = acc[i];
}

// ---------------- K0b: q = cls_token @ Wq   (batch-invariant) ----------------
__global__ __launch_bounds__(256) void q_kernel(const float* __restrict__ cls,
    const float* __restrict__ Wq, float* __restrict__ qws){
  int idx = blockIdx.x * 256 + threadIdx.x;         // 0..1023
  int n = idx >> 9, c = idx & 511;
  float s = 0.f;
  for (int kd = 0; kd < DIM; ++kd)
    s = fmaf(cls[n * DIM + kd], Wq[(size_t)kd * DIM + c], s);
  qws[n * DIM + c] = s;
}

// ---------------- K0c: transpose f32 [R][C] -> bf16 [C][R] ----------------
__global__ __launch_bounds__(256) void transpose_kernel(const float* __restrict__ in,
    unsigned short* __restrict__ out, int R, int C){
  __shared__ unsigned short t[64][65];
  int c0 = blockIdx.x * 64, r0 = blockIdx.y * 64;
  #pragma unroll
  for (int i = 0; i < 16; ++i){
    int idx = i * 256 + threadIdx.x;
    int r = idx >> 6, c = idx & 63;
    t[c][r] = f2b(in[(size_t)(r0 + r) * C + c0 + c]);
  }
  __syncthreads();
  #pragma unroll
  for (int i = 0; i < 16; ++i){
    int idx = i * 256 + threadIdx.x;
    int r = idx >> 6, c = idx & 63;
    out[(size_t)(c0 + r) * R + r0 + c] = t[r][c];
  }
}

// ---------------- K1: depthwise 19-tap conv along s -> pos bf16 ----------------
__global__ __launch_bounds__(256) void conv_kernel(const float* __restrict__ X,
    const float* __restrict__ ksum, unsigned short* __restrict__ Pos){
  int blk = blockIdx.x;
  int b = blk >> 6;                 // 64 s-chunks of 32 per batch
  int s0 = (blk & 63) * 32;
  int d0 = threadIdx.x * 2;
  float kx[19], ky[19];
  #pragma unroll
  for (int i = 0; i < 19; ++i){
    float2 kv = *(const float2*)&ksum[i * DIM + d0];
    kx[i] = kv.x; ky[i] = kv.y;
  }
  const float* xb = X + ((size_t)b * SEQ) * DIM + d0;
  for (int g = 0; g < 8; ++g){
    int sb = s0 + g * 4;
    float ax[4] = {0.f,0.f,0.f,0.f}, ay[4] = {0.f,0.f,0.f,0.f};
    #pragma unroll
    for (int i = 0; i < 22; ++i){
      int s = sb + i - 9;
      float xv = 0.f, yv = 0.f;
      if (s >= 0 && s < SEQ){
        float2 t = *(const float2*)&xb[(size_t)s * DIM];
        xv = t.x; yv = t.y;
      }
      #pragma unroll
      for (int o = 0; o < 4; ++o){
        int tap = i - o;
        if (tap >= 0 && tap < 19){
          ax[o] = fmaf(xv, kx[tap], ax[o]);
          ay[o] = fmaf(yv, ky[tap], ay[o]);
        }
      }
    }
    #pragma unroll
    for (int o = 0; o < 4; ++o){
      unsigned int packed = (unsigned int)f2b(ax[o]) | ((unsigned int)f2b(ay[o]) << 16);
      *(unsigned int*)&Pos[((size_t)(b * SEQ + sb + o)) * DIM + d0] = packed;
    }
  }
}

// ---------------- GEMM: C = A[M,512] @ Bt[N,512]^T, out bf16 (optional residual) ----------------
template<int N_, bool RES>
__global__ __launch_bounds__(256) void gemm_kernel(const unsigned short* __restrict__ A,
    const unsigned short* __restrict__ Bt, const float* __restrict__ Xres,
    const float* __restrict__ bias, unsigned short* __restrict__ Out){
  __shared__ unsigned short lA[128 * 64];
  __shared__ unsigned short lB[128 * 64];
  const int K = 512;
  int tid = threadIdx.x;
  int w = tid >> 6, lane = tid & 63;
  int wm = w >> 1, wn = w & 1;
  size_t mBase = (size_t)blockIdx.y * 128;
  int nBase = blockIdx.x * 128;
  f32x4 acc[4][4] = {};
  int e = lane * 8;
  for (int k0 = 0; k0 < K; k0 += 64){
    __syncthreads();
    #pragma unroll
    for (int c = 0; c < 4; ++c){
      int chunk = w * 4 + c;
      int ee = chunk * 512 + e;
      int row = ee >> 6, col = ee & 63;
      gload16(A + (mBase + row) * K + k0 + col, &lA[chunk * 512]);
    }
    #pragma unroll
    for (int c = 0; c < 4; ++c){
      int chunk = w * 4 + c;
      int ee = chunk * 512 + e;
      int row = ee >> 6, col = ee & 63;
      gload16(Bt + (size_t)(nBase + row) * K + k0 + col, &lB[chunk * 512]);
    }
    __syncthreads();
    #pragma unroll
    for (int kk = 0; kk < 2; ++kk){
      short8 af[4], bfr[4];
      #pragma unroll
      for (int m = 0; m < 4; ++m)
        af[m] = *(const short8*)&lA[(wm * 64 + m * 16 + (lane & 15)) * 64 + kk * 32 + (lane >> 4) * 8];
      #pragma unroll
      for (int n = 0; n < 4; ++n)
        bfr[n] = *(const short8*)&lB[(wn * 64 + n * 16 + (lane & 15)) * 64 + kk * 32 + (lane >> 4) * 8];
      #pragma unroll
      for (int m = 0; m < 4; ++m){
        #pragma unroll
        for (int n = 0; n < 4; ++n)
          acc[m][n] = __builtin_amdgcn_mfma_f32_16x16x32_bf16(af[m], bfr[n], acc[m][n], 0, 0, 0);
      }
    }
  }
  int r0 = (lane >> 4) * 4;
  int cl = lane & 15;
  #pragma unroll
  for (int m = 0; m < 4; ++m){
    #pragma unroll
    for (int n = 0; n < 4; ++n){
      int col = nBase + wn * 64 + n * 16 + cl;
      #pragma unroll
      for (int j = 0; j < 4; ++j){
        size_t row = mBase + wm * 64 + m * 16 + r0 + j;
        float v = acc[m][n][j];
        if (RES) v += Xres[row * N_ + col] + bias[col];
        Out[row * N_ + col] = f2b(v);
      }
    }
  }
}

// ---------------- LN: xn = layernorm(y) * g + b, bf16 in / bf16 out ----------------
__global__ __launch_bounds__(256) void ln_kernel(const unsigned short* __restrict__ Y,
    const float* __restrict__ g, const float* __restrict__ bta, unsigned short* __restrict__ Xn){
  int row = blockIdx.x * 4 + (threadIdx.x >> 6);
  int lane = threadIdx.x & 63;
  int c = lane * 8;
  ushort8 yv = *(const ushort8*)(Y + (size_t)row * DIM + c);
  float v[8];
  float sm = 0.f, sq = 0.f;
  #pragma unroll
  for (int j = 0; j < 8; ++j){
    v[j] = b2f((unsigned short)yv[j]);
    sm += v[j]; sq += v[j] * v[j];
  }
  #pragma unroll
  for (int off = 32; off; off >>= 1){
    sm += __shfl_xor(sm, off, 64);
    sq += __shfl_xor(sq, off, 64);
  }
  float mean = sm * (1.f / 512.f);
  float var = sq * (1.f / 512.f) - mean * mean;
  float rstd = rsqrtf(var + 1e-5f);
  ushort8 o;
  #pragma unroll
  for (int j = 0; j < 8; ++j)
    o[j] = f2b((v[j] - mean) * rstd * g[c + j] + bta[c + j]);
  *(ushort8*)(Xn + (size_t)row * DIM + c) = o;
}

// ---------------- Attention: per (b,h), sigmoid scores + o accumulation ----------------
__global__ __launch_bounds__(256) void attn_kernel(const unsigned short* __restrict__ KV,
    const float* __restrict__ qws, float* __restrict__ aout, float* __restrict__ o_ws){
  __shared__ float qs[2][32];
  __shared__ unsigned short vls[256 * 32];
  __shared__ float als[256 * 2];
  __shared__ float red[256];
  int tid = threadIdx.x;
  int bh = blockIdx.x;
  int b = bh >> 4, h = bh & 15;
  if (tid < 64) qs[tid >> 5][tid & 31] = qws[(tid >> 5) * DIM + h * HDIM + (tid & 31)];
  __syncthreads();
  const float SCALE = 0.17677669529663687f;   // 1/sqrt(32)
  const float LOGS  = 7.6246189861593985f;    // ln(2048)
  int sub = tid >> 6, nn = (tid >> 5) & 1, hd = tid & 31;
  float oacc = 0.f;
  const unsigned short* kvb = KV + ((size_t)b * SEQ) * 1024 + h * HDIM;
  float* ab = aout + ((size_t)(b * NH + h) * NCLS) * SEQ;
  for (int ch = 0; ch < 8; ++ch){
    int s = ch * 256 + tid;
    const unsigned short* kp = kvb + (size_t)s * 1024;
    float sc0 = 0.f, sc1 = 0.f;
    #pragma unroll
    for (int g8 = 0; g8 < 4; ++g8){
      ushort8 kk = *(const ushort8*)(kp + g8 * 8);
      #pragma unroll
      for (int j = 0; j < 8; ++j){
        float kf = b2f((unsigned short)kk[j]);
        sc0 = fmaf(qs[0][g8 * 8 + j], kf, sc0);
        sc1 = fmaf(qs[1][g8 * 8 + j], kf, sc1);
      }
    }
    sc0 = fmaf(sc0, SCALE, -LOGS);
    sc1 = fmaf(sc1, SCALE, -LOGS);
    float a0 = 1.f / (1.f + expf(-sc0));
    float a1 = 1.f / (1.f + expf(-sc1));
    ab[s] = a0;
    ab[SEQ + s] = a1;
    als[tid * 2 + 0] = a0;
    als[tid * 2 + 1] = a1;
    *(ushort8*)&vls[tid * 32 + 0]  = *(const ushort8*)(kp + 512);
    *(ushort8*)&vls[tid * 32 + 8]  = *(const ushort8*)(kp + 520);
    *(ushort8*)&vls[tid * 32 + 16] = *(const ushort8*)(kp + 528);
    *(ushort8*)&vls[tid * 32 + 24] = *(const ushort8*)(kp + 536);
    __syncthreads();
    #pragma unroll 8
    for (int i = 0; i < 64; ++i){
      int ss = sub * 64 + i;
      oacc = fmaf(als[ss * 2 + nn], b2f(vls[ss * 32 + hd]), oacc);
    }
    __syncthreads();
  }
  red[tid] = oacc;
  __syncthreads();
  if (tid < 64){
    float o = red[tid] + red[tid + 64] + red[tid + 128] + red[tid + 192];
    o_ws[((size_t)(b * NCLS + (tid >> 5)) * NH + h) * HDIM + (tid & 31)] = o;
  }
}

// ---------------- Head: oproj -> LN -> Wc1 relu -> Wc2 -> logits, one block per row ----------------
__global__ __launch_bounds__(256) void head_kernel(const float* __restrict__ o_ws,
    const float* __restrict__ Wproj, const float* __restrict__ bproj,
    const float* __restrict__ g2, const float* __restrict__ b2v,
    const float* __restrict__ Wc1, const float* __restrict__ bc1,
    const float* __restrict__ Wc2, const float* __restrict__ bc2,
    float* __restrict__ logits){
  __shared__ float orow[512];
  __shared__ float hrow[512];
  __shared__ float wred[8];
  __shared__ float wred2[4];
  int tid = threadIdx.x;
  int row = blockIdx.x;
  orow[tid] = o_ws[(size_t)row * DIM + tid];
  orow[tid + 256] = o_ws[(size_t)row * DIM + tid + 256];
  __syncthreads();
  int c0 = tid * 2;
  float a0 = 0.f, a1 = 0.f;
  for (int d = 0; d < DIM; ++d){
    float ov = orow[d];
    const float* wr = Wproj + (size_t)d * DIM + c0;
    a0 = fmaf(ov, wr[0], a0);
    a1 = fmaf(ov, wr[1], a1);
  }
  a0 += bproj[c0]; a1 += bproj[c0 + 1];
  float sm = a0 + a1, sq = a0 * a0 + a1 * a1;
  #pragma unroll
  for (int off = 32; off; off >>= 1){
    sm += __shfl_xor(sm, off, 64);
    sq += __shfl_xor(sq, off, 64);
  }
  int w = tid >> 6, lane = tid & 63;
  if (lane == 0){ wred[w * 2] = sm; wred[w * 2 + 1] = sq; }
  __syncthreads();
  sm = wred[0] + wred[2] + wred[4] + wred[6];
  sq = wred[1] + wred[3] + wred[5] + wred[7];
  float mean = sm * (1.f / 512.f);
  float var = sq * (1.f / 512.f) - mean * mean;
  float rstd = rsqrtf(var + 1e-5f);
  hrow[c0]     = (a0 - mean) * rstd * g2[c0]     + b2v[c0];
  hrow[c0 + 1] = (a1 - mean) * rstd * g2[c0 + 1] + b2v[c0 + 1];
  __syncthreads();
  float h0 = 0.f, h1 = 0.f;
  for (int d = 0; d < DIM; ++d){
    float lv = hrow[d];
    const float* wr = Wc1 + (size_t)d * DIM + c0;
    h0 = fmaf(lv, wr[0], h0);
    h1 = fmaf(lv, wr[1], h1);
  }
  h0 += bc1[c0]; h1 += bc1[c0 + 1];
  h0 = h0 > 0.f ? h0 : 0.f;
  h1 = h1 > 0.f ? h1 : 0.f;
  float p = h0 * Wc2[c0] + h1 * Wc2[c0 + 1];
  #pragma unroll
  for (int off = 32; off; off >>= 1) p += __shfl_xor(p, off, 64);
  if (lane == 0) wred2[w] = p;
  __syncthreads();
  if (tid == 0) logits[row] = wred2[0] + wred2[1] + wred2[2] + wred2[3] + bc2[0];
}

extern "C" void kernel_launch(void* const* d_in, const int* in_sizes, int n_in,
                              void* d_out, int out_size, void* d_ws, size_t ws_size,
                              hipStream_t stream) {
  const float* x     = (const float*)d_in[0];
  const float* wave1 = (const float*)d_in[1];
  const float* wave2 = (const float*)d_in[2];
  const float* wave3 = (const float*)d_in[3];
  const float* Wp1   = (const float*)d_in[4];
  const float* bp1   = (const float*)d_in[5];
  const float* cls   = (const float*)d_in[6];
  const float* ln1g  = (const float*)d_in[7];
  const float* ln1b  = (const float*)d_in[8];
  const float* Wq    = (const float*)d_in[9];
  const float* Wkv   = (const float*)d_in[10];
  const float* Wproj = (const float*)d_in[11];
  const float* bproj = (const float*)d_in[12];
  const float* ln2g  = (const float*)d_in[13];
  const float* ln2b  = (const float*)d_in[14];
  const float* Wc1   = (const float*)d_in[15];
  const float* bc1   = (const float*)d_in[16];
  const float* Wc2   = (const float*)d_in[17];
  const float* bc2   = (const float*)d_in[18];

  float* out = (float*)d_out;
  float* logits = out;            // [32,2]
  float* attn   = out + 64;       // [32,16,2,2048]

  unsigned char* ws = (unsigned char*)d_ws;
  // layout (bytes): needs ~196 MB of workspace
  float* ksum          = (float*)(ws);                          // 19*512*4
  float* qws           = (float*)(ws + 65536);                  // 2*512*4
  unsigned short* Wp1T = (unsigned short*)(ws + 131072);        // 512KB
  unsigned short* WkvT = (unsigned short*)(ws + (1ull << 20));  // 1MB
  float* o_ws          = (float*)(ws + (2ull << 20));           // 128KB
  unsigned short* pos  = (unsigned short*)(ws + (4ull << 20));  // 64MB  (reused as xn)
  unsigned short* yb   = (unsigned short*)(ws + (68ull << 20)); // 64MB  (reused as head of kv)
  unsigned short* xn   = pos;
  unsigned short* kv   = yb;                                    // 128MB total (68..196MB)

  wavelet_kernel<<<dim3(2), dim3(256), 0, stream>>>(wave1, wave2, wave3, ksum);
  q_kernel<<<dim3(4), dim3(256), 0, stream>>>(cls, Wq, qws);
  transpose_kernel<<<dim3(8, 8), dim3(256), 0, stream>>>(Wp1, Wp1T, 512, 512);
  transpose_kernel<<<dim3(16, 8), dim3(256), 0, stream>>>(Wkv, WkvT, 512, 1024);
  conv_kernel<<<dim3(NBATCH * 64), dim3(256), 0, stream>>>(x, ksum, pos);
  gemm_kernel<512, true><<<dim3(4, 512), dim3(256), 0, stream>>>(pos, Wp1T, x, bp1, yb);
  ln_kernel<<<dim3(16384), dim3(256), 0, stream>>>(yb, ln1g, ln1b, xn);
  gemm_kernel<1024, false><<<dim3(8, 512), dim3(256), 0, stream>>>(xn, WkvT, nullptr, nullptr, kv);
  attn_kernel<<<dim3(NBATCH * NH), dim3(256), 0, stream>>>(kv, qws, attn, o_ws);
  head_kernel<<<dim3(64), dim3(256), 0, stream>>>(o_ws, Wproj, bproj, ln2g, ln2b,
                                                  Wc1, bc1, Wc2, bc2, logits);
}

// Round 2
// 436.937 us; speedup vs baseline: 1.0715x; 1.0715x over previous
//
#include <hip/hip_runtime.h>

#define SEQ 2048
#define DIM 512
#define NBATCH 32
#define NH 16
#define HDIM 32
#define NCLS 2

typedef __attribute__((ext_vector_type(8))) short short8;
typedef __attribute__((ext_vector_type(8))) unsigned short ushort8;
typedef __attribute__((ext_vector_type(4))) float f32x4;

__device__ __forceinline__ float b2f(unsigned short u){
  union { unsigned int i; float f; } v; v.i = ((unsigned int)u) << 16; return v.f;
}
__device__ __forceinline__ unsigned short f2b(float f){
  unsigned int x = __float_as_uint(f);
  unsigned int r = (x + 0x7fffu + ((x >> 16) & 1u)) >> 16;
  return (unsigned short)r;
}
__device__ __forceinline__ void gload16(const void* g, void* l){
  __builtin_amdgcn_global_load_lds((const __attribute__((address_space(1))) void*)g,
                                   (__attribute__((address_space(3))) void*)l, 16, 0, 0);
}

// ---------------- K0: combined mexican-hat kernel ksum[19][512] ----------------
__global__ __launch_bounds__(256) void wavelet_kernel(const float* __restrict__ w1,
    const float* __restrict__ w2, const float* __restrict__ w3, float* __restrict__ ksum){
  int d = blockIdx.x * 256 + threadIdx.x;           // 0..511
  const float C = 0.86732501f;                      // 2/(3^0.5 * pi^0.25)
  float acc[19];
  #pragma unroll
  for (int i = 0; i < 19; ++i) acc[i] = 0.f;
  const float* waves[3] = { w1, w2, w3 };
  for (int t = 0; t < 3; ++t){
    float scale = waves[t][d];
    float shift = waves[t][DIM + d];
    float inv = 1.f / scale;
    float amp = C * rsqrtf(fabsf(scale));
    #pragma unroll
    for (int i = 0; i < 19; ++i){
      float u = ((float)(i - 9) - shift) * inv;
      acc[i] += amp * (1.f - u * u) * expf(-0.5f * u * u);
    }
  }
  #pragma unroll
  for (int i = 0; i < 19; ++i) ksum[i * DIM + d] = acc[i];
}

// ---------------- K0b: q = cls_token @ Wq   (batch-invariant) ----------------
__global__ __launch_bounds__(256) void q_kernel(const float* __restrict__ cls,
    const float* __restrict__ Wq, float* __restrict__ qws){
  int idx = blockIdx.x * 256 + threadIdx.x;         // 0..1023
  int n = idx >> 9, c = idx & 511;
  float s = 0.f;
  for (int kd = 0; kd < DIM; ++kd)
    s = fmaf(cls[n * DIM + kd], Wq[(size_t)kd * DIM + c], s);
  qws[n * DIM + c] = s;
}

// ---------------- K0c: transpose f32 [R][C] -> bf16 [C][R] ----------------
__global__ __launch_bounds__(256) void transpose_kernel(const float* __restrict__ in,
    unsigned short* __restrict__ out, int R, int C){
  __shared__ unsigned short t[64][65];
  int c0 = blockIdx.x * 64, r0 = blockIdx.y * 64;
  #pragma unroll
  for (int i = 0; i < 16; ++i){
    int idx = i * 256 + threadIdx.x;
    int r = idx >> 6, c = idx & 63;
    t[c][r] = f2b(in[(size_t)(r0 + r) * C + c0 + c]);
  }
  __syncthreads();
  #pragma unroll
  for (int i = 0; i < 16; ++i){
    int idx = i * 256 + threadIdx.x;
    int r = idx >> 6, c = idx & 63;
    out[(size_t)(c0 + r) * R + r0 + c] = t[r][c];
  }
}

// ---------------- Stage 1 fused: conv -> pos@Wp1 + x + bp1 -> LN -> xn (bf16) ----------
// One block = 128 rows x full 512 cols. 512 threads = 8 waves (2m x 4n).
__global__ __launch_bounds__(512) void stage1_kernel(
    const float* __restrict__ X, const float* __restrict__ ksum,
    const unsigned short* __restrict__ Wp1T, const float* __restrict__ bp1,
    const float* __restrict__ g1, const float* __restrict__ b1,
    unsigned short* __restrict__ Xn){
  __shared__ float xstage[160 * 64];        // x rows mloc-9 .. mloc+150 (need 146), f32
  __shared__ unsigned short lA[128 * 64];   // conv output (bf16), XOR-swizzled
  __shared__ float rowred[4][128][2];
  __shared__ float stats[128][2];
  int tid = threadIdx.x;
  int w = tid >> 6, lane = tid & 63;
  int wm = w >> 2, wn = w & 3;
  size_t mBase = (size_t)blockIdx.x * 128;
  int mloc = (int)(mBase & (SEQ - 1));
  const float* xb = X + (mBase - mloc) * DIM;   // batch base
  bool topEdge = (mloc == 0), botEdge = (mloc == SEQ - 128);
  int d = tid & 63, sgrp = tid >> 6;
  int q = lane >> 4, cl = lane & 15;
  f32x4 acc[4][8] = {};

  for (int k0 = 0; k0 < DIM; k0 += 64){
    __syncthreads();
    // stage x rows (mloc-9 .. mloc+150 clamped), cols k0..k0+63, f32
    #pragma unroll
    for (int i = 0; i < 5; ++i){
      int lrow = i * 32 + w * 4 + q;
      int srow = mloc - 9 + lrow;
      srow = srow < 0 ? 0 : (srow > SEQ - 1 ? SEQ - 1 : srow);
      gload16(xb + (size_t)srow * DIM + k0 + cl * 4, &xstage[(i * 32 + w * 4) * 64]);
    }
    __syncthreads();
    if (topEdge){
      for (int j = tid; j < 9 * 64; j += 512) xstage[j] = 0.f;
    }
    if (botEdge){
      for (int j = tid; j < 9 * 64; j += 512) xstage[137 * 64 + j] = 0.f;
    }
    if (topEdge || botEdge) __syncthreads();
    // taps for channel k0+d
    float kx[19];
    #pragma unroll
    for (int t = 0; t < 19; ++t) kx[t] = ksum[t * DIM + k0 + d];
    // conv: 16 output rows per thread (rows sgrp*16..+15), channel d
    #pragma unroll
    for (int g = 0; g < 4; ++g){
      int r0 = sgrp * 16 + g * 4;
      float a0 = 0.f, a1 = 0.f, a2 = 0.f, a3 = 0.f;
      #pragma unroll
      for (int i = 0; i < 22; ++i){
        float xv = xstage[(r0 + i) * 64 + d];
        if (i < 19)           a0 = fmaf(xv, kx[i], a0);
        if (i >= 1 && i < 20) a1 = fmaf(xv, kx[i - 1], a1);
        if (i >= 2 && i < 21) a2 = fmaf(xv, kx[i - 2], a2);
        if (i >= 3)           a3 = fmaf(xv, kx[i - 3], a3);
      }
      #pragma unroll
      for (int o = 0; o < 4; ++o){
        int r = r0 + o;
        float av = (o == 0) ? a0 : (o == 1) ? a1 : (o == 2) ? a2 : a3;
        lA[(r * 64 + d) ^ ((r & 7) << 3)] = f2b(av);   // swizzled write
      }
    }
    __syncthreads();
    // MFMA: A from lA (swizzled read), B direct from global Wp1T (L2-hot, 512 KB)
    #pragma unroll
    for (int kk = 0; kk < 2; ++kk){
      short8 af[4];
      #pragma unroll
      for (int m = 0; m < 4; ++m){
        int row = wm * 64 + m * 16 + cl;
        af[m] = *(const short8*)&lA[(row * 64 + kk * 32 + q * 8) ^ ((row & 7) << 3)];
      }
      #pragma unroll
      for (int n = 0; n < 8; ++n){
        short8 bf = *(const short8*)(Wp1T + (size_t)(wn * 128 + n * 16 + cl) * DIM
                                     + k0 + kk * 32 + q * 8);
        #pragma unroll
        for (int m = 0; m < 4; ++m)
          acc[m][n] = __builtin_amdgcn_mfma_f32_16x16x32_bf16(af[m], bf, acc[m][n], 0, 0, 0);
      }
    }
  }
  // epilogue: y = acc + x + bp1; per-row LN (full 512 cols in block); write xn bf16
  #pragma unroll
  for (int m = 0; m < 4; ++m){
    #pragma unroll
    for (int j = 0; j < 4; ++j){
      int row = wm * 64 + m * 16 + q * 4 + j;
      float sm = 0.f, sq = 0.f;
      #pragma unroll
      for (int n = 0; n < 8; ++n){
        int col = wn * 128 + n * 16 + cl;
        float v = acc[m][n][j] + X[(mBase + row) * DIM + col] + bp1[col];
        acc[m][n][j] = v;
        sm += v; sq += v * v;
      }
      #pragma unroll
      for (int off = 8; off; off >>= 1){
        sm += __shfl_xor(sm, off, 16);
        sq += __shfl_xor(sq, off, 16);
      }
      if (cl == 0){ rowred[wn][row][0] = sm; rowred[wn][row][1] = sq; }
    }
  }
  __syncthreads();
  if (tid < 128){
    float sm = rowred[0][tid][0] + rowred[1][tid][0] + rowred[2][tid][0] + rowred[3][tid][0];
    float sq = rowred[0][tid][1] + rowred[1][tid][1] + rowred[2][tid][1] + rowred[3][tid][1];
    float mean = sm * (1.f / 512.f);
    float var = sq * (1.f / 512.f) - mean * mean;
    stats[tid][0] = mean;
    stats[tid][1] = rsqrtf(var + 1e-5f);
  }
  __syncthreads();
  #pragma unroll
  for (int m = 0; m < 4; ++m){
    #pragma unroll
    for (int j = 0; j < 4; ++j){
      int row = wm * 64 + m * 16 + q * 4 + j;
      float mean = stats[row][0], rstd = stats[row][1];
      #pragma unroll
      for (int n = 0; n < 8; ++n){
        int col = wn * 128 + n * 16 + cl;
        Xn[(mBase + row) * DIM + col] = f2b((acc[m][n][j] - mean) * rstd * g1[col] + b1[col]);
      }
    }
  }
}

// ---------------- GEMM kv: C = Xn[M,512] @ WkvT[1024,512]^T, out bf16, XCD-swizzled ----
__global__ __launch_bounds__(256) void gemm_kv_kernel(const unsigned short* __restrict__ A,
    const unsigned short* __restrict__ Bt, unsigned short* __restrict__ Out){
  __shared__ unsigned short lA[128 * 64];
  __shared__ unsigned short lB[128 * 64];
  const int K = 512, N_ = 1024, NB = 8;
  int tid = threadIdx.x;
  int w = tid >> 6, lane = tid & 63;
  int wm = w >> 1, wn = w & 1;
  // XCD-bijective swizzle: 4096 blocks, each XCD gets a contiguous m-chunk
  int id = blockIdx.x;
  int nid = (id & 7) * 512 + (id >> 3);
  int nBase = (nid % NB) * 128;
  size_t mBase = (size_t)(nid / NB) * 128;
  f32x4 acc[4][4] = {};
  int e = lane * 8;
  for (int k0 = 0; k0 < K; k0 += 64){
    __syncthreads();
    #pragma unroll
    for (int c = 0; c < 4; ++c){
      int chunk = w * 4 + c;
      int ee = chunk * 512 + e;
      int row = ee >> 6, col = ee & 63;
      gload16(A + (mBase + row) * K + k0 + col, &lA[chunk * 512]);
    }
    #pragma unroll
    for (int c = 0; c < 4; ++c){
      int chunk = w * 4 + c;
      int ee = chunk * 512 + e;
      int row = ee >> 6, col = ee & 63;
      gload16(Bt + (size_t)(nBase + row) * K + k0 + col, &lB[chunk * 512]);
    }
    __syncthreads();
    #pragma unroll
    for (int kk = 0; kk < 2; ++kk){
      short8 af[4], bfr[4];
      #pragma unroll
      for (int m = 0; m < 4; ++m)
        af[m] = *(const short8*)&lA[(wm * 64 + m * 16 + (lane & 15)) * 64 + kk * 32 + (lane >> 4) * 8];
      #pragma unroll
      for (int n = 0; n < 4; ++n)
        bfr[n] = *(const short8*)&lB[(wn * 64 + n * 16 + (lane & 15)) * 64 + kk * 32 + (lane >> 4) * 8];
      #pragma unroll
      for (int m = 0; m < 4; ++m){
        #pragma unroll
        for (int n = 0; n < 4; ++n)
          acc[m][n] = __builtin_amdgcn_mfma_f32_16x16x32_bf16(af[m], bfr[n], acc[m][n], 0, 0, 0);
      }
    }
  }
  int r0 = (lane >> 4) * 4;
  int clx = lane & 15;
  #pragma unroll
  for (int m = 0; m < 4; ++m){
    #pragma unroll
    for (int n = 0; n < 4; ++n){
      int col = nBase + wn * 64 + n * 16 + clx;
      #pragma unroll
      for (int j = 0; j < 4; ++j){
        size_t row = mBase + wm * 64 + m * 16 + r0 + j;
        Out[row * N_ + col] = f2b(acc[m][n][j]);
      }
    }
  }
}

// ---------------- Attention: per (b,h), sigmoid scores + o accumulation ----------------
__global__ __launch_bounds__(256) void attn_kernel(const unsigned short* __restrict__ KV,
    const float* __restrict__ qws, float* __restrict__ aout, float* __restrict__ o_ws){
  __shared__ float qs[2][32];
  __shared__ unsigned short vls[256 * 32];
  __shared__ float als[256 * 2];
  __shared__ float red[256];
  int tid = threadIdx.x;
  int bh = blockIdx.x;
  int b = bh >> 4, h = bh & 15;
  if (tid < 64) qs[tid >> 5][tid & 31] = qws[(tid >> 5) * DIM + h * HDIM + (tid & 31)];
  __syncthreads();
  const float SCALE = 0.17677669529663687f;   // 1/sqrt(32)
  const float LOGS  = 7.6246189861593985f;    // ln(2048)
  int sub = tid >> 6, nn = (tid >> 5) & 1, hd = tid & 31;
  float oacc = 0.f;
  const unsigned short* kvb = KV + ((size_t)b * SEQ) * 1024 + h * HDIM;
  float* ab = aout + ((size_t)(b * NH + h) * NCLS) * SEQ;
  for (int ch = 0; ch < 8; ++ch){
    int s = ch * 256 + tid;
    const unsigned short* kp = kvb + (size_t)s * 1024;
    float sc0 = 0.f, sc1 = 0.f;
    #pragma unroll
    for (int g8 = 0; g8 < 4; ++g8){
      ushort8 kk = *(const ushort8*)(kp + g8 * 8);
      #pragma unroll
      for (int j = 0; j < 8; ++j){
        float kf = b2f((unsigned short)kk[j]);
        sc0 = fmaf(qs[0][g8 * 8 + j], kf, sc0);
        sc1 = fmaf(qs[1][g8 * 8 + j], kf, sc1);
      }
    }
    sc0 = fmaf(sc0, SCALE, -LOGS);
    sc1 = fmaf(sc1, SCALE, -LOGS);
    float a0 = 1.f / (1.f + expf(-sc0));
    float a1 = 1.f / (1.f + expf(-sc1));
    ab[s] = a0;
    ab[SEQ + s] = a1;
    als[tid * 2 + 0] = a0;
    als[tid * 2 + 1] = a1;
    *(ushort8*)&vls[tid * 32 + 0]  = *(const ushort8*)(kp + 512);
    *(ushort8*)&vls[tid * 32 + 8]  = *(const ushort8*)(kp + 520);
    *(ushort8*)&vls[tid * 32 + 16] = *(const ushort8*)(kp + 528);
    *(ushort8*)&vls[tid * 32 + 24] = *(const ushort8*)(kp + 536);
    __syncthreads();
    #pragma unroll 8
    for (int i = 0; i < 64; ++i){
      int ss = sub * 64 + i;
      oacc = fmaf(als[ss * 2 + nn], b2f(vls[ss * 32 + hd]), oacc);
    }
    __syncthreads();
  }
  red[tid] = oacc;
  __syncthreads();
  if (tid < 64){
    float o = red[tid] + red[tid + 64] + red[tid + 128] + red[tid + 192];
    o_ws[((size_t)(b * NCLS + (tid >> 5)) * NH + h) * HDIM + (tid & 31)] = o;
  }
}

// ---------------- Head: oproj -> LN -> Wc1 relu -> Wc2 -> logits, one block per row ----------------
__global__ __launch_bounds__(256) void head_kernel(const float* __restrict__ o_ws,
    const float* __restrict__ Wproj, const float* __restrict__ bproj,
    const float* __restrict__ g2, const float* __restrict__ b2v,
    const float* __restrict__ Wc1, const float* __restrict__ bc1,
    const float* __restrict__ Wc2, const float* __restrict__ bc2,
    float* __restrict__ logits){
  __shared__ float orow[512];
  __shared__ float hrow[512];
  __shared__ float wred[8];
  __shared__ float wred2[4];
  int tid = threadIdx.x;
  int row = blockIdx.x;
  orow[tid] = o_ws[(size_t)row * DIM + tid];
  orow[tid + 256] = o_ws[(size_t)row * DIM + tid + 256];
  __syncthreads();
  int c0 = tid * 2;
  float a0 = 0.f, a1 = 0.f;
  for (int dd = 0; dd < DIM; ++dd){
    float ov = orow[dd];
    const float* wr = Wproj + (size_t)dd * DIM + c0;
    a0 = fmaf(ov, wr[0], a0);
    a1 = fmaf(ov, wr[1], a1);
  }
  a0 += bproj[c0]; a1 += bproj[c0 + 1];
  float sm = a0 + a1, sq = a0 * a0 + a1 * a1;
  #pragma unroll
  for (int off = 32; off; off >>= 1){
    sm += __shfl_xor(sm, off, 64);
    sq += __shfl_xor(sq, off, 64);
  }
  int w = tid >> 6, lane = tid & 63;
  if (lane == 0){ wred[w * 2] = sm; wred[w * 2 + 1] = sq; }
  __syncthreads();
  sm = wred[0] + wred[2] + wred[4] + wred[6];
  sq = wred[1] + wred[3] + wred[5] + wred[7];
  float mean = sm * (1.f / 512.f);
  float var = sq * (1.f / 512.f) - mean * mean;
  float rstd = rsqrtf(var + 1e-5f);
  hrow[c0]     = (a0 - mean) * rstd * g2[c0]     + b2v[c0];
  hrow[c0 + 1] = (a1 - mean) * rstd * g2[c0 + 1] + b2v[c0 + 1];
  __syncthreads();
  float h0 = 0.f, h1 = 0.f;
  for (int dd = 0; dd < DIM; ++dd){
    float lv = hrow[dd];
    const float* wr = Wc1 + (size_t)dd * DIM + c0;
    h0 = fmaf(lv, wr[0], h0);
    h1 = fmaf(lv, wr[1], h1);
  }
  h0 += bc1[c0]; h1 += bc1[c0 + 1];
  h0 = h0 > 0.f ? h0 : 0.f;
  h1 = h1 > 0.f ? h1 : 0.f;
  float p = h0 * Wc2[c0] + h1 * Wc2[c0 + 1];
  #pragma unroll
  for (int off = 32; off; off >>= 1) p += __shfl_xor(p, off, 64);
  if (lane == 0) wred2[w] = p;
  __syncthreads();
  if (tid == 0) logits[row] = wred2[0] + wred2[1] + wred2[2] + wred2[3] + bc2[0];
}

extern "C" void kernel_launch(void* const* d_in, const int* in_sizes, int n_in,
                              void* d_out, int out_size, void* d_ws, size_t ws_size,
                              hipStream_t stream) {
  const float* x     = (const float*)d_in[0];
  const float* wave1 = (const float*)d_in[1];
  const float* wave2 = (const float*)d_in[2];
  const float* wave3 = (const float*)d_in[3];
  const float* Wp1   = (const float*)d_in[4];
  const float* bp1   = (const float*)d_in[5];
  const float* cls   = (const float*)d_in[6];
  const float* ln1g  = (const float*)d_in[7];
  const float* ln1b  = (const float*)d_in[8];
  const float* Wq    = (const float*)d_in[9];
  const float* Wkv   = (const float*)d_in[10];
  const float* Wproj = (const float*)d_in[11];
  const float* bproj = (const float*)d_in[12];
  const float* ln2g  = (const float*)d_in[13];
  const float* ln2b  = (const float*)d_in[14];
  const float* Wc1   = (const float*)d_in[15];
  const float* bc1   = (const float*)d_in[16];
  const float* Wc2   = (const float*)d_in[17];
  const float* bc2   = (const float*)d_in[18];

  float* out = (float*)d_out;
  float* logits = out;            // [32,2]
  float* attn   = out + 64;       // [32,16,2,2048]

  unsigned char* ws = (unsigned char*)d_ws;
  float* ksum          = (float*)(ws);                          // 19*512*4
  float* qws           = (float*)(ws + 65536);                  // 2*512*4
  unsigned short* Wp1T = (unsigned short*)(ws + 131072);        // 512KB
  unsigned short* WkvT = (unsigned short*)(ws + (1ull << 20));  // 1MB
  float* o_ws          = (float*)(ws + (2ull << 20));           // 128KB
  unsigned short* xn   = (unsigned short*)(ws + (4ull << 20));  // 64MB
  unsigned short* kv   = (unsigned short*)(ws + (68ull << 20)); // 128MB

  wavelet_kernel<<<dim3(2), dim3(256), 0, stream>>>(wave1, wave2, wave3, ksum);
  q_kernel<<<dim3(4), dim3(256), 0, stream>>>(cls, Wq, qws);
  transpose_kernel<<<dim3(8, 8), dim3(256), 0, stream>>>(Wp1, Wp1T, 512, 512);
  transpose_kernel<<<dim3(16, 8), dim3(256), 0, stream>>>(Wkv, WkvT, 512, 1024);
  stage1_kernel<<<dim3(512), dim3(512), 0, stream>>>(x, ksum, Wp1T, bp1, ln1g, ln1b, xn);
  gemm_kv_kernel<<<dim3(4096), dim3(256), 0, stream>>>(xn, WkvT, kv);
  attn_kernel<<<dim3(NBATCH * NH), dim3(256), 0, stream>>>(kv, qws, attn, o_ws);
  head_kernel<<<dim3(64), dim3(256), 0, stream>>>(o_ws, Wproj, bproj, ln2g, ln2b,
                                                  Wc1, bc1, Wc2, bc2, logits);
}

// Round 3
// 381.993 us; speedup vs baseline: 1.2256x; 1.1438x over previous
//
#include <hip/hip_runtime.h>

#define SEQ 2048
#define DIM 512
#define NBATCH 32
#define NH 16
#define HDIM 32
#define NCLS 2

typedef __attribute__((ext_vector_type(8))) short short8;
typedef __attribute__((ext_vector_type(8))) unsigned short ushort8;
typedef __attribute__((ext_vector_type(4))) float f32x4;

__device__ __forceinline__ float b2f(unsigned short u){
  union { unsigned int i; float f; } v; v.i = ((unsigned int)u) << 16; return v.f;
}
__device__ __forceinline__ unsigned short f2b(float f){
  unsigned int x = __float_as_uint(f);
  unsigned int r = (x + 0x7fffu + ((x >> 16) & 1u)) >> 16;
  return (unsigned short)r;
}
__device__ __forceinline__ void gload16(const void* g, void* l){
  __builtin_amdgcn_global_load_lds((const __attribute__((address_space(1))) void*)g,
                                   (__attribute__((address_space(3))) void*)l, 16, 0, 0);
}

// ---------------- combined mexican-hat kernel ksum[19][512] ----------------
__global__ __launch_bounds__(256) void wavelet_kernel(const float* __restrict__ w1,
    const float* __restrict__ w2, const float* __restrict__ w3, float* __restrict__ ksum){
  int d = blockIdx.x * 256 + threadIdx.x;
  const float C = 0.86732501f;
  float acc[19];
  #pragma unroll
  for (int i = 0; i < 19; ++i) acc[i] = 0.f;
  const float* waves[3] = { w1, w2, w3 };
  for (int t = 0; t < 3; ++t){
    float scale = waves[t][d];
    float shift = waves[t][DIM + d];
    float inv = 1.f / scale;
    float amp = C * rsqrtf(fabsf(scale));
    #pragma unroll
    for (int i = 0; i < 19; ++i){
      float u = ((float)(i - 9) - shift) * inv;
      acc[i] += amp * (1.f - u * u) * expf(-0.5f * u * u);
    }
  }
  #pragma unroll
  for (int i = 0; i < 19; ++i) ksum[i * DIM + d] = acc[i];
}

// ---------------- q = cls_token @ Wq ----------------
__global__ __launch_bounds__(256) void q_kernel(const float* __restrict__ cls,
    const float* __restrict__ Wq, float* __restrict__ qws){
  int idx = blockIdx.x * 256 + threadIdx.x;
  int n = idx >> 9, c = idx & 511;
  float s = 0.f;
  for (int kd = 0; kd < DIM; ++kd)
    s = fmaf(cls[n * DIM + kd], Wq[(size_t)kd * DIM + c], s);
  qws[n * DIM + c] = s;
}

// ---------------- transpose f32 [R][C] -> bf16 [C][R] ----------------
__global__ __launch_bounds__(256) void transpose_kernel(const float* __restrict__ in,
    unsigned short* __restrict__ out, int R, int C){
  __shared__ unsigned short t[64][65];
  int c0 = blockIdx.x * 64, r0 = blockIdx.y * 64;
  #pragma unroll
  for (int i = 0; i < 16; ++i){
    int idx = i * 256 + threadIdx.x;
    int r = idx >> 6, c = idx & 63;
    t[c][r] = f2b(in[(size_t)(r0 + r) * C + c0 + c]);
  }
  __syncthreads();
  #pragma unroll
  for (int i = 0; i < 16; ++i){
    int idx = i * 256 + threadIdx.x;
    int r = idx >> 6, c = idx & 63;
    out[(size_t)(c0 + r) * R + r0 + c] = t[r][c];
  }
}

// ---------------- GvT[c][d] = g[d] * Wkv[d][512+c], bf16 [512][512] ----------------
__global__ __launch_bounds__(256) void gvt_kernel(const float* __restrict__ Wkv,
    const float* __restrict__ g1, unsigned short* __restrict__ GvT){
  __shared__ unsigned short t[64][65];
  int c0 = blockIdx.x * 64, r0 = blockIdx.y * 64;
  #pragma unroll
  for (int i = 0; i < 16; ++i){
    int idx = i * 256 + threadIdx.x;
    int r = idx >> 6, c = idx & 63;
    t[c][r] = f2b(Wkv[(size_t)(r0 + r) * 1024 + 512 + c0 + c] * g1[r0 + r]);
  }
  __syncthreads();
  #pragma unroll
  for (int i = 0; i < 16; ++i){
    int idx = i * 256 + threadIdx.x;
    int r = idx >> 6, c = idx & 63;
    GvT[(size_t)(c0 + r) * 512 + r0 + c] = t[r][c];
  }
}

// ---------------- Aq_basic[d][hn] ----------------
__global__ __launch_bounds__(256) void aq1_kernel(const float* __restrict__ Wkv,
    const float* __restrict__ qws, float* __restrict__ Aqb){
  int idx = blockIdx.x * 256 + threadIdx.x;   // 16384
  int d = idx >> 5, hn = idx & 31;
  int h = hn >> 1, n = hn & 1;
  float s = 0.f;
  #pragma unroll
  for (int hd = 0; hd < 32; ++hd)
    s = fmaf(Wkv[(size_t)d * 1024 + h * 32 + hd], qws[n * 512 + h * 32 + hd], s);
  Aqb[d * 32 + hn] = s;
}

// ---------------- AqT'[hn][d] = SCALE * g[d] * Aq_basic[d][hn], bf16 ----------------
__global__ __launch_bounds__(256) void aqt_kernel(const float* __restrict__ Aqb,
    const float* __restrict__ g1, unsigned short* __restrict__ AqT){
  int idx = blockIdx.x * 256 + threadIdx.x;   // 16384
  int hn = idx >> 9, d = idx & 511;
  AqT[hn * 512 + d] = f2b(0.17677669529663687f * g1[d] * Aqb[d * 32 + hn]);
}

// ---------------- gv, bv, ga, ba ----------------
__global__ __launch_bounds__(256) void vec_kernel(const float* __restrict__ Wkv,
    const float* __restrict__ g1, const float* __restrict__ b1,
    const float* __restrict__ Aqb, float* __restrict__ gv, float* __restrict__ bv,
    float* __restrict__ ga, float* __restrict__ ba){
  int tid = blockIdx.x * 256 + threadIdx.x;
  if (tid < 512){
    float s1 = 0.f, s2 = 0.f;
    for (int d = 0; d < 512; ++d){
      float wv = Wkv[(size_t)d * 1024 + 512 + tid];
      s1 = fmaf(g1[d], wv, s1);
      s2 = fmaf(b1[d], wv, s2);
    }
    gv[tid] = s1; bv[tid] = s2;
  } else if (tid < 544){
    int hn = tid - 512;
    float s1 = 0.f, s2 = 0.f;
    for (int d = 0; d < 512; ++d){
      float a = Aqb[d * 32 + hn];
      s1 = fmaf(g1[d], a, s1);
      s2 = fmaf(b1[d], a, s2);
    }
    ga[hn] = 0.17677669529663687f * s1;
    ba[hn] = 0.17677669529663687f * s2 - 7.6246189861593985f;
  }
}

// ---------------- depthwise 19-tap conv -> pos bf16 ----------------
__global__ __launch_bounds__(256) void conv_kernel(const float* __restrict__ X,
    const float* __restrict__ ksum, unsigned short* __restrict__ Pos){
  int blk = blockIdx.x;
  int b = blk >> 6;
  int s0 = (blk & 63) * 32;
  int d0 = threadIdx.x * 2;
  float kx[19], ky[19];
  #pragma unroll
  for (int i = 0; i < 19; ++i){
    float2 kv = *(const float2*)&ksum[i * DIM + d0];
    kx[i] = kv.x; ky[i] = kv.y;
  }
  const float* xb = X + ((size_t)b * SEQ) * DIM + d0;
  for (int g = 0; g < 8; ++g){
    int sb = s0 + g * 4;
    float ax[4] = {0.f,0.f,0.f,0.f}, ay[4] = {0.f,0.f,0.f,0.f};
    #pragma unroll
    for (int i = 0; i < 22; ++i){
      int s = sb + i - 9;
      float xv = 0.f, yv = 0.f;
      if (s >= 0 && s < SEQ){
        float2 t = *(const float2*)&xb[(size_t)s * DIM];
        xv = t.x; yv = t.y;
      }
      #pragma unroll
      for (int o = 0; o < 4; ++o){
        int tap = i - o;
        if (tap >= 0 && tap < 19){
          ax[o] = fmaf(xv, kx[tap], ax[o]);
          ay[o] = fmaf(yv, ky[tap], ay[o]);
        }
      }
    }
    #pragma unroll
    for (int o = 0; o < 4; ++o){
      unsigned int packed = (unsigned int)f2b(ax[o]) | ((unsigned int)f2b(ay[o]) << 16);
      *(unsigned int*)&Pos[((size_t)(b * SEQ + sb + o)) * DIM + d0] = packed;
    }
  }
}

// ---------------- GEMM1 + residual + row-stat partials ----------------
__global__ __launch_bounds__(256) void gemm1_kernel(const unsigned short* __restrict__ A,
    const unsigned short* __restrict__ Bt, const float* __restrict__ Xres,
    const float* __restrict__ bias, unsigned short* __restrict__ Out,
    float* __restrict__ stat_part){
  __shared__ unsigned short lA[128 * 64];
  __shared__ unsigned short lB[128 * 64];
  __shared__ float sred[128][2][2];
  const int K = 512;
  int tid = threadIdx.x;
  int w = tid >> 6, lane = tid & 63;
  int wm = w >> 1, wn = w & 1;
  int id = blockIdx.x;
  int nid = (id & 7) * 256 + (id >> 3);
  int nch = nid & 3;
  size_t mBase = (size_t)(nid >> 2) * 128;
  int nBase = nch * 128;
  f32x4 acc[4][4] = {};
  int e = lane * 8;
  for (int k0 = 0; k0 < K; k0 += 64){
    __syncthreads();
    #pragma unroll
    for (int c = 0; c < 4; ++c){
      int chunk = w * 4 + c;
      int ee = chunk * 512 + e;
      int row = ee >> 6, col = ee & 63;
      gload16(A + (mBase + row) * K + k0 + col, &lA[chunk * 512]);
    }
    #pragma unroll
    for (int c = 0; c < 4; ++c){
      int chunk = w * 4 + c;
      int ee = chunk * 512 + e;
      int row = ee >> 6, col = ee & 63;
      gload16(Bt + (size_t)(nBase + row) * K + k0 + col, &lB[chunk * 512]);
    }
    __syncthreads();
    #pragma unroll
    for (int kk = 0; kk < 2; ++kk){
      short8 af[4], bfr[4];
      #pragma unroll
      for (int m = 0; m < 4; ++m)
        af[m] = *(const short8*)&lA[(wm * 64 + m * 16 + (lane & 15)) * 64 + kk * 32 + (lane >> 4) * 8];
      #pragma unroll
      for (int n = 0; n < 4; ++n)
        bfr[n] = *(const short8*)&lB[(wn * 64 + n * 16 + (lane & 15)) * 64 + kk * 32 + (lane >> 4) * 8];
      #pragma unroll
      for (int m = 0; m < 4; ++m){
        #pragma unroll
        for (int n = 0; n < 4; ++n)
          acc[m][n] = __builtin_amdgcn_mfma_f32_16x16x32_bf16(af[m], bfr[n], acc[m][n], 0, 0, 0);
      }
    }
  }
  int q = lane >> 4, cl = lane & 15;
  #pragma unroll
  for (int m = 0; m < 4; ++m){
    #pragma unroll
    for (int j = 0; j < 4; ++j){
      int rl = wm * 64 + m * 16 + q * 4 + j;
      size_t row = mBase + rl;
      float sm = 0.f, sq = 0.f;
      #pragma unroll
      for (int n = 0; n < 4; ++n){
        int col = nBase + wn * 64 + n * 16 + cl;
        float v = acc[m][n][j] + Xres[row * DIM + col] + bias[col];
        Out[row * DIM + col] = f2b(v);
        sm += v; sq += v * v;
      }
      #pragma unroll
      for (int off = 1; off < 16; off <<= 1){
        sm += __shfl_xor(sm, off, 64);
        sq += __shfl_xor(sq, off, 64);
      }
      if (cl == 0){ sred[rl][wn][0] = sm; sred[rl][wn][1] = sq; }
    }
  }
  __syncthreads();
  if (tid < 128){
    float sm = sred[tid][0][0] + sred[tid][1][0];
    float sq = sred[tid][0][1] + sred[tid][1][1];
    stat_part[((mBase + tid) * 4 + nch) * 2 + 0] = sm;
    stat_part[((mBase + tid) * 4 + nch) * 2 + 1] = sq;
  }
}

// ---------------- statfin ----------------
__global__ __launch_bounds__(256) void statfin_kernel(const float* __restrict__ stat_part,
    float* __restrict__ statM, float* __restrict__ statS){
  int r = blockIdx.x * 256 + threadIdx.x;
  float sm = 0.f, sq = 0.f;
  #pragma unroll
  for (int i = 0; i < 4; ++i){
    sm += stat_part[((size_t)r * 4 + i) * 2 + 0];
    sq += stat_part[((size_t)r * 4 + i) * 2 + 1];
  }
  float mean = sm * (1.f / 512.f);
  float var = sq * (1.f / 512.f) - mean * mean;
  statM[r] = mean;
  statS[r] = rsqrtf(var + 1e-5f);
}

// ---------------- stage2: v + scores + attn + PV partials ----------------
__global__ __launch_bounds__(256) void stage2_kernel(
    const unsigned short* __restrict__ Y, const unsigned short* __restrict__ GvT,
    const unsigned short* __restrict__ AqT, const float* __restrict__ statM,
    const float* __restrict__ statS, const float* __restrict__ gv,
    const float* __restrict__ bv, const float* __restrict__ ga,
    const float* __restrict__ ba, float* __restrict__ aout, float* __restrict__ o_part){
  __shared__ __align__(16) char smem[67072];
  unsigned short* lA = (unsigned short*)smem;
  unsigned short* lB = (unsigned short*)(smem + 16384);
  unsigned short* aq = (unsigned short*)(smem + 32768);
  float* stats = (float*)(smem + 66048);
  float* attn_lds = (float*)smem;
  float* o_red = (float*)(smem + 16896);
  const int K = 512;
  int tid = threadIdx.x;
  int w = tid >> 6, lane = tid & 63;
  int wm = w >> 1, wn = w & 1;
  int q = lane >> 4, cl = lane & 15;
  int id = blockIdx.x;
  int nid = (id & 7) * 256 + (id >> 3);
  int nch = nid & 3;
  int mb = nid >> 2;
  size_t mBase = (size_t)mb * 128;
  int nBase = nch * 128;
  for (int i = tid; i < 32 * 64; i += 256){
    int r = i >> 6, c8 = (i & 63) * 8;
    *(ushort8*)&aq[r * 520 + c8] = *(const ushort8*)&AqT[r * 512 + c8];
  }
  if (tid < 128){
    stats[tid * 2 + 0] = statM[mBase + tid];
    stats[tid * 2 + 1] = statS[mBase + tid];
  }
  f32x4 acc[4][4] = {};
  f32x4 accs[4] = {};
  int e = lane * 8;
  for (int k0 = 0; k0 < K; k0 += 64){
    __syncthreads();
    #pragma unroll
    for (int c = 0; c < 4; ++c){
      int chunk = w * 4 + c;
      int ee = chunk * 512 + e;
      int row = ee >> 6, col = ee & 63;
      gload16(Y + (mBase + row) * K + k0 + col, &lA[chunk * 512]);
    }
    #pragma unroll
    for (int c = 0; c < 4; ++c){
      int chunk = w * 4 + c;
      int ee = chunk * 512 + e;
      int row = ee >> 6, col = ee & 63;
      gload16(GvT + (size_t)(nBase + row) * K + k0 + col, &lB[chunk * 512]);
    }
    __syncthreads();
    #pragma unroll
    for (int kk = 0; kk < 2; ++kk){
      short8 af[4], bfr[4], bq;
      #pragma unroll
      for (int m = 0; m < 4; ++m)
        af[m] = *(const short8*)&lA[(wm * 64 + m * 16 + cl) * 64 + kk * 32 + q * 8];
      #pragma unroll
      for (int n = 0; n < 4; ++n)
        bfr[n] = *(const short8*)&lB[(wn * 64 + n * 16 + cl) * 64 + kk * 32 + q * 8];
      bq = *(const short8*)&aq[(wn * 16 + cl) * 520 + k0 + kk * 32 + q * 8];
      #pragma unroll
      for (int m = 0; m < 4; ++m){
        #pragma unroll
        for (int n = 0; n < 4; ++n)
          acc[m][n] = __builtin_amdgcn_mfma_f32_16x16x32_bf16(af[m], bfr[n], acc[m][n], 0, 0, 0);
        accs[m] = __builtin_amdgcn_mfma_f32_16x16x32_bf16(af[m], bq, accs[m], 0, 0, 0);
      }
    }
  }
  __syncthreads();
  int hn = wn * 16 + cl;
  float gav = ga[hn], bav = ba[hn];
  float gv4[4], bv4[4];
  #pragma unroll
  for (int n = 0; n < 4; ++n){
    int cg = nBase + wn * 64 + n * 16 + cl;
    gv4[n] = gv[cg]; bv4[n] = bv[cg];
  }
  int b = mb >> 4;
  int scb = (mb & 15) * 128;
  #pragma unroll
  for (int m = 0; m < 4; ++m){
    #pragma unroll
    for (int j = 0; j < 4; ++j){
      int rl = wm * 64 + m * 16 + q * 4 + j;
      float mu = stats[rl * 2 + 0], s = stats[rl * 2 + 1];
      float sc = s * accs[m][j] - s * mu * gav + bav;
      float at = 1.f / (1.f + expf(-sc));
      attn_lds[rl * 33 + hn] = at;
      if (nch == 0)
        aout[((size_t)(b * NH + (hn >> 1)) * NCLS + (hn & 1)) * SEQ + scb + rl] = at;
      #pragma unroll
      for (int n = 0; n < 4; ++n)
        acc[m][n][j] = s * acc[m][n][j] - s * mu * gv4[n] + bv4[n];
    }
  }
  __syncthreads();
  float o0[4] = {}, o1[4] = {};
  #pragma unroll
  for (int n = 0; n < 4; ++n){
    int cg = nBase + wn * 64 + n * 16 + cl;
    int h2 = ((cg >> 5) << 1);
    #pragma unroll
    for (int m = 0; m < 4; ++m){
      #pragma unroll
      for (int j = 0; j < 4; ++j){
        int rl = wm * 64 + m * 16 + q * 4 + j;
        float vv = acc[m][n][j];
        o0[n] = fmaf(attn_lds[rl * 33 + h2 + 0], vv, o0[n]);
        o1[n] = fmaf(attn_lds[rl * 33 + h2 + 1], vv, o1[n]);
      }
    }
  }
  #pragma unroll
  for (int n = 0; n < 4; ++n){
    o0[n] += __shfl_xor(o0[n], 16, 64);
    o0[n] += __shfl_xor(o0[n], 32, 64);
    o1[n] += __shfl_xor(o1[n], 16, 64);
    o1[n] += __shfl_xor(o1[n], 32, 64);
  }
  if (q == 0){
    #pragma unroll
    for (int n = 0; n < 4; ++n){
      int c = wn * 64 + n * 16 + cl;
      o_red[(0 * 2 + wm) * 128 + c] = o0[n];
      o_red[(1 * 2 + wm) * 128 + c] = o1[n];
    }
  }
  __syncthreads();
  {
    int nn = tid >> 7, c = tid & 127;
    float v = o_red[(nn * 2 + 0) * 128 + c] + o_red[(nn * 2 + 1) * 128 + c];
    o_part[((size_t)mb * 2 + nn) * 512 + nBase + c] = v;
  }
}

// ---------------- Head ----------------
__global__ __launch_bounds__(256) void head_kernel(const float* __restrict__ o_part,
    const float* __restrict__ Wproj, const float* __restrict__ bproj,
    const float* __restrict__ g2, const float* __restrict__ b2v,
    const float* __restrict__ Wc1, const float* __restrict__ bc1,
    const float* __restrict__ Wc2, const float* __restrict__ bc2,
    float* __restrict__ logits){
  __shared__ float orow[512];
  __shared__ float hrow[512];
  __shared__ float wred[8];
  __shared__ float wred2[4];
  int tid = threadIdx.x;
  int row = blockIdx.x;
  int b = row >> 1, nn = row & 1;
  for (int i = tid; i < 512; i += 256){
    float s = 0.f;
    const float* op = o_part + (((size_t)b * 16) * 2 + nn) * 512 + i;
    #pragma unroll
    for (int sc = 0; sc < 16; ++sc) s += op[(size_t)sc * 1024];
    orow[i] = s;
  }
  __syncthreads();
  int c0 = tid * 2;
  float a0 = 0.f, a1 = 0.f;
  for (int dd = 0; dd < DIM; ++dd){
    float ov = orow[dd];
    const float* wr = Wproj + (size_t)dd * DIM + c0;
    a0 = fmaf(ov, wr[0], a0);
    a1 = fmaf(ov, wr[1], a1);
  }
  a0 += bproj[c0]; a1 += bproj[c0 + 1];
  float sm = a0 + a1, sq = a0 * a0 + a1 * a1;
  #pragma unroll
  for (int off = 32; off; off >>= 1){
    sm += __shfl_xor(sm, off, 64);
    sq += __shfl_xor(sq, off, 64);
  }
  int w = tid >> 6, lane = tid & 63;
  if (lane == 0){ wred[w * 2] = sm; wred[w * 2 + 1] = sq; }
  __syncthreads();
  sm = wred[0] + wred[2] + wred[4] + wred[6];
  sq = wred[1] + wred[3] + wred[5] + wred[7];
  float mean = sm * (1.f / 512.f);
  float var = sq * (1.f / 512.f) - mean * mean;
  float rstd = rsqrtf(var + 1e-5f);
  hrow[c0]     = (a0 - mean) * rstd * g2[c0]     + b2v[c0];
  hrow[c0 + 1] = (a1 - mean) * rstd * g2[c0 + 1] + b2v[c0 + 1];
  __syncthreads();
  float h0 = 0.f, h1 = 0.f;
  for (int dd = 0; dd < DIM; ++dd){
    float lv = hrow[dd];
    const float* wr = Wc1 + (size_t)dd * DIM + c0;
    h0 = fmaf(lv, wr[0], h0);
    h1 = fmaf(lv, wr[1], h1);
  }
  h0 += bc1[c0]; h1 += bc1[c0 + 1];
  h0 = h0 > 0.f ? h0 : 0.f;
  h1 = h1 > 0.f ? h1 : 0.f;
  float p = h0 * Wc2[c0] + h1 * Wc2[c0 + 1];
  #pragma unroll
  for (int off = 32; off; off >>= 1) p += __shfl_xor(p, off, 64);
  if (lane == 0) wred2[w] = p;
  __syncthreads();
  if (tid == 0) logits[row] = wred2[0] + wred2[1] + wred2[2] + wred2[3] + bc2[0];
}

extern "C" void kernel_launch(void* const* d_in, const int* in_sizes, int n_in,
                              void* d_out, int out_size, void* d_ws, size_t ws_size,
                              hipStream_t stream) {
  const float* x     = (const float*)d_in[0];
  const float* wave1 = (const float*)d_in[1];
  const float* wave2 = (const float*)d_in[2];
  const float* wave3 = (const float*)d_in[3];
  const float* Wp1   = (const float*)d_in[4];
  const float* bp1   = (const float*)d_in[5];
  const float* cls   = (const float*)d_in[6];
  const float* ln1g  = (const float*)d_in[7];
  const float* ln1b  = (const float*)d_in[8];
  const float* Wq    = (const float*)d_in[9];
  const float* Wkv   = (const float*)d_in[10];
  const float* Wproj = (const float*)d_in[11];
  const float* bproj = (const float*)d_in[12];
  const float* ln2g  = (const float*)d_in[13];
  const float* ln2b  = (const float*)d_in[14];
  const float* Wc1   = (const float*)d_in[15];
  const float* bc1   = (const float*)d_in[16];
  const float* Wc2   = (const float*)d_in[17];
  const float* bc2   = (const float*)d_in[18];

  float* out = (float*)d_out;
  float* logits = out;
  float* attn   = out + 64;

  unsigned char* ws = (unsigned char*)d_ws;
  float* ksum           = (float*)(ws);
  float* qws            = (float*)(ws + (64u << 10));
  unsigned short* Wp1T  = (unsigned short*)(ws + (128u << 10));
  unsigned short* GvT   = (unsigned short*)(ws + (640u << 10));
  unsigned short* AqT   = (unsigned short*)(ws + (1152u << 10));
  float* Aqb            = (float*)(ws + (1184u << 10));
  float* gv             = (float*)(ws + (1248u << 10));
  float* bv             = (float*)(ws + (1252u << 10));
  float* ga             = (float*)(ws + (1256u << 10));
  float* ba             = (float*)(ws + (1260u << 10));
  float* statM          = (float*)(ws + (1264u << 10));
  float* statS          = (float*)(ws + (1520u << 10));
  float* o_part         = (float*)(ws + (1776u << 10));
  float* stat_part      = (float*)(ws + (4096u << 10));
  unsigned short* pos   = (unsigned short*)(ws + (8ull << 20));
  unsigned short* yb    = (unsigned short*)(ws + (72ull << 20));

  wavelet_kernel<<<dim3(2), dim3(256), 0, stream>>>(wave1, wave2, wave3, ksum);
  q_kernel<<<dim3(4), dim3(256), 0, stream>>>(cls, Wq, qws);
  transpose_kernel<<<dim3(8, 8), dim3(256), 0, stream>>>(Wp1, Wp1T, 512, 512);
  gvt_kernel<<<dim3(8, 8), dim3(256), 0, stream>>>(Wkv, ln1g, GvT);
  aq1_kernel<<<dim3(64), dim3(256), 0, stream>>>(Wkv, qws, Aqb);
  aqt_kernel<<<dim3(64), dim3(256), 0, stream>>>(Aqb, ln1g, AqT);
  vec_kernel<<<dim3(3), dim3(256), 0, stream>>>(Wkv, ln1g, ln1b, Aqb, gv, bv, ga, ba);
  conv_kernel<<<dim3(NBATCH * 64), dim3(256), 0, stream>>>(x, ksum, pos);
  gemm1_kernel<<<dim3(2048), dim3(256), 0, stream>>>(pos, Wp1T, x, bp1, yb, stat_part);
  statfin_kernel<<<dim3(256), dim3(256), 0, stream>>>(stat_part, statM, statS);
  stage2_kernel<<<dim3(2048), dim3(256), 0, stream>>>(yb, GvT, AqT, statM, statS,
                                                      gv, bv, ga, ba, attn, o_part);
  head_kernel<<<dim3(64), dim3(256), 0, stream>>>(o_part, Wproj, bproj, ln2g, ln2b,
                                                  Wc1, bc1, Wc2, bc2, logits);
}

// Round 4
// 327.669 us; speedup vs baseline: 1.4288x; 1.1658x over previous
//
#include <hip/hip_runtime.h>

#define SEQ 2048
#define DIM 512
#define NBATCH 32
#define NH 16
#define HDIM 32
#define NCLS 2

typedef __attribute__((ext_vector_type(8))) short short8;
typedef __attribute__((ext_vector_type(8))) unsigned short ushort8;
typedef __attribute__((ext_vector_type(4))) float f32x4;

__device__ __forceinline__ float b2f(unsigned short u){
  union { unsigned int i; float f; } v; v.i = ((unsigned int)u) << 16; return v.f;
}
__device__ __forceinline__ unsigned short f2b(float f){
  unsigned int x = __float_as_uint(f);
  unsigned int r = (x + 0x7fffu + ((x >> 16) & 1u)) >> 16;
  return (unsigned short)r;
}
__device__ __forceinline__ void gload16(const void* g, void* l){
  __builtin_amdgcn_global_load_lds((const __attribute__((address_space(1))) void*)g,
                                   (__attribute__((address_space(3))) void*)l, 16, 0, 0);
}

// ---------------- prep1: wavelet ksum | q = cls@Wq | Wp1T | GvT ----------------
__global__ __launch_bounds__(256) void prep1_kernel(
    const float* __restrict__ w1, const float* __restrict__ w2, const float* __restrict__ w3,
    float* __restrict__ ksum,
    const float* __restrict__ cls, const float* __restrict__ Wq, float* __restrict__ qws,
    const float* __restrict__ Wp1, unsigned short* __restrict__ Wp1T,
    const float* __restrict__ Wkv, const float* __restrict__ g1, unsigned short* __restrict__ GvT){
  __shared__ unsigned short t[64][65];
  int bid = blockIdx.x;
  int tid = threadIdx.x;
  if (bid < 2){
    int d = bid * 256 + tid;
    const float C = 0.86732501f;
    float acc[19];
    #pragma unroll
    for (int i = 0; i < 19; ++i) acc[i] = 0.f;
    const float* waves[3] = { w1, w2, w3 };
    for (int tt = 0; tt < 3; ++tt){
      float scale = waves[tt][d];
      float shift = waves[tt][DIM + d];
      float inv = 1.f / scale;
      float amp = C * rsqrtf(fabsf(scale));
      #pragma unroll
      for (int i = 0; i < 19; ++i){
        float u = ((float)(i - 9) - shift) * inv;
        acc[i] += amp * (1.f - u * u) * expf(-0.5f * u * u);
      }
    }
    #pragma unroll
    for (int i = 0; i < 19; ++i) ksum[i * DIM + d] = acc[i];
  } else if (bid < 6){
    int idx = (bid - 2) * 256 + tid;
    int n = idx >> 9, c = idx & 511;
    float s = 0.f;
    for (int kd = 0; kd < DIM; ++kd)
      s = fmaf(cls[n * DIM + kd], Wq[(size_t)kd * DIM + c], s);
    qws[n * DIM + c] = s;
  } else if (bid < 70){
    int bx = bid - 6;
    int c0 = (bx & 7) * 64, r0 = (bx >> 3) * 64;
    #pragma unroll
    for (int i = 0; i < 16; ++i){
      int idx = i * 256 + tid;
      int r = idx >> 6, c = idx & 63;
      t[c][r] = f2b(Wp1[(size_t)(r0 + r) * 512 + c0 + c]);
    }
    __syncthreads();
    #pragma unroll
    for (int i = 0; i < 16; ++i){
      int idx = i * 256 + tid;
      int r = idx >> 6, c = idx & 63;
      Wp1T[(size_t)(c0 + r) * 512 + r0 + c] = t[r][c];
    }
  } else {
    int bx = bid - 70;
    int c0 = (bx & 7) * 64, r0 = (bx >> 3) * 64;
    #pragma unroll
    for (int i = 0; i < 16; ++i){
      int idx = i * 256 + tid;
      int r = idx >> 6, c = idx & 63;
      t[c][r] = f2b(Wkv[(size_t)(r0 + r) * 1024 + 512 + c0 + c] * g1[r0 + r]);
    }
    __syncthreads();
    #pragma unroll
    for (int i = 0; i < 16; ++i){
      int idx = i * 256 + tid;
      int r = idx >> 6, c = idx & 63;
      GvT[(size_t)(c0 + r) * 512 + r0 + c] = t[r][c];
    }
  }
}

// ---------------- prep2: Aq_basic[d][hn] ----------------
__global__ __launch_bounds__(256) void prep2_kernel(const float* __restrict__ Wkv,
    const float* __restrict__ qws, float* __restrict__ Aqb){
  int idx = blockIdx.x * 256 + threadIdx.x;   // 16384
  int d = idx >> 5, hn = idx & 31;
  int h = hn >> 1, n = hn & 1;
  float s = 0.f;
  #pragma unroll
  for (int hd = 0; hd < 32; ++hd)
    s = fmaf(Wkv[(size_t)d * 1024 + h * 32 + hd], qws[n * 512 + h * 32 + hd], s);
  Aqb[d * 32 + hn] = s;
}

// ---------------- prep3: AqT | gv,bv,ga,ba ----------------
__global__ __launch_bounds__(256) void prep3_kernel(const float* __restrict__ Aqb,
    const float* __restrict__ g1, const float* __restrict__ b1,
    const float* __restrict__ Wkv, unsigned short* __restrict__ AqT,
    float* __restrict__ gv, float* __restrict__ bv,
    float* __restrict__ ga, float* __restrict__ ba){
  int bid = blockIdx.x;
  if (bid < 64){
    int idx = bid * 256 + threadIdx.x;
    int hn = idx >> 9, d = idx & 511;
    AqT[hn * 512 + d] = f2b(0.17677669529663687f * g1[d] * Aqb[d * 32 + hn]);
  } else {
    int tid = (bid - 64) * 256 + threadIdx.x;
    if (tid < 512){
      float s1 = 0.f, s2 = 0.f;
      for (int d = 0; d < 512; ++d){
        float wv = Wkv[(size_t)d * 1024 + 512 + tid];
        s1 = fmaf(g1[d], wv, s1);
        s2 = fmaf(b1[d], wv, s2);
      }
      gv[tid] = s1; bv[tid] = s2;
    } else if (tid < 544){
      int hn = tid - 512;
      float s1 = 0.f, s2 = 0.f;
      for (int d = 0; d < 512; ++d){
        float a = Aqb[d * 32 + hn];
        s1 = fmaf(g1[d], a, s1);
        s2 = fmaf(b1[d], a, s2);
      }
      ga[hn] = 0.17677669529663687f * s1;
      ba[hn] = 0.17677669529663687f * s2 - 7.6246189861593985f;
    }
  }
}

// ---------------- conv v2: sliding-window FIR, 16 outputs x 2 channels / thread --------
template<bool EDGE>
__device__ __forceinline__ void conv_strip(const float* __restrict__ xb,
    const float* __restrict__ ksum, unsigned short* __restrict__ Pos,
    int b, int s0, int d0){
  float kx[19], ky[19];
  #pragma unroll
  for (int t = 0; t < 19; ++t){
    float2 kv = *(const float2*)&ksum[t * DIM + d0];
    kx[t] = kv.x; ky[t] = kv.y;
  }
  float ox[16], oy[16];
  #pragma unroll
  for (int o = 0; o < 16; ++o){ ox[o] = 0.f; oy[o] = 0.f; }
  const float* xp = xb + (size_t)(s0 - 9) * DIM + d0;
  #pragma unroll
  for (int bi = 0; bi < 5; ++bi){
    float xvx[8], xvy[8];
    #pragma unroll
    for (int j = 0; j < 8; ++j){
      int w = bi * 8 + j;
      if (w < 34){
        if (EDGE){
          int s = s0 - 9 + w;
          int sc = s < 0 ? 0 : (s > SEQ - 1 ? SEQ - 1 : s);
          float2 tv = *(const float2*)&xb[(size_t)sc * DIM + d0];
          bool ok = (s >= 0) && (s < SEQ);
          xvx[j] = ok ? tv.x : 0.f;
          xvy[j] = ok ? tv.y : 0.f;
        } else {
          float2 tv = *(const float2*)&xp[(size_t)w * DIM];
          xvx[j] = tv.x; xvy[j] = tv.y;
        }
      }
    }
    #pragma unroll
    for (int j = 0; j < 8; ++j){
      int w = bi * 8 + j;
      if (w < 34){
        #pragma unroll
        for (int o = 0; o < 16; ++o){
          int t2 = w - o;
          if (t2 >= 0 && t2 < 19){
            ox[o] = fmaf(xvx[j], kx[t2], ox[o]);
            oy[o] = fmaf(xvy[j], ky[t2], oy[o]);
          }
        }
      }
    }
  }
  #pragma unroll
  for (int o = 0; o < 16; ++o){
    unsigned int packed = (unsigned int)f2b(ox[o]) | ((unsigned int)f2b(oy[o]) << 16);
    *(unsigned int*)&Pos[((size_t)(b * SEQ + s0 + o)) * DIM + d0] = packed;
  }
}

__global__ __launch_bounds__(256) void conv_kernel(const float* __restrict__ X,
    const float* __restrict__ ksum, unsigned short* __restrict__ Pos){
  int id = blockIdx.x;                       // 4096
  int id2 = (id & 7) * 512 + (id >> 3);      // XCD-bijective: strips contiguous per XCD
  int b = id2 >> 7;
  int strip = id2 & 127;
  int s0 = strip * 16;
  int d0 = threadIdx.x * 2;
  const float* xb = X + ((size_t)b * SEQ) * DIM;
  if (strip == 0 || strip == 127)
    conv_strip<true>(xb, ksum, Pos, b, s0, d0);
  else
    conv_strip<false>(xb, ksum, Pos, b, s0, d0);
}

// ---------------- GEMM1 + residual + row-stat partials ----------------
__global__ __launch_bounds__(256) void gemm1_kernel(const unsigned short* __restrict__ A,
    const unsigned short* __restrict__ Bt, const float* __restrict__ Xres,
    const float* __restrict__ bias, unsigned short* __restrict__ Out,
    float* __restrict__ stat_part){
  __shared__ unsigned short lA[128 * 64];
  __shared__ unsigned short lB[128 * 64];
  __shared__ float sred[128][2][2];
  const int K = 512;
  int tid = threadIdx.x;
  int w = tid >> 6, lane = tid & 63;
  int wm = w >> 1, wn = w & 1;
  int id = blockIdx.x;
  int nid = (id & 7) * 256 + (id >> 3);
  int nch = nid & 3;
  size_t mBase = (size_t)(nid >> 2) * 128;
  int nBase = nch * 128;
  f32x4 acc[4][4] = {};
  int e = lane * 8;
  for (int k0 = 0; k0 < K; k0 += 64){
    __syncthreads();
    #pragma unroll
    for (int c = 0; c < 4; ++c){
      int chunk = w * 4 + c;
      int ee = chunk * 512 + e;
      int row = ee >> 6, col = ee & 63;
      gload16(A + (mBase + row) * K + k0 + col, &lA[chunk * 512]);
    }
    #pragma unroll
    for (int c = 0; c < 4; ++c){
      int chunk = w * 4 + c;
      int ee = chunk * 512 + e;
      int row = ee >> 6, col = ee & 63;
      gload16(Bt + (size_t)(nBase + row) * K + k0 + col, &lB[chunk * 512]);
    }
    __syncthreads();
    #pragma unroll
    for (int kk = 0; kk < 2; ++kk){
      short8 af[4], bfr[4];
      #pragma unroll
      for (int m = 0; m < 4; ++m)
        af[m] = *(const short8*)&lA[(wm * 64 + m * 16 + (lane & 15)) * 64 + kk * 32 + (lane >> 4) * 8];
      #pragma unroll
      for (int n = 0; n < 4; ++n)
        bfr[n] = *(const short8*)&lB[(wn * 64 + n * 16 + (lane & 15)) * 64 + kk * 32 + (lane >> 4) * 8];
      #pragma unroll
      for (int m = 0; m < 4; ++m){
        #pragma unroll
        for (int n = 0; n < 4; ++n)
          acc[m][n] = __builtin_amdgcn_mfma_f32_16x16x32_bf16(af[m], bfr[n], acc[m][n], 0, 0, 0);
      }
    }
  }
  int q = lane >> 4, cl = lane & 15;
  #pragma unroll
  for (int m = 0; m < 4; ++m){
    #pragma unroll
    for (int j = 0; j < 4; ++j){
      int rl = wm * 64 + m * 16 + q * 4 + j;
      size_t row = mBase + rl;
      float sm = 0.f, sq = 0.f;
      #pragma unroll
      for (int n = 0; n < 4; ++n){
        int col = nBase + wn * 64 + n * 16 + cl;
        float v = acc[m][n][j] + Xres[row * DIM + col] + bias[col];
        Out[row * DIM + col] = f2b(v);
        sm += v; sq += v * v;
      }
      #pragma unroll
      for (int off = 1; off < 16; off <<= 1){
        sm += __shfl_xor(sm, off, 64);
        sq += __shfl_xor(sq, off, 64);
      }
      if (cl == 0){ sred[rl][wn][0] = sm; sred[rl][wn][1] = sq; }
    }
  }
  __syncthreads();
  if (tid < 128){
    float sm = sred[tid][0][0] + sred[tid][1][0];
    float sq = sred[tid][0][1] + sred[tid][1][1];
    stat_part[((mBase + tid) * 4 + nch) * 2 + 0] = sm;
    stat_part[((mBase + tid) * 4 + nch) * 2 + 1] = sq;
  }
}

// ---------------- statfin ----------------
__global__ __launch_bounds__(256) void statfin_kernel(const float* __restrict__ stat_part,
    float* __restrict__ statM, float* __restrict__ statS){
  int r = blockIdx.x * 256 + threadIdx.x;
  float sm = 0.f, sq = 0.f;
  #pragma unroll
  for (int i = 0; i < 4; ++i){
    sm += stat_part[((size_t)r * 4 + i) * 2 + 0];
    sq += stat_part[((size_t)r * 4 + i) * 2 + 1];
  }
  float mean = sm * (1.f / 512.f);
  float var = sq * (1.f / 512.f) - mean * mean;
  statM[r] = mean;
  statS[r] = rsqrtf(var + 1e-5f);
}

// ---------------- stage2: v + scores + attn + PV partials ----------------
__global__ __launch_bounds__(256) void stage2_kernel(
    const unsigned short* __restrict__ Y, const unsigned short* __restrict__ GvT,
    const unsigned short* __restrict__ AqT, const float* __restrict__ statM,
    const float* __restrict__ statS, const float* __restrict__ gv,
    const float* __restrict__ bv, const float* __restrict__ ga,
    const float* __restrict__ ba, float* __restrict__ aout, float* __restrict__ o_part){
  __shared__ __align__(16) char smem[67072];
  unsigned short* lA = (unsigned short*)smem;
  unsigned short* lB = (unsigned short*)(smem + 16384);
  unsigned short* aq = (unsigned short*)(smem + 32768);
  float* stats = (float*)(smem + 66048);
  float* attn_lds = (float*)smem;
  float* o_red = (float*)(smem + 16896);
  const int K = 512;
  int tid = threadIdx.x;
  int w = tid >> 6, lane = tid & 63;
  int wm = w >> 1, wn = w & 1;
  int q = lane >> 4, cl = lane & 15;
  int id = blockIdx.x;
  int nid = (id & 7) * 256 + (id >> 3);
  int nch = nid & 3;
  int mb = nid >> 2;
  size_t mBase = (size_t)mb * 128;
  int nBase = nch * 128;
  for (int i = tid; i < 32 * 64; i += 256){
    int r = i >> 6, c8 = (i & 63) * 8;
    *(ushort8*)&aq[r * 520 + c8] = *(const ushort8*)&AqT[r * 512 + c8];
  }
  if (tid < 128){
    stats[tid * 2 + 0] = statM[mBase + tid];
    stats[tid * 2 + 1] = statS[mBase + tid];
  }
  f32x4 acc[4][4] = {};
  f32x4 accs[4] = {};
  int e = lane * 8;
  for (int k0 = 0; k0 < K; k0 += 64){
    __syncthreads();
    #pragma unroll
    for (int c = 0; c < 4; ++c){
      int chunk = w * 4 + c;
      int ee = chunk * 512 + e;
      int row = ee >> 6, col = ee & 63;
      gload16(Y + (mBase + row) * K + k0 + col, &lA[chunk * 512]);
    }
    #pragma unroll
    for (int c = 0; c < 4; ++c){
      int chunk = w * 4 + c;
      int ee = chunk * 512 + e;
      int row = ee >> 6, col = ee & 63;
      gload16(GvT + (size_t)(nBase + row) * K + k0 + col, &lB[chunk * 512]);
    }
    __syncthreads();
    #pragma unroll
    for (int kk = 0; kk < 2; ++kk){
      short8 af[4], bfr[4], bq;
      #pragma unroll
      for (int m = 0; m < 4; ++m)
        af[m] = *(const short8*)&lA[(wm * 64 + m * 16 + cl) * 64 + kk * 32 + q * 8];
      #pragma unroll
      for (int n = 0; n < 4; ++n)
        bfr[n] = *(const short8*)&lB[(wn * 64 + n * 16 + cl) * 64 + kk * 32 + q * 8];
      bq = *(const short8*)&aq[(wn * 16 + cl) * 520 + k0 + kk * 32 + q * 8];
      #pragma unroll
      for (int m = 0; m < 4; ++m){
        #pragma unroll
        for (int n = 0; n < 4; ++n)
          acc[m][n] = __builtin_amdgcn_mfma_f32_16x16x32_bf16(af[m], bfr[n], acc[m][n], 0, 0, 0);
        accs[m] = __builtin_amdgcn_mfma_f32_16x16x32_bf16(af[m], bq, accs[m], 0, 0, 0);
      }
    }
  }
  __syncthreads();
  int hn = wn * 16 + cl;
  float gav = ga[hn], bav = ba[hn];
  float gv4[4], bv4[4];
  #pragma unroll
  for (int n = 0; n < 4; ++n){
    int cg = nBase + wn * 64 + n * 16 + cl;
    gv4[n] = gv[cg]; bv4[n] = bv[cg];
  }
  int b = mb >> 4;
  int scb = (mb & 15) * 128;
  #pragma unroll
  for (int m = 0; m < 4; ++m){
    #pragma unroll
    for (int j = 0; j < 4; ++j){
      int rl = wm * 64 + m * 16 + q * 4 + j;
      float mu = stats[rl * 2 + 0], s = stats[rl * 2 + 1];
      float sc = s * accs[m][j] - s * mu * gav + bav;
      float at = 1.f / (1.f + expf(-sc));
      attn_lds[rl * 33 + hn] = at;
      if (nch == 0)
        aout[((size_t)(b * NH + (hn >> 1)) * NCLS + (hn & 1)) * SEQ + scb + rl] = at;
      #pragma unroll
      for (int n = 0; n < 4; ++n)
        acc[m][n][j] = s * acc[m][n][j] - s * mu * gv4[n] + bv4[n];
    }
  }
  __syncthreads();
  float o0[4] = {}, o1[4] = {};
  #pragma unroll
  for (int n = 0; n < 4; ++n){
    int cg = nBase + wn * 64 + n * 16 + cl;
    int h2 = ((cg >> 5) << 1);
    #pragma unroll
    for (int m = 0; m < 4; ++m){
      #pragma unroll
      for (int j = 0; j < 4; ++j){
        int rl = wm * 64 + m * 16 + q * 4 + j;
        float vv = acc[m][n][j];
        o0[n] = fmaf(attn_lds[rl * 33 + h2 + 0], vv, o0[n]);
        o1[n] = fmaf(attn_lds[rl * 33 + h2 + 1], vv, o1[n]);
      }
    }
  }
  #pragma unroll
  for (int n = 0; n < 4; ++n){
    o0[n] += __shfl_xor(o0[n], 16, 64);
    o0[n] += __shfl_xor(o0[n], 32, 64);
    o1[n] += __shfl_xor(o1[n], 16, 64);
    o1[n] += __shfl_xor(o1[n], 32, 64);
  }
  if (q == 0){
    #pragma unroll
    for (int n = 0; n < 4; ++n){
      int c = wn * 64 + n * 16 + cl;
      o_red[(0 * 2 + wm) * 128 + c] = o0[n];
      o_red[(1 * 2 + wm) * 128 + c] = o1[n];
    }
  }
  __syncthreads();
  {
    int nn = tid >> 7, c = tid & 127;
    float v = o_red[(nn * 2 + 0) * 128 + c] + o_red[(nn * 2 + 1) * 128 + c];
    o_part[((size_t)mb * 2 + nn) * 512 + nBase + c] = v;
  }
}

// ---------------- Head ----------------
__global__ __launch_bounds__(256) void head_kernel(const float* __restrict__ o_part,
    const float* __restrict__ Wproj, const float* __restrict__ bproj,
    const float* __restrict__ g2, const float* __restrict__ b2v,
    const float* __restrict__ Wc1, const float* __restrict__ bc1,
    const float* __restrict__ Wc2, const float* __restrict__ bc2,
    float* __restrict__ logits){
  __shared__ float orow[512];
  __shared__ float hrow[512];
  __shared__ float wred[8];
  __shared__ float wred2[4];
  int tid = threadIdx.x;
  int row = blockIdx.x;
  int b = row >> 1, nn = row & 1;
  for (int i = tid; i < 512; i += 256){
    float s = 0.f;
    const float* op = o_part + (((size_t)b * 16) * 2 + nn) * 512 + i;
    #pragma unroll
    for (int sc = 0; sc < 16; ++sc) s += op[(size_t)sc * 1024];
    orow[i] = s;
  }
  __syncthreads();
  int c0 = tid * 2;
  float a0 = 0.f, a1 = 0.f;
  for (int dd = 0; dd < DIM; ++dd){
    float ov = orow[dd];
    const float* wr = Wproj + (size_t)dd * DIM + c0;
    a0 = fmaf(ov, wr[0], a0);
    a1 = fmaf(ov, wr[1], a1);
  }
  a0 += bproj[c0]; a1 += bproj[c0 + 1];
  float sm = a0 + a1, sq = a0 * a0 + a1 * a1;
  #pragma unroll
  for (int off = 32; off; off >>= 1){
    sm += __shfl_xor(sm, off, 64);
    sq += __shfl_xor(sq, off, 64);
  }
  int w = tid >> 6, lane = tid & 63;
  if (lane == 0){ wred[w * 2] = sm; wred[w * 2 + 1] = sq; }
  __syncthreads();
  sm = wred[0] + wred[2] + wred[4] + wred[6];
  sq = wred[1] + wred[3] + wred[5] + wred[7];
  float mean = sm * (1.f / 512.f);
  float var = sq * (1.f / 512.f) - mean * mean;
  float rstd = rsqrtf(var + 1e-5f);
  hrow[c0]     = (a0 - mean) * rstd * g2[c0]     + b2v[c0];
  hrow[c0 + 1] = (a1 - mean) * rstd * g2[c0 + 1] + b2v[c0 + 1];
  __syncthreads();
  float h0 = 0.f, h1 = 0.f;
  for (int dd = 0; dd < DIM; ++dd){
    float lv = hrow[dd];
    const float* wr = Wc1 + (size_t)dd * DIM + c0;
    h0 = fmaf(lv, wr[0], h0);
    h1 = fmaf(lv, wr[1], h1);
  }
  h0 += bc1[c0]; h1 += bc1[c0 + 1];
  h0 = h0 > 0.f ? h0 : 0.f;
  h1 = h1 > 0.f ? h1 : 0.f;
  float p = h0 * Wc2[c0] + h1 * Wc2[c0 + 1];
  #pragma unroll
  for (int off = 32; off; off >>= 1) p += __shfl_xor(p, off, 64);
  if (lane == 0) wred2[w] = p;
  __syncthreads();
  if (tid == 0) logits[row] = wred2[0] + wred2[1] + wred2[2] + wred2[3] + bc2[0];
}

extern "C" void kernel_launch(void* const* d_in, const int* in_sizes, int n_in,
                              void* d_out, int out_size, void* d_ws, size_t ws_size,
                              hipStream_t stream) {
  const float* x     = (const float*)d_in[0];
  const float* wave1 = (const float*)d_in[1];
  const float* wave2 = (const float*)d_in[2];
  const float* wave3 = (const float*)d_in[3];
  const float* Wp1   = (const float*)d_in[4];
  const float* bp1   = (const float*)d_in[5];
  const float* cls   = (const float*)d_in[6];
  const float* ln1g  = (const float*)d_in[7];
  const float* ln1b  = (const float*)d_in[8];
  const float* Wq    = (const float*)d_in[9];
  const float* Wkv   = (const float*)d_in[10];
  const float* Wproj = (const float*)d_in[11];
  const float* bproj = (const float*)d_in[12];
  const float* ln2g  = (const float*)d_in[13];
  const float* ln2b  = (const float*)d_in[14];
  const float* Wc1   = (const float*)d_in[15];
  const float* bc1   = (const float*)d_in[16];
  const float* Wc2   = (const float*)d_in[17];
  const float* bc2   = (const float*)d_in[18];

  float* out = (float*)d_out;
  float* logits = out;
  float* attn   = out + 64;

  unsigned char* ws = (unsigned char*)d_ws;
  float* ksum           = (float*)(ws);
  float* qws            = (float*)(ws + (64u << 10));
  unsigned short* Wp1T  = (unsigned short*)(ws + (128u << 10));
  unsigned short* GvT   = (unsigned short*)(ws + (640u << 10));
  unsigned short* AqT   = (unsigned short*)(ws + (1152u << 10));
  float* Aqb            = (float*)(ws + (1184u << 10));
  float* gv             = (float*)(ws + (1248u << 10));
  float* bv             = (float*)(ws + (1252u << 10));
  float* ga             = (float*)(ws + (1256u << 10));
  float* ba             = (float*)(ws + (1260u << 10));
  float* statM          = (float*)(ws + (1264u << 10));
  float* statS          = (float*)(ws + (1520u << 10));
  float* o_part         = (float*)(ws + (1776u << 10));
  float* stat_part      = (float*)(ws + (4096u << 10));
  unsigned short* pos   = (unsigned short*)(ws + (8ull << 20));
  unsigned short* yb    = (unsigned short*)(ws + (72ull << 20));

  prep1_kernel<<<dim3(134), dim3(256), 0, stream>>>(wave1, wave2, wave3, ksum,
                                                    cls, Wq, qws, Wp1, Wp1T, Wkv, ln1g, GvT);
  prep2_kernel<<<dim3(64), dim3(256), 0, stream>>>(Wkv, qws, Aqb);
  prep3_kernel<<<dim3(67), dim3(256), 0, stream>>>(Aqb, ln1g, ln1b, Wkv, AqT, gv, bv, ga, ba);
  conv_kernel<<<dim3(4096), dim3(256), 0, stream>>>(x, ksum, pos);
  gemm1_kernel<<<dim3(2048), dim3(256), 0, stream>>>(pos, Wp1T, x, bp1, yb, stat_part);
  statfin_kernel<<<dim3(256), dim3(256), 0, stream>>>(stat_part, statM, statS);
  stage2_kernel<<<dim3(2048), dim3(256), 0, stream>>>(yb, GvT, AqT, statM, statS,
                                                      gv, bv, ga, ba, attn, o_part);
  head_kernel<<<dim3(64), dim3(256), 0, stream>>>(o_part, Wproj, bproj, ln2g, ln2b,
                                                  Wc1, bc1, Wc2, bc2, logits);
}

// Round 5
// 312.200 us; speedup vs baseline: 1.4996x; 1.0495x over previous
//
#include <hip/hip_runtime.h>

#define SEQ 2048
#define DIM 512
#define NBATCH 32
#define NH 16
#define HDIM 32
#define NCLS 2

typedef __attribute__((ext_vector_type(8))) short short8;
typedef __attribute__((ext_vector_type(8))) unsigned short ushort8;
typedef __attribute__((ext_vector_type(4))) float f32x4;

__device__ __forceinline__ float b2f(unsigned short u){
  union { unsigned int i; float f; } v; v.i = ((unsigned int)u) << 16; return v.f;
}
__device__ __forceinline__ unsigned short f2b(float f){
  unsigned int x = __float_as_uint(f);
  unsigned int r = (x + 0x7fffu + ((x >> 16) & 1u)) >> 16;
  return (unsigned short)r;
}
__device__ __forceinline__ void gload16(const void* g, void* l){
  __builtin_amdgcn_global_load_lds((const __attribute__((address_space(1))) void*)g,
                                   (__attribute__((address_space(3))) void*)l, 16, 0, 0);
}

// ---------------- prep1: wavelet ksum | q = cls@Wq | Wp1T | GvT ----------------
__global__ __launch_bounds__(256) void prep1_kernel(
    const float* __restrict__ w1, const float* __restrict__ w2, const float* __restrict__ w3,
    float* __restrict__ ksum,
    const float* __restrict__ cls, const float* __restrict__ Wq, float* __restrict__ qws,
    const float* __restrict__ Wp1, unsigned short* __restrict__ Wp1T,
    const float* __restrict__ Wkv, const float* __restrict__ g1, unsigned short* __restrict__ GvT){
  __shared__ unsigned short t[64][65];
  int bid = blockIdx.x;
  int tid = threadIdx.x;
  if (bid < 2){
    int d = bid * 256 + tid;
    const float C = 0.86732501f;
    float acc[19];
    #pragma unroll
    for (int i = 0; i < 19; ++i) acc[i] = 0.f;
    const float* waves[3] = { w1, w2, w3 };
    for (int tt = 0; tt < 3; ++tt){
      float scale = waves[tt][d];
      float shift = waves[tt][DIM + d];
      float inv = 1.f / scale;
      float amp = C * rsqrtf(fabsf(scale));
      #pragma unroll
      for (int i = 0; i < 19; ++i){
        float u = ((float)(i - 9) - shift) * inv;
        acc[i] += amp * (1.f - u * u) * expf(-0.5f * u * u);
      }
    }
    #pragma unroll
    for (int i = 0; i < 19; ++i) ksum[i * DIM + d] = acc[i];
  } else if (bid < 6){
    int idx = (bid - 2) * 256 + tid;
    int n = idx >> 9, c = idx & 511;
    float s = 0.f;
    for (int kd = 0; kd < DIM; ++kd)
      s = fmaf(cls[n * DIM + kd], Wq[(size_t)kd * DIM + c], s);
    qws[n * DIM + c] = s;
  } else if (bid < 70){
    int bx = bid - 6;
    int c0 = (bx & 7) * 64, r0 = (bx >> 3) * 64;
    #pragma unroll
    for (int i = 0; i < 16; ++i){
      int idx = i * 256 + tid;
      int r = idx >> 6, c = idx & 63;
      t[c][r] = f2b(Wp1[(size_t)(r0 + r) * 512 + c0 + c]);
    }
    __syncthreads();
    #pragma unroll
    for (int i = 0; i < 16; ++i){
      int idx = i * 256 + tid;
      int r = idx >> 6, c = idx & 63;
      Wp1T[(size_t)(c0 + r) * 512 + r0 + c] = t[r][c];
    }
  } else {
    int bx = bid - 70;
    int c0 = (bx & 7) * 64, r0 = (bx >> 3) * 64;
    #pragma unroll
    for (int i = 0; i < 16; ++i){
      int idx = i * 256 + tid;
      int r = idx >> 6, c = idx & 63;
      t[c][r] = f2b(Wkv[(size_t)(r0 + r) * 1024 + 512 + c0 + c] * g1[r0 + r]);
    }
    __syncthreads();
    #pragma unroll
    for (int i = 0; i < 16; ++i){
      int idx = i * 256 + tid;
      int r = idx >> 6, c = idx & 63;
      GvT[(size_t)(c0 + r) * 512 + r0 + c] = t[r][c];
    }
  }
}

// ---------------- prep2: Aq_basic[d][hn] ----------------
__global__ __launch_bounds__(256) void prep2_kernel(const float* __restrict__ Wkv,
    const float* __restrict__ qws, float* __restrict__ Aqb){
  int idx = blockIdx.x * 256 + threadIdx.x;   // 16384
  int d = idx >> 5, hn = idx & 31;
  int h = hn >> 1, n = hn & 1;
  float s = 0.f;
  #pragma unroll
  for (int hd = 0; hd < 32; ++hd)
    s = fmaf(Wkv[(size_t)d * 1024 + h * 32 + hd], qws[n * 512 + h * 32 + hd], s);
  Aqb[d * 32 + hn] = s;
}

// ---------------- prep3: AqT | gv,bv,ga,ba ----------------
__global__ __launch_bounds__(256) void prep3_kernel(const float* __restrict__ Aqb,
    const float* __restrict__ g1, const float* __restrict__ b1,
    const float* __restrict__ Wkv, unsigned short* __restrict__ AqT,
    float* __restrict__ gv, float* __restrict__ bv,
    float* __restrict__ ga, float* __restrict__ ba){
  int bid = blockIdx.x;
  if (bid < 64){
    int idx = bid * 256 + threadIdx.x;
    int hn = idx >> 9, d = idx & 511;
    AqT[hn * 512 + d] = f2b(0.17677669529663687f * g1[d] * Aqb[d * 32 + hn]);
  } else {
    int tid = (bid - 64) * 256 + threadIdx.x;
    if (tid < 512){
      float s1 = 0.f, s2 = 0.f;
      for (int d = 0; d < 512; ++d){
        float wv = Wkv[(size_t)d * 1024 + 512 + tid];
        s1 = fmaf(g1[d], wv, s1);
        s2 = fmaf(b1[d], wv, s2);
      }
      gv[tid] = s1; bv[tid] = s2;
    } else if (tid < 544){
      int hn = tid - 512;
      float s1 = 0.f, s2 = 0.f;
      for (int d = 0; d < 512; ++d){
        float a = Aqb[d * 32 + hn];
        s1 = fmaf(g1[d], a, s1);
        s2 = fmaf(b1[d], a, s2);
      }
      ga[hn] = 0.17677669529663687f * s1;
      ba[hn] = 0.17677669529663687f * s2 - 7.6246189861593985f;
    }
  }
}

// ---------------- conv: sliding-window FIR ----------------
template<bool EDGE>
__device__ __forceinline__ void conv_strip(const float* __restrict__ xb,
    const float* __restrict__ ksum, unsigned short* __restrict__ Pos,
    int b, int s0, int d0){
  float kx[19], ky[19];
  #pragma unroll
  for (int t = 0; t < 19; ++t){
    float2 kv = *(const float2*)&ksum[t * DIM + d0];
    kx[t] = kv.x; ky[t] = kv.y;
  }
  float ox[16], oy[16];
  #pragma unroll
  for (int o = 0; o < 16; ++o){ ox[o] = 0.f; oy[o] = 0.f; }
  const float* xp = xb + (size_t)(s0 - 9) * DIM + d0;
  #pragma unroll
  for (int bi = 0; bi < 5; ++bi){
    float xvx[8], xvy[8];
    #pragma unroll
    for (int j = 0; j < 8; ++j){
      int w = bi * 8 + j;
      if (w < 34){
        if (EDGE){
          int s = s0 - 9 + w;
          int sc = s < 0 ? 0 : (s > SEQ - 1 ? SEQ - 1 : s);
          float2 tv = *(const float2*)&xb[(size_t)sc * DIM + d0];
          bool ok = (s >= 0) && (s < SEQ);
          xvx[j] = ok ? tv.x : 0.f;
          xvy[j] = ok ? tv.y : 0.f;
        } else {
          float2 tv = *(const float2*)&xp[(size_t)w * DIM];
          xvx[j] = tv.x; xvy[j] = tv.y;
        }
      }
    }
    #pragma unroll
    for (int j = 0; j < 8; ++j){
      int w = bi * 8 + j;
      if (w < 34){
        #pragma unroll
        for (int o = 0; o < 16; ++o){
          int t2 = w - o;
          if (t2 >= 0 && t2 < 19){
            ox[o] = fmaf(xvx[j], kx[t2], ox[o]);
            oy[o] = fmaf(xvy[j], ky[t2], oy[o]);
          }
        }
      }
    }
  }
  #pragma unroll
  for (int o = 0; o < 16; ++o){
    unsigned int packed = (unsigned int)f2b(ox[o]) | ((unsigned int)f2b(oy[o]) << 16);
    *(unsigned int*)&Pos[((size_t)(b * SEQ + s0 + o)) * DIM + d0] = packed;
  }
}

__global__ __launch_bounds__(256) void conv_kernel(const float* __restrict__ X,
    const float* __restrict__ ksum, unsigned short* __restrict__ Pos){
  int id = blockIdx.x;                       // 4096
  int id2 = (id & 7) * 512 + (id >> 3);
  int b = id2 >> 7;
  int strip = id2 & 127;
  int s0 = strip * 16;
  int d0 = threadIdx.x * 2;
  const float* xb = X + ((size_t)b * SEQ) * DIM;
  if (strip == 0 || strip == 127)
    conv_strip<true>(xb, ksum, Pos, b, s0, d0);
  else
    conv_strip<false>(xb, ksum, Pos, b, s0, d0);
}

// ---------------- GEMM1: 256x128 tile, dbuf pipelined, residual + stat partials --------
__global__ __launch_bounds__(512) void gemm1_kernel(const unsigned short* __restrict__ A,
    const unsigned short* __restrict__ Bt, const float* __restrict__ Xres,
    const float* __restrict__ bias, unsigned short* __restrict__ Out,
    float* __restrict__ stat_part){
  __shared__ unsigned short lA[2 * 16384];   // 2 x 256x64 bf16 = 64 KB
  __shared__ unsigned short lB[2 * 8192];    // 2 x 128x64 bf16 = 32 KB
  __shared__ float sred[256][2][2];
  int tid = threadIdx.x;
  int w = tid >> 6, lane = tid & 63;
  int wm = w >> 1, wn = w & 1;               // wm 0..3 (64-row blocks), wn 0..1
  int q = lane >> 4, cl = lane & 15;
  int id = blockIdx.x;                        // 1024
  int nid = (id & 7) * 128 + (id >> 3);       // XCD-bijective
  int nch = nid & 3;
  size_t mBase = (size_t)(nid >> 2) * 256;
  int nBase = nch * 128;

  auto stage = [&](int buf, int k0){
    int bA = buf * 16384;
    #pragma unroll
    for (int p = 0; p < 4; ++p){
      int ee = p * 4096 + tid * 8;
      int row = ee >> 6, col = ee & 63;
      gload16(A + (mBase + row) * 512 + k0 + col, &lA[bA + ee]);
    }
    int bB = buf * 8192;
    #pragma unroll
    for (int p = 0; p < 2; ++p){
      int ee = p * 4096 + tid * 8;
      int row = ee >> 6, col = ee & 63;
      gload16(Bt + (size_t)(nBase + row) * 512 + k0 + col, &lB[bB + ee]);
    }
  };

  f32x4 acc[4][4] = {};
  stage(0, 0);
  __syncthreads();
  int cur = 0;
  for (int t = 0; t < 8; ++t){
    if (t < 7) stage(cur ^ 1, (t + 1) * 64);
    const unsigned short* cA = &lA[cur * 16384];
    const unsigned short* cB = &lB[cur * 8192];
    #pragma unroll
    for (int kk = 0; kk < 2; ++kk){
      short8 af[4], bfr[4];
      #pragma unroll
      for (int m = 0; m < 4; ++m)
        af[m] = *(const short8*)&cA[(wm * 64 + m * 16 + cl) * 64 + kk * 32 + q * 8];
      #pragma unroll
      for (int n = 0; n < 4; ++n)
        bfr[n] = *(const short8*)&cB[(wn * 64 + n * 16 + cl) * 64 + kk * 32 + q * 8];
      #pragma unroll
      for (int m = 0; m < 4; ++m){
        #pragma unroll
        for (int n = 0; n < 4; ++n)
          acc[m][n] = __builtin_amdgcn_mfma_f32_16x16x32_bf16(af[m], bfr[n], acc[m][n], 0, 0, 0);
      }
    }
    __syncthreads();
    cur ^= 1;
  }
  #pragma unroll
  for (int m = 0; m < 4; ++m){
    #pragma unroll
    for (int j = 0; j < 4; ++j){
      int rl = wm * 64 + m * 16 + q * 4 + j;
      size_t row = mBase + rl;
      float sm = 0.f, sq = 0.f;
      #pragma unroll
      for (int n = 0; n < 4; ++n){
        int col = nBase + wn * 64 + n * 16 + cl;
        float v = acc[m][n][j] + Xres[row * DIM + col] + bias[col];
        Out[row * DIM + col] = f2b(v);
        sm += v; sq += v * v;
      }
      #pragma unroll
      for (int off = 1; off < 16; off <<= 1){
        sm += __shfl_xor(sm, off, 64);
        sq += __shfl_xor(sq, off, 64);
      }
      if (cl == 0){ sred[rl][wn][0] = sm; sred[rl][wn][1] = sq; }
    }
  }
  __syncthreads();
  if (tid < 256){
    float sm = sred[tid][0][0] + sred[tid][1][0];
    float sq = sred[tid][0][1] + sred[tid][1][1];
    stat_part[((mBase + tid) * 4 + nch) * 2 + 0] = sm;
    stat_part[((mBase + tid) * 4 + nch) * 2 + 1] = sq;
  }
}

// ---------------- stage2: dbuf pipelined; v + scores + attn + PV partials --------------
__global__ __launch_bounds__(256) void stage2_kernel(
    const unsigned short* __restrict__ Y, const unsigned short* __restrict__ GvT,
    const unsigned short* __restrict__ AqT, const float* __restrict__ stat_part,
    const float* __restrict__ gv, const float* __restrict__ bv,
    const float* __restrict__ ga, const float* __restrict__ ba,
    float* __restrict__ aout, float* __restrict__ o_part){
  __shared__ __align__(16) char smem[66560];
  unsigned short* lA = (unsigned short*)smem;               // 2 x 16 KB
  unsigned short* lB = (unsigned short*)(smem + 32768);     // 2 x 16 KB
  float* stats = (float*)(smem + 65536);                    // 128*2*4 = 1024
  float* attn_lds = (float*)smem;                           // overlay (after loop)
  float* o_red = (float*)(smem + 16896);                    // overlay
  int tid = threadIdx.x;
  int w = tid >> 6, lane = tid & 63;
  int wm = w >> 1, wn = w & 1;
  int q = lane >> 4, cl = lane & 15;
  int id = blockIdx.x;
  int nid = (id & 7) * 256 + (id >> 3);
  int nch = nid & 3;
  int mb = nid >> 2;
  size_t mBase = (size_t)mb * 128;
  int nBase = nch * 128;

  auto stage = [&](int buf, int k0){
    #pragma unroll
    for (int p = 0; p < 4; ++p){
      int ee = p * 2048 + tid * 8;
      int row = ee >> 6, col = ee & 63;
      gload16(Y + (mBase + row) * 512 + k0 + col, &lA[buf * 8192 + ee]);
      gload16(GvT + (size_t)(nBase + row) * 512 + k0 + col, &lB[buf * 8192 + ee]);
    }
  };

  stage(0, 0);
  if (tid < 128){
    float sm = 0.f, sq = 0.f;
    #pragma unroll
    for (int i = 0; i < 4; ++i){
      sm += stat_part[((mBase + tid) * 4 + i) * 2 + 0];
      sq += stat_part[((mBase + tid) * 4 + i) * 2 + 1];
    }
    float mean = sm * (1.f / 512.f);
    float var = sq * (1.f / 512.f) - mean * mean;
    stats[tid * 2 + 0] = mean;
    stats[tid * 2 + 1] = rsqrtf(var + 1e-5f);
  }
  __syncthreads();

  int hn = wn * 16 + cl;
  f32x4 acc[4][4] = {};
  f32x4 accs[4] = {};
  int cur = 0;
  for (int t = 0; t < 8; ++t){
    if (t < 7) stage(cur ^ 1, (t + 1) * 64);
    int k0 = t * 64;
    const unsigned short* cA = &lA[cur * 8192];
    const unsigned short* cB = &lB[cur * 8192];
    #pragma unroll
    for (int kk = 0; kk < 2; ++kk){
      short8 af[4], bfr[4], bq;
      bq = *(const short8*)&AqT[hn * 512 + k0 + kk * 32 + q * 8];
      #pragma unroll
      for (int m = 0; m < 4; ++m)
        af[m] = *(const short8*)&cA[(wm * 64 + m * 16 + cl) * 64 + kk * 32 + q * 8];
      #pragma unroll
      for (int n = 0; n < 4; ++n)
        bfr[n] = *(const short8*)&cB[(wn * 64 + n * 16 + cl) * 64 + kk * 32 + q * 8];
      #pragma unroll
      for (int m = 0; m < 4; ++m){
        #pragma unroll
        for (int n = 0; n < 4; ++n)
          acc[m][n] = __builtin_amdgcn_mfma_f32_16x16x32_bf16(af[m], bfr[n], acc[m][n], 0, 0, 0);
        accs[m] = __builtin_amdgcn_mfma_f32_16x16x32_bf16(af[m], bq, accs[m], 0, 0, 0);
      }
    }
    __syncthreads();
    cur ^= 1;
  }
  // epilogue
  float gav = ga[hn], bav = ba[hn];
  float gv4[4], bv4[4];
  #pragma unroll
  for (int n = 0; n < 4; ++n){
    int cg = nBase + wn * 64 + n * 16 + cl;
    gv4[n] = gv[cg]; bv4[n] = bv[cg];
  }
  int b = mb >> 4;
  int scb = (mb & 15) * 128;
  float st[8];
  #pragma unroll
  for (int m = 0; m < 4; ++m){
    #pragma unroll
    for (int j = 0; j < 4; ++j){
      int rl = wm * 64 + m * 16 + q * 4 + j;
      st[0] = stats[rl * 2 + 0]; st[1] = stats[rl * 2 + 1];
      float mu = st[0], s = st[1];
      float sc = s * accs[m][j] - s * mu * gav + bav;
      float at = 1.f / (1.f + expf(-sc));
      attn_lds[rl * 33 + hn] = at;
      if (nch == 0)
        aout[((size_t)(b * NH + (hn >> 1)) * NCLS + (hn & 1)) * SEQ + scb + rl] = at;
      #pragma unroll
      for (int n = 0; n < 4; ++n)
        acc[m][n][j] = s * acc[m][n][j] - s * mu * gv4[n] + bv4[n];
    }
  }
  __syncthreads();
  float o0[4] = {}, o1[4] = {};
  #pragma unroll
  for (int n = 0; n < 4; ++n){
    int cg = nBase + wn * 64 + n * 16 + cl;
    int h2 = ((cg >> 5) << 1);
    #pragma unroll
    for (int m = 0; m < 4; ++m){
      #pragma unroll
      for (int j = 0; j < 4; ++j){
        int rl = wm * 64 + m * 16 + q * 4 + j;
        float vv = acc[m][n][j];
        o0[n] = fmaf(attn_lds[rl * 33 + h2 + 0], vv, o0[n]);
        o1[n] = fmaf(attn_lds[rl * 33 + h2 + 1], vv, o1[n]);
      }
    }
  }
  #pragma unroll
  for (int n = 0; n < 4; ++n){
    o0[n] += __shfl_xor(o0[n], 16, 64);
    o0[n] += __shfl_xor(o0[n], 32, 64);
    o1[n] += __shfl_xor(o1[n], 16, 64);
    o1[n] += __shfl_xor(o1[n], 32, 64);
  }
  if (q == 0){
    #pragma unroll
    for (int n = 0; n < 4; ++n){
      int c = wn * 64 + n * 16 + cl;
      o_red[(0 * 2 + wm) * 128 + c] = o0[n];
      o_red[(1 * 2 + wm) * 128 + c] = o1[n];
    }
  }
  __syncthreads();
  {
    int nn = tid >> 7, c = tid & 127;
    float v = o_red[(nn * 2 + 0) * 128 + c] + o_red[(nn * 2 + 1) * 128 + c];
    o_part[((size_t)mb * 2 + nn) * 512 + nBase + c] = v;
  }
}

// ---------------- Head ----------------
__global__ __launch_bounds__(256) void head_kernel(const float* __restrict__ o_part,
    const float* __restrict__ Wproj, const float* __restrict__ bproj,
    const float* __restrict__ g2, const float* __restrict__ b2v,
    const float* __restrict__ Wc1, const float* __restrict__ bc1,
    const float* __restrict__ Wc2, const float* __restrict__ bc2,
    float* __restrict__ logits){
  __shared__ float orow[512];
  __shared__ float hrow[512];
  __shared__ float wred[8];
  __shared__ float wred2[4];
  int tid = threadIdx.x;
  int row = blockIdx.x;
  int b = row >> 1, nn = row & 1;
  for (int i = tid; i < 512; i += 256){
    float s = 0.f;
    const float* op = o_part + (((size_t)b * 16) * 2 + nn) * 512 + i;
    #pragma unroll
    for (int sc = 0; sc < 16; ++sc) s += op[(size_t)sc * 1024];
    orow[i] = s;
  }
  __syncthreads();
  int c0 = tid * 2;
  float a0 = 0.f, a1 = 0.f;
  for (int dd = 0; dd < DIM; ++dd){
    float ov = orow[dd];
    const float* wr = Wproj + (size_t)dd * DIM + c0;
    a0 = fmaf(ov, wr[0], a0);
    a1 = fmaf(ov, wr[1], a1);
  }
  a0 += bproj[c0]; a1 += bproj[c0 + 1];
  float sm = a0 + a1, sq = a0 * a0 + a1 * a1;
  #pragma unroll
  for (int off = 32; off; off >>= 1){
    sm += __shfl_xor(sm, off, 64);
    sq += __shfl_xor(sq, off, 64);
  }
  int w = tid >> 6, lane = tid & 63;
  if (lane == 0){ wred[w * 2] = sm; wred[w * 2 + 1] = sq; }
  __syncthreads();
  sm = wred[0] + wred[2] + wred[4] + wred[6];
  sq = wred[1] + wred[3] + wred[5] + wred[7];
  float mean = sm * (1.f / 512.f);
  float var = sq * (1.f / 512.f) - mean * mean;
  float rstd = rsqrtf(var + 1e-5f);
  hrow[c0]     = (a0 - mean) * rstd * g2[c0]     + b2v[c0];
  hrow[c0 + 1] = (a1 - mean) * rstd * g2[c0 + 1] + b2v[c0 + 1];
  __syncthreads();
  float h0 = 0.f, h1 = 0.f;
  for (int dd = 0; dd < DIM; ++dd){
    float lv = hrow[dd];
    const float* wr = Wc1 + (size_t)dd * DIM + c0;
    h0 = fmaf(lv, wr[0], h0);
    h1 = fmaf(lv, wr[1], h1);
  }
  h0 += bc1[c0]; h1 += bc1[c0 + 1];
  h0 = h0 > 0.f ? h0 : 0.f;
  h1 = h1 > 0.f ? h1 : 0.f;
  float p = h0 * Wc2[c0] + h1 * Wc2[c0 + 1];
  #pragma unroll
  for (int off = 32; off; off >>= 1) p += __shfl_xor(p, off, 64);
  if (lane == 0) wred2[w] = p;
  __syncthreads();
  if (tid == 0) logits[row] = wred2[0] + wred2[1] + wred2[2] + wred2[3] + bc2[0];
}

extern "C" void kernel_launch(void* const* d_in, const int* in_sizes, int n_in,
                              void* d_out, int out_size, void* d_ws, size_t ws_size,
                              hipStream_t stream) {
  const float* x     = (const float*)d_in[0];
  const float* wave1 = (const float*)d_in[1];
  const float* wave2 = (const float*)d_in[2];
  const float* wave3 = (const float*)d_in[3];
  const float* Wp1   = (const float*)d_in[4];
  const float* bp1   = (const float*)d_in[5];
  const float* cls   = (const float*)d_in[6];
  const float* ln1g  = (const float*)d_in[7];
  const float* ln1b  = (const float*)d_in[8];
  const float* Wq    = (const float*)d_in[9];
  const float* Wkv   = (const float*)d_in[10];
  const float* Wproj = (const float*)d_in[11];
  const float* bproj = (const float*)d_in[12];
  const float* ln2g  = (const float*)d_in[13];
  const float* ln2b  = (const float*)d_in[14];
  const float* Wc1   = (const float*)d_in[15];
  const float* bc1   = (const float*)d_in[16];
  const float* Wc2   = (const float*)d_in[17];
  const float* bc2   = (const float*)d_in[18];

  float* out = (float*)d_out;
  float* logits = out;
  float* attn   = out + 64;

  unsigned char* ws = (unsigned char*)d_ws;
  float* ksum           = (float*)(ws);
  float* qws            = (float*)(ws + (64u << 10));
  unsigned short* Wp1T  = (unsigned short*)(ws + (128u << 10));
  unsigned short* GvT   = (unsigned short*)(ws + (640u << 10));
  unsigned short* AqT   = (unsigned short*)(ws + (1152u << 10));
  float* Aqb            = (float*)(ws + (1184u << 10));
  float* gv             = (float*)(ws + (1248u << 10));
  float* bv             = (float*)(ws + (1252u << 10));
  float* ga             = (float*)(ws + (1256u << 10));
  float* ba             = (float*)(ws + (1260u << 10));
  float* o_part         = (float*)(ws + (1776u << 10));
  float* stat_part      = (float*)(ws + (4096u << 10));
  unsigned short* pos   = (unsigned short*)(ws + (8ull << 20));
  unsigned short* yb    = (unsigned short*)(ws + (72ull << 20));

  prep1_kernel<<<dim3(134), dim3(256), 0, stream>>>(wave1, wave2, wave3, ksum,
                                                    cls, Wq, qws, Wp1, Wp1T, Wkv, ln1g, GvT);
  prep2_kernel<<<dim3(64), dim3(256), 0, stream>>>(Wkv, qws, Aqb);
  prep3_kernel<<<dim3(67), dim3(256), 0, stream>>>(Aqb, ln1g, ln1b, Wkv, AqT, gv, bv, ga, ba);
  conv_kernel<<<dim3(4096), dim3(256), 0, stream>>>(x, ksum, pos);
  gemm1_kernel<<<dim3(1024), dim3(512), 0, stream>>>(pos, Wp1T, x, bp1, yb, stat_part);
  stage2_kernel<<<dim3(2048), dim3(256), 0, stream>>>(yb, GvT, AqT, stat_part,
                                                      gv, bv, ga, ba, attn, o_part);
  head_kernel<<<dim3(64), dim3(256), 0, stream>>>(o_part, Wproj, bproj, ln2g, ln2b,
                                                  Wc1, bc1, Wc2, bc2, logits);
}

// Round 6
// 309.051 us; speedup vs baseline: 1.5149x; 1.0102x over previous
//
#include <hip/hip_runtime.h>

#define SEQ 2048
#define DIM 512
#define NBATCH 32
#define NH 16
#define HDIM 32
#define NCLS 2

typedef __attribute__((ext_vector_type(8))) short short8;
typedef __attribute__((ext_vector_type(8))) unsigned short ushort8;
typedef __attribute__((ext_vector_type(4))) float f32x4;

__device__ __forceinline__ float b2f(unsigned short u){
  union { unsigned int i; float f; } v; v.i = ((unsigned int)u) << 16; return v.f;
}
__device__ __forceinline__ unsigned short f2b(float f){
  unsigned int x = __float_as_uint(f);
  unsigned int r = (x + 0x7fffu + ((x >> 16) & 1u)) >> 16;
  return (unsigned short)r;
}
__device__ __forceinline__ void gload16(const void* g, void* l){
  __builtin_amdgcn_global_load_lds((const __attribute__((address_space(1))) void*)g,
                                   (__attribute__((address_space(3))) void*)l, 16, 0, 0);
}

// ---------------- prep1: wavelet ksum | q = cls@Wq | Wp1T | GvT ----------------
__global__ __launch_bounds__(256) void prep1_kernel(
    const float* __restrict__ w1, const float* __restrict__ w2, const float* __restrict__ w3,
    float* __restrict__ ksum,
    const float* __restrict__ cls, const float* __restrict__ Wq, float* __restrict__ qws,
    const float* __restrict__ Wp1, unsigned short* __restrict__ Wp1T,
    const float* __restrict__ Wkv, const float* __restrict__ g1, unsigned short* __restrict__ GvT){
  __shared__ unsigned short t[64][65];
  int bid = blockIdx.x;
  int tid = threadIdx.x;
  if (bid < 2){
    int d = bid * 256 + tid;
    const float C = 0.86732501f;
    float acc[19];
    #pragma unroll
    for (int i = 0; i < 19; ++i) acc[i] = 0.f;
    const float* waves[3] = { w1, w2, w3 };
    for (int tt = 0; tt < 3; ++tt){
      float scale = waves[tt][d];
      float shift = waves[tt][DIM + d];
      float inv = 1.f / scale;
      float amp = C * rsqrtf(fabsf(scale));
      #pragma unroll
      for (int i = 0; i < 19; ++i){
        float u = ((float)(i - 9) - shift) * inv;
        acc[i] += amp * (1.f - u * u) * expf(-0.5f * u * u);
      }
    }
    #pragma unroll
    for (int i = 0; i < 19; ++i) ksum[i * DIM + d] = acc[i];
  } else if (bid < 6){
    int idx = (bid - 2) * 256 + tid;
    int n = idx >> 9, c = idx & 511;
    float s = 0.f;
    for (int kd = 0; kd < DIM; ++kd)
      s = fmaf(cls[n * DIM + kd], Wq[(size_t)kd * DIM + c], s);
    qws[n * DIM + c] = s;
  } else if (bid < 70){
    int bx = bid - 6;
    int c0 = (bx & 7) * 64, r0 = (bx >> 3) * 64;
    #pragma unroll
    for (int i = 0; i < 16; ++i){
      int idx = i * 256 + tid;
      int r = idx >> 6, c = idx & 63;
      t[c][r] = f2b(Wp1[(size_t)(r0 + r) * 512 + c0 + c]);
    }
    __syncthreads();
    #pragma unroll
    for (int i = 0; i < 16; ++i){
      int idx = i * 256 + tid;
      int r = idx >> 6, c = idx & 63;
      Wp1T[(size_t)(c0 + r) * 512 + r0 + c] = t[r][c];
    }
  } else {
    int bx = bid - 70;
    int c0 = (bx & 7) * 64, r0 = (bx >> 3) * 64;
    #pragma unroll
    for (int i = 0; i < 16; ++i){
      int idx = i * 256 + tid;
      int r = idx >> 6, c = idx & 63;
      t[c][r] = f2b(Wkv[(size_t)(r0 + r) * 1024 + 512 + c0 + c] * g1[r0 + r]);
    }
    __syncthreads();
    #pragma unroll
    for (int i = 0; i < 16; ++i){
      int idx = i * 256 + tid;
      int r = idx >> 6, c = idx & 63;
      GvT[(size_t)(c0 + r) * 512 + r0 + c] = t[r][c];
    }
  }
}

// ---------------- prep2: AqT direct | ga/ba | gv/bv  (Aqb eliminated) ----------------
__global__ __launch_bounds__(256) void prep2_kernel(const float* __restrict__ Wkv,
    const float* __restrict__ qws, const float* __restrict__ g1, const float* __restrict__ b1,
    unsigned short* __restrict__ AqT, float* __restrict__ gv, float* __restrict__ bv,
    float* __restrict__ ga, float* __restrict__ ba){
  const float SCALE = 0.17677669529663687f;
  const float LOGS  = 7.6246189861593985f;
  int bid = blockIdx.x;
  int tid = threadIdx.x;
  if (bid < 64){
    // AqT[hn][d] = SCALE * g1[d] * sum_hd Wkv[d][h*32+hd] * q[n][h*32+hd]
    int idx = bid * 256 + tid;           // 16384
    int hn = idx >> 9, d = idx & 511;
    int h = hn >> 1, n = hn & 1;
    float s = 0.f;
    #pragma unroll
    for (int hd = 0; hd < 32; ++hd)
      s = fmaf(Wkv[(size_t)d * 1024 + h * 32 + hd], qws[n * 512 + h * 32 + hd], s);
    AqT[hn * 512 + d] = f2b(SCALE * g1[d] * s);
  } else if (bid < 96){
    // ga/ba[hn]: block per hn, reduce over d
    __shared__ float red[64];
    int hn = bid - 64;
    int h = hn >> 1, n = hn & 1;
    float s1 = 0.f, s2 = 0.f;
    #pragma unroll
    for (int dd = 0; dd < 2; ++dd){
      int d = tid + dd * 256;
      float inner = 0.f;
      #pragma unroll
      for (int hd = 0; hd < 32; ++hd)
        inner = fmaf(Wkv[(size_t)d * 1024 + h * 32 + hd], qws[n * 512 + h * 32 + hd], inner);
      s1 = fmaf(g1[d], inner, s1);
      s2 = fmaf(b1[d], inner, s2);
    }
    #pragma unroll
    for (int off = 32; off; off >>= 1){
      s1 += __shfl_xor(s1, off, 64);
      s2 += __shfl_xor(s2, off, 64);
    }
    int w = tid >> 6, lane = tid & 63;
    if (lane == 0){ red[w * 2] = s1; red[w * 2 + 1] = s2; }
    __syncthreads();
    if (tid == 0){
      float t1 = red[0] + red[2] + red[4] + red[6];
      float t2 = red[1] + red[3] + red[5] + red[7];
      ga[hn] = SCALE * t1;
      ba[hn] = SCALE * t2 - LOGS;
    }
  } else {
    int c = (bid - 96) * 256 + tid;      // 0..511
    float s1 = 0.f, s2 = 0.f;
    for (int d = 0; d < 512; ++d){
      float wv = Wkv[(size_t)d * 1024 + 512 + c];
      s1 = fmaf(g1[d], wv, s1);
      s2 = fmaf(b1[d], wv, s2);
    }
    gv[c] = s1; bv[c] = s2;
  }
}

// ---------------- conv: sliding-window FIR ----------------
template<bool EDGE>
__device__ __forceinline__ void conv_strip(const float* __restrict__ xb,
    const float* __restrict__ ksum, unsigned short* __restrict__ Pos,
    int b, int s0, int d0){
  float kx[19], ky[19];
  #pragma unroll
  for (int t = 0; t < 19; ++t){
    float2 kv = *(const float2*)&ksum[t * DIM + d0];
    kx[t] = kv.x; ky[t] = kv.y;
  }
  float ox[16], oy[16];
  #pragma unroll
  for (int o = 0; o < 16; ++o){ ox[o] = 0.f; oy[o] = 0.f; }
  const float* xp = xb + (size_t)(s0 - 9) * DIM + d0;
  #pragma unroll
  for (int bi = 0; bi < 5; ++bi){
    float xvx[8], xvy[8];
    #pragma unroll
    for (int j = 0; j < 8; ++j){
      int w = bi * 8 + j;
      if (w < 34){
        if (EDGE){
          int s = s0 - 9 + w;
          int sc = s < 0 ? 0 : (s > SEQ - 1 ? SEQ - 1 : s);
          float2 tv = *(const float2*)&xb[(size_t)sc * DIM + d0];
          bool ok = (s >= 0) && (s < SEQ);
          xvx[j] = ok ? tv.x : 0.f;
          xvy[j] = ok ? tv.y : 0.f;
        } else {
          float2 tv = *(const float2*)&xp[(size_t)w * DIM];
          xvx[j] = tv.x; xvy[j] = tv.y;
        }
      }
    }
    #pragma unroll
    for (int j = 0; j < 8; ++j){
      int w = bi * 8 + j;
      if (w < 34){
        #pragma unroll
        for (int o = 0; o < 16; ++o){
          int t2 = w - o;
          if (t2 >= 0 && t2 < 19){
            ox[o] = fmaf(xvx[j], kx[t2], ox[o]);
            oy[o] = fmaf(xvy[j], ky[t2], oy[o]);
          }
        }
      }
    }
  }
  #pragma unroll
  for (int o = 0; o < 16; ++o){
    unsigned int packed = (unsigned int)f2b(ox[o]) | ((unsigned int)f2b(oy[o]) << 16);
    *(unsigned int*)&Pos[((size_t)(b * SEQ + s0 + o)) * DIM + d0] = packed;
  }
}

__global__ __launch_bounds__(256) void conv_kernel(const float* __restrict__ X,
    const float* __restrict__ ksum, unsigned short* __restrict__ Pos){
  int id = blockIdx.x;                       // 4096
  int id2 = (id & 7) * 512 + (id >> 3);
  int b = id2 >> 7;
  int strip = id2 & 127;
  int s0 = strip * 16;
  int d0 = threadIdx.x * 2;
  const float* xb = X + ((size_t)b * SEQ) * DIM;
  if (strip == 0 || strip == 127)
    conv_strip<true>(xb, ksum, Pos, b, s0, d0);
  else
    conv_strip<false>(xb, ksum, Pos, b, s0, d0);
}

// ---------------- GEMM1: 128x128 dbuf pipelined, residual + stat partials --------------
__global__ __launch_bounds__(256) void gemm1_kernel(const unsigned short* __restrict__ A,
    const unsigned short* __restrict__ Bt, const float* __restrict__ Xres,
    const float* __restrict__ bias, unsigned short* __restrict__ Out,
    float* __restrict__ stat_part){
  __shared__ unsigned short lA[2 * 8192];    // 2 x 128x64 bf16 = 32 KB
  __shared__ unsigned short lB[2 * 8192];    // 32 KB
  __shared__ float sred[128][2][2];
  int tid = threadIdx.x;
  int w = tid >> 6, lane = tid & 63;
  int wm = w >> 1, wn = w & 1;
  int q = lane >> 4, cl = lane & 15;
  int id = blockIdx.x;                        // 2048
  int nid = (id & 7) * 256 + (id >> 3);       // XCD-bijective; 4 n-chunks of one m-tile adjacent
  int nch = nid & 3;
  size_t mBase = (size_t)(nid >> 2) * 128;
  int nBase = nch * 128;

  auto stage = [&](int buf, int k0){
    #pragma unroll
    for (int p = 0; p < 4; ++p){
      int ee = p * 2048 + tid * 8;
      int row = ee >> 6, col = ee & 63;
      gload16(A + (mBase + row) * 512 + k0 + col, &lA[buf * 8192 + ee]);
      gload16(Bt + (size_t)(nBase + row) * 512 + k0 + col, &lB[buf * 8192 + ee]);
    }
  };

  f32x4 acc[4][4] = {};
  stage(0, 0);
  __syncthreads();
  int cur = 0;
  for (int t = 0; t < 8; ++t){
    if (t < 7) stage(cur ^ 1, (t + 1) * 64);
    const unsigned short* cA = &lA[cur * 8192];
    const unsigned short* cB = &lB[cur * 8192];
    #pragma unroll
    for (int kk = 0; kk < 2; ++kk){
      short8 af[4], bfr[4];
      #pragma unroll
      for (int m = 0; m < 4; ++m)
        af[m] = *(const short8*)&cA[(wm * 64 + m * 16 + cl) * 64 + kk * 32 + q * 8];
      #pragma unroll
      for (int n = 0; n < 4; ++n)
        bfr[n] = *(const short8*)&cB[(wn * 64 + n * 16 + cl) * 64 + kk * 32 + q * 8];
      #pragma unroll
      for (int m = 0; m < 4; ++m){
        #pragma unroll
        for (int n = 0; n < 4; ++n)
          acc[m][n] = __builtin_amdgcn_mfma_f32_16x16x32_bf16(af[m], bfr[n], acc[m][n], 0, 0, 0);
      }
    }
    __syncthreads();
    cur ^= 1;
  }
  #pragma unroll
  for (int m = 0; m < 4; ++m){
    #pragma unroll
    for (int j = 0; j < 4; ++j){
      int rl = wm * 64 + m * 16 + q * 4 + j;
      size_t row = mBase + rl;
      float sm = 0.f, sq = 0.f;
      #pragma unroll
      for (int n = 0; n < 4; ++n){
        int col = nBase + wn * 64 + n * 16 + cl;
        float v = acc[m][n][j] + Xres[row * DIM + col] + bias[col];
        Out[row * DIM + col] = f2b(v);
        sm += v; sq += v * v;
      }
      #pragma unroll
      for (int off = 1; off < 16; off <<= 1){
        sm += __shfl_xor(sm, off, 64);
        sq += __shfl_xor(sq, off, 64);
      }
      if (cl == 0){ sred[rl][wn][0] = sm; sred[rl][wn][1] = sq; }
    }
  }
  __syncthreads();
  if (tid < 128){
    float sm = sred[tid][0][0] + sred[tid][1][0];
    float sq = sred[tid][0][1] + sred[tid][1][1];
    stat_part[((mBase + tid) * 4 + nch) * 2 + 0] = sm;
    stat_part[((mBase + tid) * 4 + nch) * 2 + 1] = sq;
  }
}

// ---------------- stage2: dbuf pipelined; v + scores + attn + PV partials --------------
__global__ __launch_bounds__(256) void stage2_kernel(
    const unsigned short* __restrict__ Y, const unsigned short* __restrict__ GvT,
    const unsigned short* __restrict__ AqT, const float* __restrict__ stat_part,
    const float* __restrict__ gv, const float* __restrict__ bv,
    const float* __restrict__ ga, const float* __restrict__ ba,
    float* __restrict__ aout, float* __restrict__ o_part){
  __shared__ __align__(16) char smem[66560];
  unsigned short* lA = (unsigned short*)smem;               // 2 x 16 KB
  unsigned short* lB = (unsigned short*)(smem + 32768);     // 2 x 16 KB
  float* stats = (float*)(smem + 65536);                    // 128*2*4 = 1024
  float* attn_lds = (float*)smem;                           // overlay (after loop)
  float* o_red = (float*)(smem + 16896);                    // overlay
  int tid = threadIdx.x;
  int w = tid >> 6, lane = tid & 63;
  int wm = w >> 1, wn = w & 1;
  int q = lane >> 4, cl = lane & 15;
  int id = blockIdx.x;
  int nid = (id & 7) * 256 + (id >> 3);
  int nch = nid & 3;
  int mb = nid >> 2;
  size_t mBase = (size_t)mb * 128;
  int nBase = nch * 128;

  auto stage = [&](int buf, int k0){
    #pragma unroll
    for (int p = 0; p < 4; ++p){
      int ee = p * 2048 + tid * 8;
      int row = ee >> 6, col = ee & 63;
      gload16(Y + (mBase + row) * 512 + k0 + col, &lA[buf * 8192 + ee]);
      gload16(GvT + (size_t)(nBase + row) * 512 + k0 + col, &lB[buf * 8192 + ee]);
    }
  };

  stage(0, 0);
  if (tid < 128){
    float sm = 0.f, sq = 0.f;
    #pragma unroll
    for (int i = 0; i < 4; ++i){
      sm += stat_part[((mBase + tid) * 4 + i) * 2 + 0];
      sq += stat_part[((mBase + tid) * 4 + i) * 2 + 1];
    }
    float mean = sm * (1.f / 512.f);
    float var = sq * (1.f / 512.f) - mean * mean;
    stats[tid * 2 + 0] = mean;
    stats[tid * 2 + 1] = rsqrtf(var + 1e-5f);
  }
  __syncthreads();

  int hn = wn * 16 + cl;
  f32x4 acc[4][4] = {};
  f32x4 accs[4] = {};
  int cur = 0;
  for (int t = 0; t < 8; ++t){
    if (t < 7) stage(cur ^ 1, (t + 1) * 64);
    int k0 = t * 64;
    const unsigned short* cA = &lA[cur * 8192];
    const unsigned short* cB = &lB[cur * 8192];
    #pragma unroll
    for (int kk = 0; kk < 2; ++kk){
      short8 af[4], bfr[4], bq;
      bq = *(const short8*)&AqT[hn * 512 + k0 + kk * 32 + q * 8];
      #pragma unroll
      for (int m = 0; m < 4; ++m)
        af[m] = *(const short8*)&cA[(wm * 64 + m * 16 + cl) * 64 + kk * 32 + q * 8];
      #pragma unroll
      for (int n = 0; n < 4; ++n)
        bfr[n] = *(const short8*)&cB[(wn * 64 + n * 16 + cl) * 64 + kk * 32 + q * 8];
      #pragma unroll
      for (int m = 0; m < 4; ++m){
        #pragma unroll
        for (int n = 0; n < 4; ++n)
          acc[m][n] = __builtin_amdgcn_mfma_f32_16x16x32_bf16(af[m], bfr[n], acc[m][n], 0, 0, 0);
        accs[m] = __builtin_amdgcn_mfma_f32_16x16x32_bf16(af[m], bq, accs[m], 0, 0, 0);
      }
    }
    __syncthreads();
    cur ^= 1;
  }
  // epilogue
  float gav = ga[hn], bav = ba[hn];
  float gv4[4], bv4[4];
  #pragma unroll
  for (int n = 0; n < 4; ++n){
    int cg = nBase + wn * 64 + n * 16 + cl;
    gv4[n] = gv[cg]; bv4[n] = bv[cg];
  }
  int b = mb >> 4;
  int scb = (mb & 15) * 128;
  #pragma unroll
  for (int m = 0; m < 4; ++m){
    #pragma unroll
    for (int j = 0; j < 4; ++j){
      int rl = wm * 64 + m * 16 + q * 4 + j;
      float mu = stats[rl * 2 + 0], s = stats[rl * 2 + 1];
      float sc = s * accs[m][j] - s * mu * gav + bav;
      float at = 1.f / (1.f + expf(-sc));
      attn_lds[rl * 33 + hn] = at;
      if (nch == 0)
        aout[((size_t)(b * NH + (hn >> 1)) * NCLS + (hn & 1)) * SEQ + scb + rl] = at;
      #pragma unroll
      for (int n = 0; n < 4; ++n)
        acc[m][n][j] = s * acc[m][n][j] - s * mu * gv4[n] + bv4[n];
    }
  }
  __syncthreads();
  float o0[4] = {}, o1[4] = {};
  #pragma unroll
  for (int n = 0; n < 4; ++n){
    int cg = nBase + wn * 64 + n * 16 + cl;
    int h2 = ((cg >> 5) << 1);
    #pragma unroll
    for (int m = 0; m < 4; ++m){
      #pragma unroll
      for (int j = 0; j < 4; ++j){
        int rl = wm * 64 + m * 16 + q * 4 + j;
        float vv = acc[m][n][j];
        o0[n] = fmaf(attn_lds[rl * 33 + h2 + 0], vv, o0[n]);
        o1[n] = fmaf(attn_lds[rl * 33 + h2 + 1], vv, o1[n]);
      }
    }
  }
  #pragma unroll
  for (int n = 0; n < 4; ++n){
    o0[n] += __shfl_xor(o0[n], 16, 64);
    o0[n] += __shfl_xor(o0[n], 32, 64);
    o1[n] += __shfl_xor(o1[n], 16, 64);
    o1[n] += __shfl_xor(o1[n], 32, 64);
  }
  if (q == 0){
    #pragma unroll
    for (int n = 0; n < 4; ++n){
      int c = wn * 64 + n * 16 + cl;
      o_red[(0 * 2 + wm) * 128 + c] = o0[n];
      o_red[(1 * 2 + wm) * 128 + c] = o1[n];
    }
  }
  __syncthreads();
  {
    int nn = tid >> 7, c = tid & 127;
    float v = o_red[(nn * 2 + 0) * 128 + c] + o_red[(nn * 2 + 1) * 128 + c];
    o_part[((size_t)mb * 2 + nn) * 512 + nBase + c] = v;
  }
}

// ---------------- Head ----------------
__global__ __launch_bounds__(256) void head_kernel(const float* __restrict__ o_part,
    const float* __restrict__ Wproj, const float* __restrict__ bproj,
    const float* __restrict__ g2, const float* __restrict__ b2v,
    const float* __restrict__ Wc1, const float* __restrict__ bc1,
    const float* __restrict__ Wc2, const float* __restrict__ bc2,
    float* __restrict__ logits){
  __shared__ float orow[512];
  __shared__ float hrow[512];
  __shared__ float wred[8];
  __shared__ float wred2[4];
  int tid = threadIdx.x;
  int row = blockIdx.x;
  int b = row >> 1, nn = row & 1;
  for (int i = tid; i < 512; i += 256){
    float s = 0.f;
    const float* op = o_part + (((size_t)b * 16) * 2 + nn) * 512 + i;
    #pragma unroll
    for (int sc = 0; sc < 16; ++sc) s += op[(size_t)sc * 1024];
    orow[i] = s;
  }
  __syncthreads();
  int c0 = tid * 2;
  float a0 = 0.f, a1 = 0.f;
  for (int dd = 0; dd < DIM; ++dd){
    float ov = orow[dd];
    const float* wr = Wproj + (size_t)dd * DIM + c0;
    a0 = fmaf(ov, wr[0], a0);
    a1 = fmaf(ov, wr[1], a1);
  }
  a0 += bproj[c0]; a1 += bproj[c0 + 1];
  float sm = a0 + a1, sq = a0 * a0 + a1 * a1;
  #pragma unroll
  for (int off = 32; off; off >>= 1){
    sm += __shfl_xor(sm, off, 64);
    sq += __shfl_xor(sq, off, 64);
  }
  int w = tid >> 6, lane = tid & 63;
  if (lane == 0){ wred[w * 2] = sm; wred[w * 2 + 1] = sq; }
  __syncthreads();
  sm = wred[0] + wred[2] + wred[4] + wred[6];
  sq = wred[1] + wred[3] + wred[5] + wred[7];
  float mean = sm * (1.f / 512.f);
  float var = sq * (1.f / 512.f) - mean * mean;
  float rstd = rsqrtf(var + 1e-5f);
  hrow[c0]     = (a0 - mean) * rstd * g2[c0]     + b2v[c0];
  hrow[c0 + 1] = (a1 - mean) * rstd * g2[c0 + 1] + b2v[c0 + 1];
  __syncthreads();
  float h0 = 0.f, h1 = 0.f;
  for (int dd = 0; dd < DIM; ++dd){
    float lv = hrow[dd];
    const float* wr = Wc1 + (size_t)dd * DIM + c0;
    h0 = fmaf(lv, wr[0], h0);
    h1 = fmaf(lv, wr[1], h1);
  }
  h0 += bc1[c0]; h1 += bc1[c0 + 1];
  h0 = h0 > 0.f ? h0 : 0.f;
  h1 = h1 > 0.f ? h1 : 0.f;
  float p = h0 * Wc2[c0] + h1 * Wc2[c0 + 1];
  #pragma unroll
  for (int off = 32; off; off >>= 1) p += __shfl_xor(p, off, 64);
  if (lane == 0) wred2[w] = p;
  __syncthreads();
  if (tid == 0) logits[row] = wred2[0] + wred2[1] + wred2[2] + wred2[3] + bc2[0];
}

extern "C" void kernel_launch(void* const* d_in, const int* in_sizes, int n_in,
                              void* d_out, int out_size, void* d_ws, size_t ws_size,
                              hipStream_t stream) {
  const float* x     = (const float*)d_in[0];
  const float* wave1 = (const float*)d_in[1];
  const float* wave2 = (const float*)d_in[2];
  const float* wave3 = (const float*)d_in[3];
  const float* Wp1   = (const float*)d_in[4];
  const float* bp1   = (const float*)d_in[5];
  const float* cls   = (const float*)d_in[6];
  const float* ln1g  = (const float*)d_in[7];
  const float* ln1b  = (const float*)d_in[8];
  const float* Wq    = (const float*)d_in[9];
  const float* Wkv   = (const float*)d_in[10];
  const float* Wproj = (const float*)d_in[11];
  const float* bproj = (const float*)d_in[12];
  const float* ln2g  = (const float*)d_in[13];
  const float* ln2b  = (const float*)d_in[14];
  const float* Wc1   = (const float*)d_in[15];
  const float* bc1   = (const float*)d_in[16];
  const float* Wc2   = (const float*)d_in[17];
  const float* bc2   = (const float*)d_in[18];

  float* out = (float*)d_out;
  float* logits = out;
  float* attn   = out + 64;

  unsigned char* ws = (unsigned char*)d_ws;
  float* ksum           = (float*)(ws);
  float* qws            = (float*)(ws + (64u << 10));
  unsigned short* Wp1T  = (unsigned short*)(ws + (128u << 10));
  unsigned short* GvT   = (unsigned short*)(ws + (640u << 10));
  unsigned short* AqT   = (unsigned short*)(ws + (1152u << 10));
  float* gv             = (float*)(ws + (1248u << 10));
  float* bv             = (float*)(ws + (1252u << 10));
  float* ga             = (float*)(ws + (1256u << 10));
  float* ba             = (float*)(ws + (1260u << 10));
  float* o_part         = (float*)(ws + (1776u << 10));
  float* stat_part      = (float*)(ws + (4096u << 10));
  unsigned short* pos   = (unsigned short*)(ws + (8ull << 20));
  unsigned short* yb    = (unsigned short*)(ws + (72ull << 20));

  prep1_kernel<<<dim3(134), dim3(256), 0, stream>>>(wave1, wave2, wave3, ksum,
                                                    cls, Wq, qws, Wp1, Wp1T, Wkv, ln1g, GvT);
  prep2_kernel<<<dim3(98), dim3(256), 0, stream>>>(Wkv, qws, ln1g, ln1b, AqT, gv, bv, ga, ba);
  conv_kernel<<<dim3(4096), dim3(256), 0, stream>>>(x, ksum, pos);
  gemm1_kernel<<<dim3(2048), dim3(256), 0, stream>>>(pos, Wp1T, x, bp1, yb, stat_part);
  stage2_kernel<<<dim3(2048), dim3(256), 0, stream>>>(yb, GvT, AqT, stat_part,
                                                      gv, bv, ga, ba, attn, o_part);
  head_kernel<<<dim3(64), dim3(256), 0, stream>>>(o_part, Wproj, bproj, ln2g, ln2b,
                                                  Wc1, bc1, Wc2, bc2, logits);
}

// Round 7
// 299.199 us; speedup vs baseline: 1.5648x; 1.0329x over previous
//
#include <hip/hip_runtime.h>

#define SEQ 2048
#define DIM 512
#define NBATCH 32
#define NH 16
#define HDIM 32
#define NCLS 2

typedef __attribute__((ext_vector_type(8))) short short8;
typedef __attribute__((ext_vector_type(8))) unsigned short ushort8;
typedef __attribute__((ext_vector_type(4))) float f32x4;

__device__ __forceinline__ float b2f(unsigned short u){
  union { unsigned int i; float f; } v; v.i = ((unsigned int)u) << 16; return v.f;
}
__device__ __forceinline__ unsigned short f2b(float f){
  unsigned int x = __float_as_uint(f);
  unsigned int r = (x + 0x7fffu + ((x >> 16) & 1u)) >> 16;
  return (unsigned short)r;
}
__device__ __forceinline__ void gload16(const void* g, void* l){
  __builtin_amdgcn_global_load_lds((const __attribute__((address_space(1))) void*)g,
                                   (__attribute__((address_space(3))) void*)l, 16, 0, 0);
}

// ---------------- prep1: wavelet ksum | q = cls@Wq | Wp1T | GvT ----------------
__global__ __launch_bounds__(256) void prep1_kernel(
    const float* __restrict__ w1, const float* __restrict__ w2, const float* __restrict__ w3,
    float* __restrict__ ksum,
    const float* __restrict__ cls, const float* __restrict__ Wq, float* __restrict__ qws,
    const float* __restrict__ Wp1, unsigned short* __restrict__ Wp1T,
    const float* __restrict__ Wkv, const float* __restrict__ g1, unsigned short* __restrict__ GvT){
  __shared__ unsigned short t[64][65];
  int bid = blockIdx.x;
  int tid = threadIdx.x;
  if (bid < 2){
    int d = bid * 256 + tid;
    const float C = 0.86732501f;
    float acc[19];
    #pragma unroll
    for (int i = 0; i < 19; ++i) acc[i] = 0.f;
    const float* waves[3] = { w1, w2, w3 };
    for (int tt = 0; tt < 3; ++tt){
      float scale = waves[tt][d];
      float shift = waves[tt][DIM + d];
      float inv = 1.f / scale;
      float amp = C * rsqrtf(fabsf(scale));
      #pragma unroll
      for (int i = 0; i < 19; ++i){
        float u = ((float)(i - 9) - shift) * inv;
        acc[i] += amp * (1.f - u * u) * expf(-0.5f * u * u);
      }
    }
    #pragma unroll
    for (int i = 0; i < 19; ++i) ksum[i * DIM + d] = acc[i];
  } else if (bid < 6){
    int idx = (bid - 2) * 256 + tid;
    int n = idx >> 9, c = idx & 511;
    float s = 0.f;
    for (int kd = 0; kd < DIM; ++kd)
      s = fmaf(cls[n * DIM + kd], Wq[(size_t)kd * DIM + c], s);
    qws[n * DIM + c] = s;
  } else if (bid < 70){
    int bx = bid - 6;
    int c0 = (bx & 7) * 64, r0 = (bx >> 3) * 64;
    #pragma unroll
    for (int i = 0; i < 16; ++i){
      int idx = i * 256 + tid;
      int r = idx >> 6, c = idx & 63;
      t[c][r] = f2b(Wp1[(size_t)(r0 + r) * 512 + c0 + c]);
    }
    __syncthreads();
    #pragma unroll
    for (int i = 0; i < 16; ++i){
      int idx = i * 256 + tid;
      int r = idx >> 6, c = idx & 63;
      Wp1T[(size_t)(c0 + r) * 512 + r0 + c] = t[r][c];
    }
  } else {
    int bx = bid - 70;
    int c0 = (bx & 7) * 64, r0 = (bx >> 3) * 64;
    #pragma unroll
    for (int i = 0; i < 16; ++i){
      int idx = i * 256 + tid;
      int r = idx >> 6, c = idx & 63;
      t[c][r] = f2b(Wkv[(size_t)(r0 + r) * 1024 + 512 + c0 + c] * g1[r0 + r]);
    }
    __syncthreads();
    #pragma unroll
    for (int i = 0; i < 16; ++i){
      int idx = i * 256 + tid;
      int r = idx >> 6, c = idx & 63;
      GvT[(size_t)(c0 + r) * 512 + r0 + c] = t[r][c];
    }
  }
}

// ---------------- prep2: AqT direct | ga/ba | gv/bv ----------------
__global__ __launch_bounds__(256) void prep2_kernel(const float* __restrict__ Wkv,
    const float* __restrict__ qws, const float* __restrict__ g1, const float* __restrict__ b1,
    unsigned short* __restrict__ AqT, float* __restrict__ gv, float* __restrict__ bv,
    float* __restrict__ ga, float* __restrict__ ba){
  const float SCALE = 0.17677669529663687f;
  const float LOGS  = 7.6246189861593985f;
  int bid = blockIdx.x;
  int tid = threadIdx.x;
  if (bid < 64){
    int idx = bid * 256 + tid;           // 16384
    int hn = idx >> 9, d = idx & 511;
    int h = hn >> 1, n = hn & 1;
    float s = 0.f;
    #pragma unroll
    for (int hd = 0; hd < 32; ++hd)
      s = fmaf(Wkv[(size_t)d * 1024 + h * 32 + hd], qws[n * 512 + h * 32 + hd], s);
    AqT[hn * 512 + d] = f2b(SCALE * g1[d] * s);
  } else if (bid < 96){
    __shared__ float red[64];
    int hn = bid - 64;
    int h = hn >> 1, n = hn & 1;
    float s1 = 0.f, s2 = 0.f;
    #pragma unroll
    for (int dd = 0; dd < 2; ++dd){
      int d = tid + dd * 256;
      float inner = 0.f;
      #pragma unroll
      for (int hd = 0; hd < 32; ++hd)
        inner = fmaf(Wkv[(size_t)d * 1024 + h * 32 + hd], qws[n * 512 + h * 32 + hd], inner);
      s1 = fmaf(g1[d], inner, s1);
      s2 = fmaf(b1[d], inner, s2);
    }
    #pragma unroll
    for (int off = 32; off; off >>= 1){
      s1 += __shfl_xor(s1, off, 64);
      s2 += __shfl_xor(s2, off, 64);
    }
    int w = tid >> 6, lane = tid & 63;
    if (lane == 0){ red[w * 2] = s1; red[w * 2 + 1] = s2; }
    __syncthreads();
    if (tid == 0){
      float t1 = red[0] + red[2] + red[4] + red[6];
      float t2 = red[1] + red[3] + red[5] + red[7];
      ga[hn] = SCALE * t1;
      ba[hn] = SCALE * t2 - LOGS;
    }
  } else {
    int c = (bid - 96) * 256 + tid;      // 0..511
    float s1 = 0.f, s2 = 0.f;
    for (int d = 0; d < 512; ++d){
      float wv = Wkv[(size_t)d * 1024 + 512 + c];
      s1 = fmaf(g1[d], wv, s1);
      s2 = fmaf(b1[d], wv, s2);
    }
    gv[c] = s1; bv[c] = s2;
  }
}

// ---------------- conv: sliding-window FIR ----------------
template<bool EDGE>
__device__ __forceinline__ void conv_strip(const float* __restrict__ xb,
    const float* __restrict__ ksum, unsigned short* __restrict__ Pos,
    int b, int s0, int d0){
  float kx[19], ky[19];
  #pragma unroll
  for (int t = 0; t < 19; ++t){
    float2 kv = *(const float2*)&ksum[t * DIM + d0];
    kx[t] = kv.x; ky[t] = kv.y;
  }
  float ox[16], oy[16];
  #pragma unroll
  for (int o = 0; o < 16; ++o){ ox[o] = 0.f; oy[o] = 0.f; }
  const float* xp = xb + (size_t)(s0 - 9) * DIM + d0;
  #pragma unroll
  for (int bi = 0; bi < 5; ++bi){
    float xvx[8], xvy[8];
    #pragma unroll
    for (int j = 0; j < 8; ++j){
      int w = bi * 8 + j;
      if (w < 34){
        if (EDGE){
          int s = s0 - 9 + w;
          int sc = s < 0 ? 0 : (s > SEQ - 1 ? SEQ - 1 : s);
          float2 tv = *(const float2*)&xb[(size_t)sc * DIM + d0];
          bool ok = (s >= 0) && (s < SEQ);
          xvx[j] = ok ? tv.x : 0.f;
          xvy[j] = ok ? tv.y : 0.f;
        } else {
          float2 tv = *(const float2*)&xp[(size_t)w * DIM];
          xvx[j] = tv.x; xvy[j] = tv.y;
        }
      }
    }
    #pragma unroll
    for (int j = 0; j < 8; ++j){
      int w = bi * 8 + j;
      if (w < 34){
        #pragma unroll
        for (int o = 0; o < 16; ++o){
          int t2 = w - o;
          if (t2 >= 0 && t2 < 19){
            ox[o] = fmaf(xvx[j], kx[t2], ox[o]);
            oy[o] = fmaf(xvy[j], ky[t2], oy[o]);
          }
        }
      }
    }
  }
  #pragma unroll
  for (int o = 0; o < 16; ++o){
    unsigned int packed = (unsigned int)f2b(ox[o]) | ((unsigned int)f2b(oy[o]) << 16);
    *(unsigned int*)&Pos[((size_t)(b * SEQ + s0 + o)) * DIM + d0] = packed;
  }
}

__global__ __launch_bounds__(256) void conv_kernel(const float* __restrict__ X,
    const float* __restrict__ ksum, unsigned short* __restrict__ Pos){
  int id = blockIdx.x;                       // 4096
  int id2 = (id & 7) * 512 + (id >> 3);
  int b = id2 >> 7;
  int strip = id2 & 127;
  int s0 = strip * 16;
  int d0 = threadIdx.x * 2;
  const float* xb = X + ((size_t)b * SEQ) * DIM;
  if (strip == 0 || strip == 127)
    conv_strip<true>(xb, ksum, Pos, b, s0, d0);
  else
    conv_strip<false>(xb, ksum, Pos, b, s0, d0);
}

// ---------------- GEMM1: 128x128 dbuf pipelined + T2 XOR swizzle ----------------
// LDS layout: granule (row, c8) stored at granule index row*8 + (c8 ^ (row&7)).
// Staging keeps LDS dest linear (gload_lds constraint) and inverse-permutes the
// global source; ds_read applies the same XOR. 16-way bank conflict -> 2-way (free).
__global__ __launch_bounds__(256) void gemm1_kernel(const unsigned short* __restrict__ A,
    const unsigned short* __restrict__ Bt, const float* __restrict__ Xres,
    const float* __restrict__ bias, unsigned short* __restrict__ Out,
    float* __restrict__ stat_part){
  __shared__ unsigned short lA[2 * 8192];    // 2 x 128x64 bf16 = 32 KB
  __shared__ unsigned short lB[2 * 8192];    // 32 KB
  __shared__ float sred[128][2][2];
  int tid = threadIdx.x;
  int w = tid >> 6, lane = tid & 63;
  int wm = w >> 1, wn = w & 1;
  int q = lane >> 4, cl = lane & 15;
  int id = blockIdx.x;                        // 2048
  int nid = (id & 7) * 256 + (id >> 3);       // XCD-bijective
  int nch = nid & 3;
  size_t mBase = (size_t)(nid >> 2) * 128;
  int nBase = nch * 128;

  auto stage = [&](int buf, int k0){
    #pragma unroll
    for (int p = 0; p < 4; ++p){
      int G = p * 256 + tid;                 // target LDS granule (linear dest)
      int row = G >> 3;
      int c8 = (G & 7) ^ (row & 7);          // inverse-swizzled source granule
      gload16(A + (mBase + row) * 512 + k0 + c8 * 8, &lA[buf * 8192 + G * 8]);
      gload16(Bt + (size_t)(nBase + row) * 512 + k0 + c8 * 8, &lB[buf * 8192 + G * 8]);
    }
  };

  f32x4 acc[4][4] = {};
  stage(0, 0);
  __syncthreads();
  int cur = 0;
  for (int t = 0; t < 8; ++t){
    if (t < 7) stage(cur ^ 1, (t + 1) * 64);
    const unsigned short* cA = &lA[cur * 8192];
    const unsigned short* cB = &lB[cur * 8192];
    #pragma unroll
    for (int kk = 0; kk < 2; ++kk){
      short8 af[4], bfr[4];
      #pragma unroll
      for (int m = 0; m < 4; ++m){
        int row = wm * 64 + m * 16 + cl;
        af[m] = *(const short8*)&cA[row * 64 + (((kk * 4 + q) ^ (row & 7)) * 8)];
      }
      #pragma unroll
      for (int n = 0; n < 4; ++n){
        int row = wn * 64 + n * 16 + cl;
        bfr[n] = *(const short8*)&cB[row * 64 + (((kk * 4 + q) ^ (row & 7)) * 8)];
      }
      #pragma unroll
      for (int m = 0; m < 4; ++m){
        #pragma unroll
        for (int n = 0; n < 4; ++n)
          acc[m][n] = __builtin_amdgcn_mfma_f32_16x16x32_bf16(af[m], bfr[n], acc[m][n], 0, 0, 0);
      }
    }
    __syncthreads();
    cur ^= 1;
  }
  #pragma unroll
  for (int m = 0; m < 4; ++m){
    #pragma unroll
    for (int j = 0; j < 4; ++j){
      int rl = wm * 64 + m * 16 + q * 4 + j;
      size_t row = mBase + rl;
      float sm = 0.f, sq = 0.f;
      #pragma unroll
      for (int n = 0; n < 4; ++n){
        int col = nBase + wn * 64 + n * 16 + cl;
        float v = acc[m][n][j] + Xres[row * DIM + col] + bias[col];
        Out[row * DIM + col] = f2b(v);
        sm += v; sq += v * v;
      }
      #pragma unroll
      for (int off = 1; off < 16; off <<= 1){
        sm += __shfl_xor(sm, off, 64);
        sq += __shfl_xor(sq, off, 64);
      }
      if (cl == 0){ sred[rl][wn][0] = sm; sred[rl][wn][1] = sq; }
    }
  }
  __syncthreads();
  if (tid < 128){
    float sm = sred[tid][0][0] + sred[tid][1][0];
    float sq = sred[tid][0][1] + sred[tid][1][1];
    stat_part[((mBase + tid) * 4 + nch) * 2 + 0] = sm;
    stat_part[((mBase + tid) * 4 + nch) * 2 + 1] = sq;
  }
}

// ---------------- stage2: dbuf pipelined + T2 swizzle; v + scores + attn + PV ---------
__global__ __launch_bounds__(256) void stage2_kernel(
    const unsigned short* __restrict__ Y, const unsigned short* __restrict__ GvT,
    const unsigned short* __restrict__ AqT, const float* __restrict__ stat_part,
    const float* __restrict__ gv, const float* __restrict__ bv,
    const float* __restrict__ ga, const float* __restrict__ ba,
    float* __restrict__ aout, float* __restrict__ o_part){
  __shared__ __align__(16) char smem[66560];
  unsigned short* lA = (unsigned short*)smem;               // 2 x 16 KB
  unsigned short* lB = (unsigned short*)(smem + 32768);     // 2 x 16 KB
  float* stats = (float*)(smem + 65536);                    // 128*2*4 = 1024
  float* attn_lds = (float*)smem;                           // overlay (after loop)
  float* o_red = (float*)(smem + 16896);                    // overlay
  int tid = threadIdx.x;
  int w = tid >> 6, lane = tid & 63;
  int wm = w >> 1, wn = w & 1;
  int q = lane >> 4, cl = lane & 15;
  int id = blockIdx.x;
  int nid = (id & 7) * 256 + (id >> 3);
  int nch = nid & 3;
  int mb = nid >> 2;
  size_t mBase = (size_t)mb * 128;
  int nBase = nch * 128;

  auto stage = [&](int buf, int k0){
    #pragma unroll
    for (int p = 0; p < 4; ++p){
      int G = p * 256 + tid;
      int row = G >> 3;
      int c8 = (G & 7) ^ (row & 7);
      gload16(Y + (mBase + row) * 512 + k0 + c8 * 8, &lA[buf * 8192 + G * 8]);
      gload16(GvT + (size_t)(nBase + row) * 512 + k0 + c8 * 8, &lB[buf * 8192 + G * 8]);
    }
  };

  stage(0, 0);
  if (tid < 128){
    float sm = 0.f, sq = 0.f;
    #pragma unroll
    for (int i = 0; i < 4; ++i){
      sm += stat_part[((mBase + tid) * 4 + i) * 2 + 0];
      sq += stat_part[((mBase + tid) * 4 + i) * 2 + 1];
    }
    float mean = sm * (1.f / 512.f);
    float var = sq * (1.f / 512.f) - mean * mean;
    stats[tid * 2 + 0] = mean;
    stats[tid * 2 + 1] = rsqrtf(var + 1e-5f);
  }
  __syncthreads();

  int hn = wn * 16 + cl;
  f32x4 acc[4][4] = {};
  f32x4 accs[4] = {};
  int cur = 0;
  for (int t = 0; t < 8; ++t){
    if (t < 7) stage(cur ^ 1, (t + 1) * 64);
    int k0 = t * 64;
    const unsigned short* cA = &lA[cur * 8192];
    const unsigned short* cB = &lB[cur * 8192];
    #pragma unroll
    for (int kk = 0; kk < 2; ++kk){
      short8 af[4], bfr[4], bq;
      bq = *(const short8*)&AqT[hn * 512 + k0 + kk * 32 + q * 8];
      #pragma unroll
      for (int m = 0; m < 4; ++m){
        int row = wm * 64 + m * 16 + cl;
        af[m] = *(const short8*)&cA[row * 64 + (((kk * 4 + q) ^ (row & 7)) * 8)];
      }
      #pragma unroll
      for (int n = 0; n < 4; ++n){
        int row = wn * 64 + n * 16 + cl;
        bfr[n] = *(const short8*)&cB[row * 64 + (((kk * 4 + q) ^ (row & 7)) * 8)];
      }
      #pragma unroll
      for (int m = 0; m < 4; ++m){
        #pragma unroll
        for (int n = 0; n < 4; ++n)
          acc[m][n] = __builtin_amdgcn_mfma_f32_16x16x32_bf16(af[m], bfr[n], acc[m][n], 0, 0, 0);
        accs[m] = __builtin_amdgcn_mfma_f32_16x16x32_bf16(af[m], bq, accs[m], 0, 0, 0);
      }
    }
    __syncthreads();
    cur ^= 1;
  }
  // epilogue
  float gav = ga[hn], bav = ba[hn];
  float gv4[4], bv4[4];
  #pragma unroll
  for (int n = 0; n < 4; ++n){
    int cg = nBase + wn * 64 + n * 16 + cl;
    gv4[n] = gv[cg]; bv4[n] = bv[cg];
  }
  int b = mb >> 4;
  int scb = (mb & 15) * 128;
  #pragma unroll
  for (int m = 0; m < 4; ++m){
    #pragma unroll
    for (int j = 0; j < 4; ++j){
      int rl = wm * 64 + m * 16 + q * 4 + j;
      float mu = stats[rl * 2 + 0], s = stats[rl * 2 + 1];
      float sc = s * accs[m][j] - s * mu * gav + bav;
      float at = 1.f / (1.f + expf(-sc));
      attn_lds[rl * 33 + hn] = at;
      if (nch == 0)
        aout[((size_t)(b * NH + (hn >> 1)) * NCLS + (hn & 1)) * SEQ + scb + rl] = at;
      #pragma unroll
      for (int n = 0; n < 4; ++n)
        acc[m][n][j] = s * acc[m][n][j] - s * mu * gv4[n] + bv4[n];
    }
  }
  __syncthreads();
  float o0[4] = {}, o1[4] = {};
  #pragma unroll
  for (int n = 0; n < 4; ++n){
    int cg = nBase + wn * 64 + n * 16 + cl;
    int h2 = ((cg >> 5) << 1);
    #pragma unroll
    for (int m = 0; m < 4; ++m){
      #pragma unroll
      for (int j = 0; j < 4; ++j){
        int rl = wm * 64 + m * 16 + q * 4 + j;
        float vv = acc[m][n][j];
        o0[n] = fmaf(attn_lds[rl * 33 + h2 + 0], vv, o0[n]);
        o1[n] = fmaf(attn_lds[rl * 33 + h2 + 1], vv, o1[n]);
      }
    }
  }
  #pragma unroll
  for (int n = 0; n < 4; ++n){
    o0[n] += __shfl_xor(o0[n], 16, 64);
    o0[n] += __shfl_xor(o0[n], 32, 64);
    o1[n] += __shfl_xor(o1[n], 16, 64);
    o1[n] += __shfl_xor(o1[n], 32, 64);
  }
  if (q == 0){
    #pragma unroll
    for (int n = 0; n < 4; ++n){
      int c = wn * 64 + n * 16 + cl;
      o_red[(0 * 2 + wm) * 128 + c] = o0[n];
      o_red[(1 * 2 + wm) * 128 + c] = o1[n];
    }
  }
  __syncthreads();
  {
    int nn = tid >> 7, c = tid & 127;
    float v = o_red[(nn * 2 + 0) * 128 + c] + o_red[(nn * 2 + 1) * 128 + c];
    o_part[((size_t)mb * 2 + nn) * 512 + nBase + c] = v;
  }
}

// ---------------- Head ----------------
__global__ __launch_bounds__(256) void head_kernel(const float* __restrict__ o_part,
    const float* __restrict__ Wproj, const float* __restrict__ bproj,
    const float* __restrict__ g2, const float* __restrict__ b2v,
    const float* __restrict__ Wc1, const float* __restrict__ bc1,
    const float* __restrict__ Wc2, const float* __restrict__ bc2,
    float* __restrict__ logits){
  __shared__ float orow[512];
  __shared__ float hrow[512];
  __shared__ float wred[8];
  __shared__ float wred2[4];
  int tid = threadIdx.x;
  int row = blockIdx.x;
  int b = row >> 1, nn = row & 1;
  for (int i = tid; i < 512; i += 256){
    float s = 0.f;
    const float* op = o_part + (((size_t)b * 16) * 2 + nn) * 512 + i;
    #pragma unroll
    for (int sc = 0; sc < 16; ++sc) s += op[(size_t)sc * 1024];
    orow[i] = s;
  }
  __syncthreads();
  int c0 = tid * 2;
  float a0 = 0.f, a1 = 0.f;
  for (int dd = 0; dd < DIM; ++dd){
    float ov = orow[dd];
    const float* wr = Wproj + (size_t)dd * DIM + c0;
    a0 = fmaf(ov, wr[0], a0);
    a1 = fmaf(ov, wr[1], a1);
  }
  a0 += bproj[c0]; a1 += bproj[c0 + 1];
  float sm = a0 + a1, sq = a0 * a0 + a1 * a1;
  #pragma unroll
  for (int off = 32; off; off >>= 1){
    sm += __shfl_xor(sm, off, 64);
    sq += __shfl_xor(sq, off, 64);
  }
  int w = tid >> 6, lane = tid & 63;
  if (lane == 0){ wred[w * 2] = sm; wred[w * 2 + 1] = sq; }
  __syncthreads();
  sm = wred[0] + wred[2] + wred[4] + wred[6];
  sq = wred[1] + wred[3] + wred[5] + wred[7];
  float mean = sm * (1.f / 512.f);
  float var = sq * (1.f / 512.f) - mean * mean;
  float rstd = rsqrtf(var + 1e-5f);
  hrow[c0]     = (a0 - mean) * rstd * g2[c0]     + b2v[c0];
  hrow[c0 + 1] = (a1 - mean) * rstd * g2[c0 + 1] + b2v[c0 + 1];
  __syncthreads();
  float h0 = 0.f, h1 = 0.f;
  for (int dd = 0; dd < DIM; ++dd){
    float lv = hrow[dd];
    const float* wr = Wc1 + (size_t)dd * DIM + c0;
    h0 = fmaf(lv, wr[0], h0);
    h1 = fmaf(lv, wr[1], h1);
  }
  h0 += bc1[c0]; h1 += bc1[c0 + 1];
  h0 = h0 > 0.f ? h0 : 0.f;
  h1 = h1 > 0.f ? h1 : 0.f;
  float p = h0 * Wc2[c0] + h1 * Wc2[c0 + 1];
  #pragma unroll
  for (int off = 32; off; off >>= 1) p += __shfl_xor(p, off, 64);
  if (lane == 0) wred2[w] = p;
  __syncthreads();
  if (tid == 0) logits[row] = wred2[0] + wred2[1] + wred2[2] + wred2[3] + bc2[0];
}

extern "C" void kernel_launch(void* const* d_in, const int* in_sizes, int n_in,
                              void* d_out, int out_size, void* d_ws, size_t ws_size,
                              hipStream_t stream) {
  const float* x     = (const float*)d_in[0];
  const float* wave1 = (const float*)d_in[1];
  const float* wave2 = (const float*)d_in[2];
  const float* wave3 = (const float*)d_in[3];
  const float* Wp1   = (const float*)d_in[4];
  const float* bp1   = (const float*)d_in[5];
  const float* cls   = (const float*)d_in[6];
  const float* ln1g  = (const float*)d_in[7];
  const float* ln1b  = (const float*)d_in[8];
  const float* Wq    = (const float*)d_in[9];
  const float* Wkv   = (const float*)d_in[10];
  const float* Wproj = (const float*)d_in[11];
  const float* bproj = (const float*)d_in[12];
  const float* ln2g  = (const float*)d_in[13];
  const float* ln2b  = (const float*)d_in[14];
  const float* Wc1   = (const float*)d_in[15];
  const float* bc1   = (const float*)d_in[16];
  const float* Wc2   = (const float*)d_in[17];
  const float* bc2   = (const float*)d_in[18];

  float* out = (float*)d_out;
  float* logits = out;
  float* attn   = out + 64;

  unsigned char* ws = (unsigned char*)d_ws;
  float* ksum           = (float*)(ws);
  float* qws            = (float*)(ws + (64u << 10));
  unsigned short* Wp1T  = (unsigned short*)(ws + (128u << 10));
  unsigned short* GvT   = (unsigned short*)(ws + (640u << 10));
  unsigned short* AqT   = (unsigned short*)(ws + (1152u << 10));
  float* gv             = (float*)(ws + (1248u << 10));
  float* bv             = (float*)(ws + (1252u << 10));
  float* ga             = (float*)(ws + (1256u << 10));
  float* ba             = (float*)(ws + (1260u << 10));
  float* o_part         = (float*)(ws + (1776u << 10));
  float* stat_part      = (float*)(ws + (4096u << 10));
  unsigned short* pos   = (unsigned short*)(ws + (8ull << 20));
  unsigned short* yb    = (unsigned short*)(ws + (72ull << 20));

  prep1_kernel<<<dim3(134), dim3(256), 0, stream>>>(wave1, wave2, wave3, ksum,
                                                    cls, Wq, qws, Wp1, Wp1T, Wkv, ln1g, GvT);
  prep2_kernel<<<dim3(98), dim3(256), 0, stream>>>(Wkv, qws, ln1g, ln1b, AqT, gv, bv, ga, ba);
  conv_kernel<<<dim3(4096), dim3(256), 0, stream>>>(x, ksum, pos);
  gemm1_kernel<<<dim3(2048), dim3(256), 0, stream>>>(pos, Wp1T, x, bp1, yb, stat_part);
  stage2_kernel<<<dim3(2048), dim3(256), 0, stream>>>(yb, GvT, AqT, stat_part,
                                                      gv, bv, ga, ba, attn, o_part);
  head_kernel<<<dim3(64), dim3(256), 0, stream>>>(o_part, Wproj, bproj, ln2g, ln2b,
                                                  Wc1, bc1, Wc2, bc2, logits);
}

// Round 8
// 288.914 us; speedup vs baseline: 1.6205x; 1.0356x over previous
//
#include <hip/hip_runtime.h>

#define SEQ 2048
#define DIM 512
#define NBATCH 32
#define NH 16
#define HDIM 32
#define NCLS 2

typedef __attribute__((ext_vector_type(8))) short short8;
typedef __attribute__((ext_vector_type(8))) unsigned short ushort8;
typedef __attribute__((ext_vector_type(4))) float f32x4;

__device__ __forceinline__ float b2f(unsigned short u){
  union { unsigned int i; float f; } v; v.i = ((unsigned int)u) << 16; return v.f;
}
__device__ __forceinline__ unsigned short f2b(float f){
  unsigned int x = __float_as_uint(f);
  unsigned int r = (x + 0x7fffu + ((x >> 16) & 1u)) >> 16;
  return (unsigned short)r;
}
__device__ __forceinline__ void gload16(const void* g, void* l){
  __builtin_amdgcn_global_load_lds((const __attribute__((address_space(1))) void*)g,
                                   (__attribute__((address_space(3))) void*)l, 16, 0, 0);
}

// ---------------- prep1: wavelet ksum | q = cls@Wq | Wp1T | GvT ----------------
__global__ __launch_bounds__(256) void prep1_kernel(
    const float* __restrict__ w1, const float* __restrict__ w2, const float* __restrict__ w3,
    float* __restrict__ ksum,
    const float* __restrict__ cls, const float* __restrict__ Wq, float* __restrict__ qws,
    const float* __restrict__ Wp1, unsigned short* __restrict__ Wp1T,
    const float* __restrict__ Wkv, const float* __restrict__ g1, unsigned short* __restrict__ GvT){
  __shared__ unsigned short t[64][65];
  int bid = blockIdx.x;
  int tid = threadIdx.x;
  if (bid < 2){
    int d = bid * 256 + tid;
    const float C = 0.86732501f;
    float acc[19];
    #pragma unroll
    for (int i = 0; i < 19; ++i) acc[i] = 0.f;
    const float* waves[3] = { w1, w2, w3 };
    for (int tt = 0; tt < 3; ++tt){
      float scale = waves[tt][d];
      float shift = waves[tt][DIM + d];
      float inv = 1.f / scale;
      float amp = C * rsqrtf(fabsf(scale));
      #pragma unroll
      for (int i = 0; i < 19; ++i){
        float u = ((float)(i - 9) - shift) * inv;
        acc[i] += amp * (1.f - u * u) * expf(-0.5f * u * u);
      }
    }
    #pragma unroll
    for (int i = 0; i < 19; ++i) ksum[i * DIM + d] = acc[i];
  } else if (bid < 6){
    int idx = (bid - 2) * 256 + tid;
    int n = idx >> 9, c = idx & 511;
    float s = 0.f;
    for (int kd = 0; kd < DIM; ++kd)
      s = fmaf(cls[n * DIM + kd], Wq[(size_t)kd * DIM + c], s);
    qws[n * DIM + c] = s;
  } else if (bid < 70){
    int bx = bid - 6;
    int c0 = (bx & 7) * 64, r0 = (bx >> 3) * 64;
    #pragma unroll
    for (int i = 0; i < 16; ++i){
      int idx = i * 256 + tid;
      int r = idx >> 6, c = idx & 63;
      t[c][r] = f2b(Wp1[(size_t)(r0 + r) * 512 + c0 + c]);
    }
    __syncthreads();
    #pragma unroll
    for (int i = 0; i < 16; ++i){
      int idx = i * 256 + tid;
      int r = idx >> 6, c = idx & 63;
      Wp1T[(size_t)(c0 + r) * 512 + r0 + c] = t[r][c];
    }
  } else {
    int bx = bid - 70;
    int c0 = (bx & 7) * 64, r0 = (bx >> 3) * 64;
    #pragma unroll
    for (int i = 0; i < 16; ++i){
      int idx = i * 256 + tid;
      int r = idx >> 6, c = idx & 63;
      t[c][r] = f2b(Wkv[(size_t)(r0 + r) * 1024 + 512 + c0 + c] * g1[r0 + r]);
    }
    __syncthreads();
    #pragma unroll
    for (int i = 0; i < 16; ++i){
      int idx = i * 256 + tid;
      int r = idx >> 6, c = idx & 63;
      GvT[(size_t)(c0 + r) * 512 + r0 + c] = t[r][c];
    }
  }
}

// ---------------- prep2: AqT direct | ga/ba | gv/bv ----------------
__global__ __launch_bounds__(256) void prep2_kernel(const float* __restrict__ Wkv,
    const float* __restrict__ qws, const float* __restrict__ g1, const float* __restrict__ b1,
    unsigned short* __restrict__ AqT, float* __restrict__ gv, float* __restrict__ bv,
    float* __restrict__ ga, float* __restrict__ ba){
  const float SCALE = 0.17677669529663687f;
  const float LOGS  = 7.6246189861593985f;
  int bid = blockIdx.x;
  int tid = threadIdx.x;
  if (bid < 64){
    int idx = bid * 256 + tid;           // 16384
    int hn = idx >> 9, d = idx & 511;
    int h = hn >> 1, n = hn & 1;
    float s = 0.f;
    #pragma unroll
    for (int hd = 0; hd < 32; ++hd)
      s = fmaf(Wkv[(size_t)d * 1024 + h * 32 + hd], qws[n * 512 + h * 32 + hd], s);
    AqT[hn * 512 + d] = f2b(SCALE * g1[d] * s);
  } else if (bid < 96){
    __shared__ float red[64];
    int hn = bid - 64;
    int h = hn >> 1, n = hn & 1;
    float s1 = 0.f, s2 = 0.f;
    #pragma unroll
    for (int dd = 0; dd < 2; ++dd){
      int d = tid + dd * 256;
      float inner = 0.f;
      #pragma unroll
      for (int hd = 0; hd < 32; ++hd)
        inner = fmaf(Wkv[(size_t)d * 1024 + h * 32 + hd], qws[n * 512 + h * 32 + hd], inner);
      s1 = fmaf(g1[d], inner, s1);
      s2 = fmaf(b1[d], inner, s2);
    }
    #pragma unroll
    for (int off = 32; off; off >>= 1){
      s1 += __shfl_xor(s1, off, 64);
      s2 += __shfl_xor(s2, off, 64);
    }
    int w = tid >> 6, lane = tid & 63;
    if (lane == 0){ red[w * 2] = s1; red[w * 2 + 1] = s2; }
    __syncthreads();
    if (tid == 0){
      float t1 = red[0] + red[2] + red[4] + red[6];
      float t2 = red[1] + red[3] + red[5] + red[7];
      ga[hn] = SCALE * t1;
      ba[hn] = SCALE * t2 - LOGS;
    }
  } else {
    int c = (bid - 96) * 256 + tid;      // 0..511
    float s1 = 0.f, s2 = 0.f;
    for (int d = 0; d < 512; ++d){
      float wv = Wkv[(size_t)d * 1024 + 512 + c];
      s1 = fmaf(g1[d], wv, s1);
      s2 = fmaf(b1[d], wv, s2);
    }
    gv[c] = s1; bv[c] = s2;
  }
}

// ---------------- conv: sliding-window FIR ----------------
template<bool EDGE>
__device__ __forceinline__ void conv_strip(const float* __restrict__ xb,
    const float* __restrict__ ksum, unsigned short* __restrict__ Pos,
    int b, int s0, int d0){
  float kx[19], ky[19];
  #pragma unroll
  for (int t = 0; t < 19; ++t){
    float2 kv = *(const float2*)&ksum[t * DIM + d0];
    kx[t] = kv.x; ky[t] = kv.y;
  }
  float ox[16], oy[16];
  #pragma unroll
  for (int o = 0; o < 16; ++o){ ox[o] = 0.f; oy[o] = 0.f; }
  const float* xp = xb + (size_t)(s0 - 9) * DIM + d0;
  #pragma unroll
  for (int bi = 0; bi < 5; ++bi){
    float xvx[8], xvy[8];
    #pragma unroll
    for (int j = 0; j < 8; ++j){
      int w = bi * 8 + j;
      if (w < 34){
        if (EDGE){
          int s = s0 - 9 + w;
          int sc = s < 0 ? 0 : (s > SEQ - 1 ? SEQ - 1 : s);
          float2 tv = *(const float2*)&xb[(size_t)sc * DIM + d0];
          bool ok = (s >= 0) && (s < SEQ);
          xvx[j] = ok ? tv.x : 0.f;
          xvy[j] = ok ? tv.y : 0.f;
        } else {
          float2 tv = *(const float2*)&xp[(size_t)w * DIM];
          xvx[j] = tv.x; xvy[j] = tv.y;
        }
      }
    }
    #pragma unroll
    for (int j = 0; j < 8; ++j){
      int w = bi * 8 + j;
      if (w < 34){
        #pragma unroll
        for (int o = 0; o < 16; ++o){
          int t2 = w - o;
          if (t2 >= 0 && t2 < 19){
            ox[o] = fmaf(xvx[j], kx[t2], ox[o]);
            oy[o] = fmaf(xvy[j], ky[t2], oy[o]);
          }
        }
      }
    }
  }
  #pragma unroll
  for (int o = 0; o < 16; ++o){
    unsigned int packed = (unsigned int)f2b(ox[o]) | ((unsigned int)f2b(oy[o]) << 16);
    *(unsigned int*)&Pos[((size_t)(b * SEQ + s0 + o)) * DIM + d0] = packed;
  }
}

__global__ __launch_bounds__(256) void conv_kernel(const float* __restrict__ X,
    const float* __restrict__ ksum, unsigned short* __restrict__ Pos){
  int id = blockIdx.x;                       // 4096
  int id2 = (id & 7) * 512 + (id >> 3);
  int b = id2 >> 7;
  int strip = id2 & 127;
  int s0 = strip * 16;
  int d0 = threadIdx.x * 2;
  const float* xb = X + ((size_t)b * SEQ) * DIM;
  if (strip == 0 || strip == 127)
    conv_strip<true>(xb, ksum, Pos, b, s0, d0);
  else
    conv_strip<false>(xb, ksum, Pos, b, s0, d0);
}

// ---------------- GEMM1: 128x128 dbuf + counted vmcnt + T2 swizzle + XCD-stripe --------
__global__ __launch_bounds__(256) void gemm1_kernel(const unsigned short* __restrict__ A,
    const unsigned short* __restrict__ Bt, const float* __restrict__ Xres,
    const float* __restrict__ bias, unsigned short* __restrict__ Out,
    float* __restrict__ stat_part){
  __shared__ unsigned short lA[2 * 8192];    // 32 KB
  __shared__ unsigned short lB[2 * 8192];    // 32 KB
  __shared__ float sred[128][2][2];
  int tid = threadIdx.x;
  int w = tid >> 6, lane = tid & 63;
  int wm = w >> 1, wn = w & 1;
  int q = lane >> 4, cl = lane & 15;
  // same-stripe-same-XCD: all 4 nch of one mb share an XCD's L2
  int id = blockIdx.x;                        // 2048
  int xcd = id & 7;
  int nch = (id >> 3) & 3;
  int mb  = ((id >> 5) << 3) | xcd;           // 0..511
  size_t mBase = (size_t)mb * 128;
  int nBase = nch * 128;

  auto stage = [&](int buf, int k0){          // 8 gload_lds per thread
    #pragma unroll
    for (int p = 0; p < 4; ++p){
      int G = p * 256 + tid;                  // linear LDS granule
      int row = G >> 3;
      int c8 = (G & 7) ^ (row & 7);           // inverse-swizzled source
      gload16(A + (mBase + row) * 512 + k0 + c8 * 8, &lA[buf * 8192 + G * 8]);
      gload16(Bt + (size_t)(nBase + row) * 512 + k0 + c8 * 8, &lB[buf * 8192 + G * 8]);
    }
  };

  f32x4 acc[4][4] = {};
  stage(0, 0);
  __syncthreads();                            // prologue full drain (once)
  int cur = 0;
  #pragma unroll
  for (int t = 0; t < 8; ++t){
    if (t < 7){
      stage(cur ^ 1, (t + 1) * 64);
      asm volatile("s_waitcnt vmcnt(8)" ::: "memory");   // stage(t) landed; stage(t+1) stays in flight
    } else {
      asm volatile("s_waitcnt vmcnt(0)" ::: "memory");
    }
    __builtin_amdgcn_s_barrier();
    const unsigned short* cA = &lA[cur * 8192];
    const unsigned short* cB = &lB[cur * 8192];
    #pragma unroll
    for (int kk = 0; kk < 2; ++kk){
      short8 af[4], bfr[4];
      #pragma unroll
      for (int m = 0; m < 4; ++m){
        int row = wm * 64 + m * 16 + cl;
        af[m] = *(const short8*)&cA[row * 64 + (((kk * 4 + q) ^ (row & 7)) * 8)];
      }
      #pragma unroll
      for (int n = 0; n < 4; ++n){
        int row = wn * 64 + n * 16 + cl;
        bfr[n] = *(const short8*)&cB[row * 64 + (((kk * 4 + q) ^ (row & 7)) * 8)];
      }
      #pragma unroll
      for (int m = 0; m < 4; ++m){
        #pragma unroll
        for (int n = 0; n < 4; ++n)
          acc[m][n] = __builtin_amdgcn_mfma_f32_16x16x32_bf16(af[m], bfr[n], acc[m][n], 0, 0, 0);
      }
    }
    asm volatile("s_waitcnt lgkmcnt(0)" ::: "memory");   // my ds_reads serviced before overwrite
    __builtin_amdgcn_s_barrier();
    cur ^= 1;
  }
  #pragma unroll
  for (int m = 0; m < 4; ++m){
    #pragma unroll
    for (int j = 0; j < 4; ++j){
      int rl = wm * 64 + m * 16 + q * 4 + j;
      size_t row = mBase + rl;
      float sm = 0.f, sq = 0.f;
      #pragma unroll
      for (int n = 0; n < 4; ++n){
        int col = nBase + wn * 64 + n * 16 + cl;
        float v = acc[m][n][j] + Xres[row * DIM + col] + bias[col];
        Out[row * DIM + col] = f2b(v);
        sm += v; sq += v * v;
      }
      #pragma unroll
      for (int off = 1; off < 16; off <<= 1){
        sm += __shfl_xor(sm, off, 64);
        sq += __shfl_xor(sq, off, 64);
      }
      if (cl == 0){ sred[rl][wn][0] = sm; sred[rl][wn][1] = sq; }
    }
  }
  __syncthreads();
  if (tid < 128){
    float sm = sred[tid][0][0] + sred[tid][1][0];
    float sq = sred[tid][0][1] + sred[tid][1][1];
    stat_part[((mBase + tid) * 4 + nch) * 2 + 0] = sm;
    stat_part[((mBase + tid) * 4 + nch) * 2 + 1] = sq;
  }
}

// ---------------- stage2: dbuf + counted vmcnt + swizzle; AqT folded into B-tile -------
__global__ __launch_bounds__(256) void stage2_kernel(
    const unsigned short* __restrict__ Y, const unsigned short* __restrict__ GvT,
    const unsigned short* __restrict__ AqT, const float* __restrict__ stat_part,
    const float* __restrict__ gv, const float* __restrict__ bv,
    const float* __restrict__ ga, const float* __restrict__ ba,
    float* __restrict__ aout, float* __restrict__ o_part){
  __shared__ __align__(16) char smem[74752];
  unsigned short* lA = (unsigned short*)smem;               // 2 x 16 KB
  unsigned short* lB = (unsigned short*)(smem + 32768);     // 2 x 20 KB (160 rows: 128 GvT + 32 AqT)
  float* stats = (float*)(smem + 73728);                    // 1 KB
  float* attn_lds = (float*)smem;                           // overlay (post-loop)
  float* o_red = (float*)(smem + 16896);                    // overlay
  int tid = threadIdx.x;
  int w = tid >> 6, lane = tid & 63;
  int wm = w >> 1, wn = w & 1;
  int q = lane >> 4, cl = lane & 15;
  int id = blockIdx.x;                        // 2048
  int xcd = id & 7;
  int nch = (id >> 3) & 3;
  int mb  = ((id >> 5) << 3) | xcd;
  size_t mBase = (size_t)mb * 128;
  int nBase = nch * 128;

  auto stage = [&](int buf, int k0){          // 9 gload_lds per thread
    #pragma unroll
    for (int p = 0; p < 4; ++p){
      int G = p * 256 + tid;
      int row = G >> 3;
      int c8 = (G & 7) ^ (row & 7);
      gload16(Y + (mBase + row) * 512 + k0 + c8 * 8, &lA[buf * 8192 + G * 8]);
      gload16(GvT + (size_t)(nBase + row) * 512 + k0 + c8 * 8, &lB[buf * 10240 + G * 8]);
    }
    {
      int G = 1024 + tid;                     // AqT rows 128..159
      int row = G >> 3;
      int c8 = (G & 7) ^ (row & 7);
      gload16(AqT + (size_t)(row - 128) * 512 + k0 + c8 * 8, &lB[buf * 10240 + G * 8]);
    }
  };

  stage(0, 0);
  if (tid < 128){
    float sm = 0.f, sq = 0.f;
    #pragma unroll
    for (int i = 0; i < 4; ++i){
      sm += stat_part[((mBase + tid) * 4 + i) * 2 + 0];
      sq += stat_part[((mBase + tid) * 4 + i) * 2 + 1];
    }
    float mean = sm * (1.f / 512.f);
    float var = sq * (1.f / 512.f) - mean * mean;
    stats[tid * 2 + 0] = mean;
    stats[tid * 2 + 1] = rsqrtf(var + 1e-5f);
  }
  __syncthreads();                            // prologue full drain (once)

  int hn = wn * 16 + cl;
  f32x4 acc[4][4] = {};
  f32x4 accs[4] = {};
  int cur = 0;
  #pragma unroll
  for (int t = 0; t < 8; ++t){
    if (t < 7){
      stage(cur ^ 1, (t + 1) * 64);
      asm volatile("s_waitcnt vmcnt(9)" ::: "memory");
    } else {
      asm volatile("s_waitcnt vmcnt(0)" ::: "memory");
    }
    __builtin_amdgcn_s_barrier();
    const unsigned short* cA = &lA[cur * 8192];
    const unsigned short* cB = &lB[cur * 10240];
    #pragma unroll
    for (int kk = 0; kk < 2; ++kk){
      short8 af[4], bfr[4], bq;
      {
        int row = 128 + hn;
        bq = *(const short8*)&cB[row * 64 + (((kk * 4 + q) ^ (row & 7)) * 8)];
      }
      #pragma unroll
      for (int m = 0; m < 4; ++m){
        int row = wm * 64 + m * 16 + cl;
        af[m] = *(const short8*)&cA[row * 64 + (((kk * 4 + q) ^ (row & 7)) * 8)];
      }
      #pragma unroll
      for (int n = 0; n < 4; ++n){
        int row = wn * 64 + n * 16 + cl;
        bfr[n] = *(const short8*)&cB[row * 64 + (((kk * 4 + q) ^ (row & 7)) * 8)];
      }
      #pragma unroll
      for (int m = 0; m < 4; ++m){
        #pragma unroll
        for (int n = 0; n < 4; ++n)
          acc[m][n] = __builtin_amdgcn_mfma_f32_16x16x32_bf16(af[m], bfr[n], acc[m][n], 0, 0, 0);
        accs[m] = __builtin_amdgcn_mfma_f32_16x16x32_bf16(af[m], bq, accs[m], 0, 0, 0);
      }
    }
    asm volatile("s_waitcnt lgkmcnt(0)" ::: "memory");
    __builtin_amdgcn_s_barrier();
    cur ^= 1;
  }
  // epilogue
  float gav = ga[hn], bav = ba[hn];
  float gv4[4], bv4[4];
  #pragma unroll
  for (int n = 0; n < 4; ++n){
    int cg = nBase + wn * 64 + n * 16 + cl;
    gv4[n] = gv[cg]; bv4[n] = bv[cg];
  }
  int b = mb >> 4;
  int scb = (mb & 15) * 128;
  #pragma unroll
  for (int m = 0; m < 4; ++m){
    #pragma unroll
    for (int j = 0; j < 4; ++j){
      int rl = wm * 64 + m * 16 + q * 4 + j;
      float mu = stats[rl * 2 + 0], s = stats[rl * 2 + 1];
      float sc = s * accs[m][j] - s * mu * gav + bav;
      float at = 1.f / (1.f + expf(-sc));
      attn_lds[rl * 33 + hn] = at;
      if (nch == 0)
        aout[((size_t)(b * NH + (hn >> 1)) * NCLS + (hn & 1)) * SEQ + scb + rl] = at;
      #pragma unroll
      for (int n = 0; n < 4; ++n)
        acc[m][n][j] = s * acc[m][n][j] - s * mu * gv4[n] + bv4[n];
    }
  }
  __syncthreads();
  float o0[4] = {}, o1[4] = {};
  #pragma unroll
  for (int n = 0; n < 4; ++n){
    int cg = nBase + wn * 64 + n * 16 + cl;
    int h2 = ((cg >> 5) << 1);
    #pragma unroll
    for (int m = 0; m < 4; ++m){
      #pragma unroll
      for (int j = 0; j < 4; ++j){
        int rl = wm * 64 + m * 16 + q * 4 + j;
        float vv = acc[m][n][j];
        o0[n] = fmaf(attn_lds[rl * 33 + h2 + 0], vv, o0[n]);
        o1[n] = fmaf(attn_lds[rl * 33 + h2 + 1], vv, o1[n]);
      }
    }
  }
  #pragma unroll
  for (int n = 0; n < 4; ++n){
    o0[n] += __shfl_xor(o0[n], 16, 64);
    o0[n] += __shfl_xor(o0[n], 32, 64);
    o1[n] += __shfl_xor(o1[n], 16, 64);
    o1[n] += __shfl_xor(o1[n], 32, 64);
  }
  if (q == 0){
    #pragma unroll
    for (int n = 0; n < 4; ++n){
      int c = wn * 64 + n * 16 + cl;
      o_red[(0 * 2 + wm) * 128 + c] = o0[n];
      o_red[(1 * 2 + wm) * 128 + c] = o1[n];
    }
  }
  __syncthreads();
  {
    int nn = tid >> 7, c = tid & 127;
    float v = o_red[(nn * 2 + 0) * 128 + c] + o_red[(nn * 2 + 1) * 128 + c];
    o_part[((size_t)mb * 2 + nn) * 512 + nBase + c] = v;
  }
}

// ---------------- Head ----------------
__global__ __launch_bounds__(256) void head_kernel(const float* __restrict__ o_part,
    const float* __restrict__ Wproj, const float* __restrict__ bproj,
    const float* __restrict__ g2, const float* __restrict__ b2v,
    const float* __restrict__ Wc1, const float* __restrict__ bc1,
    const float* __restrict__ Wc2, const float* __restrict__ bc2,
    float* __restrict__ logits){
  __shared__ float orow[512];
  __shared__ float hrow[512];
  __shared__ float wred[8];
  __shared__ float wred2[4];
  int tid = threadIdx.x;
  int row = blockIdx.x;
  int b = row >> 1, nn = row & 1;
  for (int i = tid; i < 512; i += 256){
    float s = 0.f;
    const float* op = o_part + (((size_t)b * 16) * 2 + nn) * 512 + i;
    #pragma unroll
    for (int sc = 0; sc < 16; ++sc) s += op[(size_t)sc * 1024];
    orow[i] = s;
  }
  __syncthreads();
  int c0 = tid * 2;
  float a0 = 0.f, a1 = 0.f;
  for (int dd = 0; dd < DIM; ++dd){
    float ov = orow[dd];
    const float* wr = Wproj + (size_t)dd * DIM + c0;
    a0 = fmaf(ov, wr[0], a0);
    a1 = fmaf(ov, wr[1], a1);
  }
  a0 += bproj[c0]; a1 += bproj[c0 + 1];
  float sm = a0 + a1, sq = a0 * a0 + a1 * a1;
  #pragma unroll
  for (int off = 32; off; off >>= 1){
    sm += __shfl_xor(sm, off, 64);
    sq += __shfl_xor(sq, off, 64);
  }
  int w = tid >> 6, lane = tid & 63;
  if (lane == 0){ wred[w * 2] = sm; wred[w * 2 + 1] = sq; }
  __syncthreads();
  sm = wred[0] + wred[2] + wred[4] + wred[6];
  sq = wred[1] + wred[3] + wred[5] + wred[7];
  float mean = sm * (1.f / 512.f);
  float var = sq * (1.f / 512.f) - mean * mean;
  float rstd = rsqrtf(var + 1e-5f);
  hrow[c0]     = (a0 - mean) * rstd * g2[c0]     + b2v[c0];
  hrow[c0 + 1] = (a1 - mean) * rstd * g2[c0 + 1] + b2v[c0 + 1];
  __syncthreads();
  float h0 = 0.f, h1 = 0.f;
  for (int dd = 0; dd < DIM; ++dd){
    float lv = hrow[dd];
    const float* wr = Wc1 + (size_t)dd * DIM + c0;
    h0 = fmaf(lv, wr[0], h0);
    h1 = fmaf(lv, wr[1], h1);
  }
  h0 += bc1[c0]; h1 += bc1[c0 + 1];
  h0 = h0 > 0.f ? h0 : 0.f;
  h1 = h1 > 0.f ? h1 : 0.f;
  float p = h0 * Wc2[c0] + h1 * Wc2[c0 + 1];
  #pragma unroll
  for (int off = 32; off; off >>= 1) p += __shfl_xor(p, off, 64);
  if (lane == 0) wred2[w] = p;
  __syncthreads();
  if (tid == 0) logits[row] = wred2[0] + wred2[1] + wred2[2] + wred2[3] + bc2[0];
}

extern "C" void kernel_launch(void* const* d_in, const int* in_sizes, int n_in,
                              void* d_out, int out_size, void* d_ws, size_t ws_size,
                              hipStream_t stream) {
  const float* x     = (const float*)d_in[0];
  const float* wave1 = (const float*)d_in[1];
  const float* wave2 = (const float*)d_in[2];
  const float* wave3 = (const float*)d_in[3];
  const float* Wp1   = (const float*)d_in[4];
  const float* bp1   = (const float*)d_in[5];
  const float* cls   = (const float*)d_in[6];
  const float* ln1g  = (const float*)d_in[7];
  const float* ln1b  = (const float*)d_in[8];
  const float* Wq    = (const float*)d_in[9];
  const float* Wkv   = (const float*)d_in[10];
  const float* Wproj = (const float*)d_in[11];
  const float* bproj = (const float*)d_in[12];
  const float* ln2g  = (const float*)d_in[13];
  const float* ln2b  = (const float*)d_in[14];
  const float* Wc1   = (const float*)d_in[15];
  const float* bc1   = (const float*)d_in[16];
  const float* Wc2   = (const float*)d_in[17];
  const float* bc2   = (const float*)d_in[18];

  float* out = (float*)d_out;
  float* logits = out;
  float* attn   = out + 64;

  unsigned char* ws = (unsigned char*)d_ws;
  float* ksum           = (float*)(ws);
  float* qws            = (float*)(ws + (64u << 10));
  unsigned short* Wp1T  = (unsigned short*)(ws + (128u << 10));
  unsigned short* GvT   = (unsigned short*)(ws + (640u << 10));
  unsigned short* AqT   = (unsigned short*)(ws + (1152u << 10));
  float* gv             = (float*)(ws + (1248u << 10));
  float* bv             = (float*)(ws + (1252u << 10));
  float* ga             = (float*)(ws + (1256u << 10));
  float* ba             = (float*)(ws + (1260u << 10));
  float* o_part         = (float*)(ws + (1776u << 10));
  float* stat_part      = (float*)(ws + (4096u << 10));
  unsigned short* pos   = (unsigned short*)(ws + (8ull << 20));
  unsigned short* yb    = (unsigned short*)(ws + (72ull << 20));

  prep1_kernel<<<dim3(134), dim3(256), 0, stream>>>(wave1, wave2, wave3, ksum,
                                                    cls, Wq, qws, Wp1, Wp1T, Wkv, ln1g, GvT);
  prep2_kernel<<<dim3(98), dim3(256), 0, stream>>>(Wkv, qws, ln1g, ln1b, AqT, gv, bv, ga, ba);
  conv_kernel<<<dim3(4096), dim3(256), 0, stream>>>(x, ksum, pos);
  gemm1_kernel<<<dim3(2048), dim3(256), 0, stream>>>(pos, Wp1T, x, bp1, yb, stat_part);
  stage2_kernel<<<dim3(2048), dim3(256), 0, stream>>>(yb, GvT, AqT, stat_part,
                                                      gv, bv, ga, ba, attn, o_part);
  head_kernel<<<dim3(64), dim3(256), 0, stream>>>(o_part, Wproj, bproj, ln2g, ln2b,
                                                  Wc1, bc1, Wc2, bc2, logits);
}

// Round 9
// 276.865 us; speedup vs baseline: 1.6910x; 1.0435x over previous
//
#include <hip/hip_runtime.h>

#define SEQ 2048
#define DIM 512
#define NBATCH 32
#define NH 16
#define HDIM 32
#define NCLS 2

typedef __attribute__((ext_vector_type(8))) short short8;
typedef __attribute__((ext_vector_type(8))) unsigned short ushort8;
typedef __attribute__((ext_vector_type(4))) float f32x4;

__device__ __forceinline__ float b2f(unsigned short u){
  union { unsigned int i; float f; } v; v.i = ((unsigned int)u) << 16; return v.f;
}
__device__ __forceinline__ unsigned short f2b(float f){
  unsigned int x = __float_as_uint(f);
  unsigned int r = (x + 0x7fffu + ((x >> 16) & 1u)) >> 16;
  return (unsigned short)r;
}
__device__ __forceinline__ void gload16(const void* g, void* l){
  __builtin_amdgcn_global_load_lds((const __attribute__((address_space(1))) void*)g,
                                   (__attribute__((address_space(3))) void*)l, 16, 0, 0);
}

// ---------------- prep1: wavelet ksum | q = cls@Wq | Wp1T | GvT ----------------
__global__ __launch_bounds__(256) void prep1_kernel(
    const float* __restrict__ w1, const float* __restrict__ w2, const float* __restrict__ w3,
    float* __restrict__ ksum,
    const float* __restrict__ cls, const float* __restrict__ Wq, float* __restrict__ qws,
    const float* __restrict__ Wp1, unsigned short* __restrict__ Wp1T,
    const float* __restrict__ Wkv, const float* __restrict__ g1, unsigned short* __restrict__ GvT){
  __shared__ unsigned short t[64][65];
  int bid = blockIdx.x;
  int tid = threadIdx.x;
  if (bid < 2){
    int d = bid * 256 + tid;
    const float C = 0.86732501f;
    float acc[19];
    #pragma unroll
    for (int i = 0; i < 19; ++i) acc[i] = 0.f;
    const float* waves[3] = { w1, w2, w3 };
    for (int tt = 0; tt < 3; ++tt){
      float scale = waves[tt][d];
      float shift = waves[tt][DIM + d];
      float inv = 1.f / scale;
      float amp = C * rsqrtf(fabsf(scale));
      #pragma unroll
      for (int i = 0; i < 19; ++i){
        float u = ((float)(i - 9) - shift) * inv;
        acc[i] += amp * (1.f - u * u) * expf(-0.5f * u * u);
      }
    }
    #pragma unroll
    for (int i = 0; i < 19; ++i) ksum[i * DIM + d] = acc[i];
  } else if (bid < 6){
    int idx = (bid - 2) * 256 + tid;
    int n = idx >> 9, c = idx & 511;
    float s = 0.f;
    for (int kd = 0; kd < DIM; ++kd)
      s = fmaf(cls[n * DIM + kd], Wq[(size_t)kd * DIM + c], s);
    qws[n * DIM + c] = s;
  } else if (bid < 70){
    int bx = bid - 6;
    int c0 = (bx & 7) * 64, r0 = (bx >> 3) * 64;
    #pragma unroll
    for (int i = 0; i < 16; ++i){
      int idx = i * 256 + tid;
      int r = idx >> 6, c = idx & 63;
      t[c][r] = f2b(Wp1[(size_t)(r0 + r) * 512 + c0 + c]);
    }
    __syncthreads();
    #pragma unroll
    for (int i = 0; i < 16; ++i){
      int idx = i * 256 + tid;
      int r = idx >> 6, c = idx & 63;
      Wp1T[(size_t)(c0 + r) * 512 + r0 + c] = t[r][c];
    }
  } else {
    int bx = bid - 70;
    int c0 = (bx & 7) * 64, r0 = (bx >> 3) * 64;
    #pragma unroll
    for (int i = 0; i < 16; ++i){
      int idx = i * 256 + tid;
      int r = idx >> 6, c = idx & 63;
      t[c][r] = f2b(Wkv[(size_t)(r0 + r) * 1024 + 512 + c0 + c] * g1[r0 + r]);
    }
    __syncthreads();
    #pragma unroll
    for (int i = 0; i < 16; ++i){
      int idx = i * 256 + tid;
      int r = idx >> 6, c = idx & 63;
      GvT[(size_t)(c0 + r) * 512 + r0 + c] = t[r][c];
    }
  }
}

// ---------------- prep2: AqT direct | ga/ba | gv/bv ----------------
__global__ __launch_bounds__(256) void prep2_kernel(const float* __restrict__ Wkv,
    const float* __restrict__ qws, const float* __restrict__ g1, const float* __restrict__ b1,
    unsigned short* __restrict__ AqT, float* __restrict__ gv, float* __restrict__ bv,
    float* __restrict__ ga, float* __restrict__ ba){
  const float SCALE = 0.17677669529663687f;
  const float LOGS  = 7.6246189861593985f;
  int bid = blockIdx.x;
  int tid = threadIdx.x;
  if (bid < 64){
    int idx = bid * 256 + tid;           // 16384
    int hn = idx >> 9, d = idx & 511;
    int h = hn >> 1, n = hn & 1;
    float s = 0.f;
    #pragma unroll
    for (int hd = 0; hd < 32; ++hd)
      s = fmaf(Wkv[(size_t)d * 1024 + h * 32 + hd], qws[n * 512 + h * 32 + hd], s);
    AqT[hn * 512 + d] = f2b(SCALE * g1[d] * s);
  } else if (bid < 96){
    __shared__ float red[64];
    int hn = bid - 64;
    int h = hn >> 1, n = hn & 1;
    float s1 = 0.f, s2 = 0.f;
    #pragma unroll
    for (int dd = 0; dd < 2; ++dd){
      int d = tid + dd * 256;
      float inner = 0.f;
      #pragma unroll
      for (int hd = 0; hd < 32; ++hd)
        inner = fmaf(Wkv[(size_t)d * 1024 + h * 32 + hd], qws[n * 512 + h * 32 + hd], inner);
      s1 = fmaf(g1[d], inner, s1);
      s2 = fmaf(b1[d], inner, s2);
    }
    #pragma unroll
    for (int off = 32; off; off >>= 1){
      s1 += __shfl_xor(s1, off, 64);
      s2 += __shfl_xor(s2, off, 64);
    }
    int w = tid >> 6, lane = tid & 63;
    if (lane == 0){ red[w * 2] = s1; red[w * 2 + 1] = s2; }
    __syncthreads();
    if (tid == 0){
      float t1 = red[0] + red[2] + red[4] + red[6];
      float t2 = red[1] + red[3] + red[5] + red[7];
      ga[hn] = SCALE * t1;
      ba[hn] = SCALE * t2 - LOGS;
    }
  } else {
    int c = (bid - 96) * 256 + tid;      // 0..511
    float s1 = 0.f, s2 = 0.f;
    for (int d = 0; d < 512; ++d){
      float wv = Wkv[(size_t)d * 1024 + 512 + c];
      s1 = fmaf(g1[d], wv, s1);
      s2 = fmaf(b1[d], wv, s2);
    }
    gv[c] = s1; bv[c] = s2;
  }
}

// ---------------- conv: sliding-window FIR ----------------
template<bool EDGE>
__device__ __forceinline__ void conv_strip(const float* __restrict__ xb,
    const float* __restrict__ ksum, unsigned short* __restrict__ Pos,
    int b, int s0, int d0){
  float kx[19], ky[19];
  #pragma unroll
  for (int t = 0; t < 19; ++t){
    float2 kv = *(const float2*)&ksum[t * DIM + d0];
    kx[t] = kv.x; ky[t] = kv.y;
  }
  float ox[16], oy[16];
  #pragma unroll
  for (int o = 0; o < 16; ++o){ ox[o] = 0.f; oy[o] = 0.f; }
  const float* xp = xb + (size_t)(s0 - 9) * DIM + d0;
  #pragma unroll
  for (int bi = 0; bi < 5; ++bi){
    float xvx[8], xvy[8];
    #pragma unroll
    for (int j = 0; j < 8; ++j){
      int w = bi * 8 + j;
      if (w < 34){
        if (EDGE){
          int s = s0 - 9 + w;
          int sc = s < 0 ? 0 : (s > SEQ - 1 ? SEQ - 1 : s);
          float2 tv = *(const float2*)&xb[(size_t)sc * DIM + d0];
          bool ok = (s >= 0) && (s < SEQ);
          xvx[j] = ok ? tv.x : 0.f;
          xvy[j] = ok ? tv.y : 0.f;
        } else {
          float2 tv = *(const float2*)&xp[(size_t)w * DIM];
          xvx[j] = tv.x; xvy[j] = tv.y;
        }
      }
    }
    #pragma unroll
    for (int j = 0; j < 8; ++j){
      int w = bi * 8 + j;
      if (w < 34){
        #pragma unroll
        for (int o = 0; o < 16; ++o){
          int t2 = w - o;
          if (t2 >= 0 && t2 < 19){
            ox[o] = fmaf(xvx[j], kx[t2], ox[o]);
            oy[o] = fmaf(xvy[j], ky[t2], oy[o]);
          }
        }
      }
    }
  }
  #pragma unroll
  for (int o = 0; o < 16; ++o){
    unsigned int packed = (unsigned int)f2b(ox[o]) | ((unsigned int)f2b(oy[o]) << 16);
    *(unsigned int*)&Pos[((size_t)(b * SEQ + s0 + o)) * DIM + d0] = packed;
  }
}

__global__ __launch_bounds__(256) void conv_kernel(const float* __restrict__ X,
    const float* __restrict__ ksum, unsigned short* __restrict__ Pos){
  int id = blockIdx.x;                       // 4096
  int id2 = (id & 7) * 512 + (id >> 3);
  int b = id2 >> 7;
  int strip = id2 & 127;
  int s0 = strip * 16;
  int d0 = threadIdx.x * 2;
  const float* xb = X + ((size_t)b * SEQ) * DIM;
  if (strip == 0 || strip == 127)
    conv_strip<true>(xb, ksum, Pos, b, s0, d0);
  else
    conv_strip<false>(xb, ksum, Pos, b, s0, d0);
}

// ---------------- GEMM1: 128x128, 8 waves, low-reg; dbuf + counted vmcnt + swizzle -----
__global__ __launch_bounds__(512, 4) void gemm1_kernel(const unsigned short* __restrict__ A,
    const unsigned short* __restrict__ Bt, const float* __restrict__ Xres,
    const float* __restrict__ bias, unsigned short* __restrict__ Out,
    float* __restrict__ stat_part){
  __shared__ unsigned short lA[2 * 8192];    // 32 KB
  __shared__ unsigned short lB[2 * 8192];    // 32 KB
  __shared__ float sred[128][2][2];
  int tid = threadIdx.x;
  int w = tid >> 6, lane = tid & 63;
  int wm = w >> 1, wn = w & 1;               // wm 0..3 (32-row stripes), wn 0..1 (64-col)
  int q = lane >> 4, cl = lane & 15;
  int id = blockIdx.x;                        // 2048
  int xcd = id & 7;
  int nch = (id >> 3) & 3;
  int mb  = ((id >> 5) << 3) | xcd;           // 0..511
  size_t mBase = (size_t)mb * 128;
  int nBase = nch * 128;

  auto stage = [&](int buf, int k0){          // 4 gload_lds per thread (uniform)
    #pragma unroll
    for (int p = 0; p < 2; ++p){
      int G = p * 512 + tid;                  // linear LDS granule
      int row = G >> 3;
      int c8 = (G & 7) ^ (row & 7);           // inverse-swizzled source
      gload16(A + (mBase + row) * 512 + k0 + c8 * 8, &lA[buf * 8192 + G * 8]);
      gload16(Bt + (size_t)(nBase + row) * 512 + k0 + c8 * 8, &lB[buf * 8192 + G * 8]);
    }
  };

  f32x4 acc[2][4] = {};
  stage(0, 0);
  __syncthreads();                            // prologue full drain (once)
  int cur = 0;
  #pragma unroll
  for (int t = 0; t < 8; ++t){
    if (t < 7){
      stage(cur ^ 1, (t + 1) * 64);
      asm volatile("s_waitcnt vmcnt(4)" ::: "memory");
    } else {
      asm volatile("s_waitcnt vmcnt(0)" ::: "memory");
    }
    __builtin_amdgcn_s_barrier();
    const unsigned short* cA = &lA[cur * 8192];
    const unsigned short* cB = &lB[cur * 8192];
    #pragma unroll
    for (int kk = 0; kk < 2; ++kk){
      short8 af[2], bfr[4];
      #pragma unroll
      for (int m = 0; m < 2; ++m){
        int row = wm * 32 + m * 16 + cl;
        af[m] = *(const short8*)&cA[row * 64 + (((kk * 4 + q) ^ (row & 7)) * 8)];
      }
      #pragma unroll
      for (int n = 0; n < 4; ++n){
        int row = wn * 64 + n * 16 + cl;
        bfr[n] = *(const short8*)&cB[row * 64 + (((kk * 4 + q) ^ (row & 7)) * 8)];
      }
      #pragma unroll
      for (int m = 0; m < 2; ++m){
        #pragma unroll
        for (int n = 0; n < 4; ++n)
          acc[m][n] = __builtin_amdgcn_mfma_f32_16x16x32_bf16(af[m], bfr[n], acc[m][n], 0, 0, 0);
      }
    }
    asm volatile("s_waitcnt lgkmcnt(0)" ::: "memory");
    __builtin_amdgcn_s_barrier();
    cur ^= 1;
  }
  #pragma unroll
  for (int m = 0; m < 2; ++m){
    #pragma unroll
    for (int j = 0; j < 4; ++j){
      int rl = wm * 32 + m * 16 + q * 4 + j;
      size_t row = mBase + rl;
      float sm = 0.f, sq = 0.f;
      #pragma unroll
      for (int n = 0; n < 4; ++n){
        int col = nBase + wn * 64 + n * 16 + cl;
        float v = acc[m][n][j] + Xres[row * DIM + col] + bias[col];
        Out[row * DIM + col] = f2b(v);
        sm += v; sq += v * v;
      }
      #pragma unroll
      for (int off = 1; off < 16; off <<= 1){
        sm += __shfl_xor(sm, off, 64);
        sq += __shfl_xor(sq, off, 64);
      }
      if (cl == 0){ sred[rl][wn][0] = sm; sred[rl][wn][1] = sq; }
    }
  }
  __syncthreads();
  if (tid < 128){
    float sm = sred[tid][0][0] + sred[tid][1][0];
    float sq = sred[tid][0][1] + sred[tid][1][1];
    stat_part[((mBase + tid) * 4 + nch) * 2 + 0] = sm;
    stat_part[((mBase + tid) * 4 + nch) * 2 + 1] = sq;
  }
}

// ---------------- stage2: 8 waves, low-reg; AqT in B-tile (dup-write padding) ----------
__global__ __launch_bounds__(512, 4) void stage2_kernel(
    const unsigned short* __restrict__ Y, const unsigned short* __restrict__ GvT,
    const unsigned short* __restrict__ AqT, const float* __restrict__ stat_part,
    const float* __restrict__ gv, const float* __restrict__ bv,
    const float* __restrict__ ga, const float* __restrict__ ba,
    float* __restrict__ aout, float* __restrict__ o_part){
  __shared__ __align__(16) char smem[74752];
  unsigned short* lA = (unsigned short*)smem;               // 2 x 16 KB
  unsigned short* lB = (unsigned short*)(smem + 32768);     // 2 x 20 KB (128 GvT + 32 AqT rows)
  float* stats = (float*)(smem + 73728);                    // 1 KB
  float* attn_lds = (float*)smem;                           // overlay (post-loop) 16896 B
  float* o_red = (float*)(smem + 16896);                    // overlay 2*4*128*4 = 4096 B
  int tid = threadIdx.x;
  int w = tid >> 6, lane = tid & 63;
  int wm = w >> 1, wn = w & 1;
  int q = lane >> 4, cl = lane & 15;
  int id = blockIdx.x;                        // 2048
  int xcd = id & 7;
  int nch = (id >> 3) & 3;
  int mb  = ((id >> 5) << 3) | xcd;
  size_t mBase = (size_t)mb * 128;
  int nBase = nch * 128;

  auto stage = [&](int buf, int k0){          // 5 gload_lds per thread (uniform)
    #pragma unroll
    for (int p = 0; p < 2; ++p){
      int G = p * 512 + tid;
      int row = G >> 3;
      int c8 = (G & 7) ^ (row & 7);
      gload16(Y + (mBase + row) * 512 + k0 + c8 * 8, &lA[buf * 8192 + G * 8]);
      gload16(GvT + (size_t)(nBase + row) * 512 + k0 + c8 * 8, &lB[buf * 10240 + G * 8]);
    }
    {
      // AqT rows 128..159; threads 256..511 duplicate threads 0..255 (same dest, same data)
      int g = tid & 255;
      int row = 128 + (g >> 3);
      int c8 = (g & 7) ^ (row & 7);
      gload16(AqT + (size_t)(row - 128) * 512 + k0 + c8 * 8, &lB[buf * 10240 + (1024 + g) * 8]);
    }
  };

  stage(0, 0);
  if (tid < 128){
    float sm = 0.f, sq = 0.f;
    #pragma unroll
    for (int i = 0; i < 4; ++i){
      sm += stat_part[((mBase + tid) * 4 + i) * 2 + 0];
      sq += stat_part[((mBase + tid) * 4 + i) * 2 + 1];
    }
    float mean = sm * (1.f / 512.f);
    float var = sq * (1.f / 512.f) - mean * mean;
    stats[tid * 2 + 0] = mean;
    stats[tid * 2 + 1] = rsqrtf(var + 1e-5f);
  }
  __syncthreads();                            // prologue full drain (once)

  int hn = wn * 16 + cl;
  f32x4 acc[2][4] = {};
  f32x4 accs[2] = {};
  int cur = 0;
  #pragma unroll
  for (int t = 0; t < 8; ++t){
    if (t < 7){
      stage(cur ^ 1, (t + 1) * 64);
      asm volatile("s_waitcnt vmcnt(5)" ::: "memory");
    } else {
      asm volatile("s_waitcnt vmcnt(0)" ::: "memory");
    }
    __builtin_amdgcn_s_barrier();
    const unsigned short* cA = &lA[cur * 8192];
    const unsigned short* cB = &lB[cur * 10240];
    #pragma unroll
    for (int kk = 0; kk < 2; ++kk){
      short8 af[2], bfr[4], bq;
      {
        int row = 128 + hn;
        bq = *(const short8*)&cB[row * 64 + (((kk * 4 + q) ^ (row & 7)) * 8)];
      }
      #pragma unroll
      for (int m = 0; m < 2; ++m){
        int row = wm * 32 + m * 16 + cl;
        af[m] = *(const short8*)&cA[row * 64 + (((kk * 4 + q) ^ (row & 7)) * 8)];
      }
      #pragma unroll
      for (int n = 0; n < 4; ++n){
        int row = wn * 64 + n * 16 + cl;
        bfr[n] = *(const short8*)&cB[row * 64 + (((kk * 4 + q) ^ (row & 7)) * 8)];
      }
      #pragma unroll
      for (int m = 0; m < 2; ++m){
        #pragma unroll
        for (int n = 0; n < 4; ++n)
          acc[m][n] = __builtin_amdgcn_mfma_f32_16x16x32_bf16(af[m], bfr[n], acc[m][n], 0, 0, 0);
        accs[m] = __builtin_amdgcn_mfma_f32_16x16x32_bf16(af[m], bq, accs[m], 0, 0, 0);
      }
    }
    asm volatile("s_waitcnt lgkmcnt(0)" ::: "memory");
    __builtin_amdgcn_s_barrier();
    cur ^= 1;
  }
  // epilogue
  float gav = ga[hn], bav = ba[hn];
  float gv4[4], bv4[4];
  #pragma unroll
  for (int n = 0; n < 4; ++n){
    int cg = nBase + wn * 64 + n * 16 + cl;
    gv4[n] = gv[cg]; bv4[n] = bv[cg];
  }
  int b = mb >> 4;
  int scb = (mb & 15) * 128;
  #pragma unroll
  for (int m = 0; m < 2; ++m){
    #pragma unroll
    for (int j = 0; j < 4; ++j){
      int rl = wm * 32 + m * 16 + q * 4 + j;
      float mu = stats[rl * 2 + 0], s = stats[rl * 2 + 1];
      float sc = s * accs[m][j] - s * mu * gav + bav;
      float at = 1.f / (1.f + expf(-sc));
      attn_lds[rl * 33 + hn] = at;
      if (nch == 0)
        aout[((size_t)(b * NH + (hn >> 1)) * NCLS + (hn & 1)) * SEQ + scb + rl] = at;
      #pragma unroll
      for (int n = 0; n < 4; ++n)
        acc[m][n][j] = s * acc[m][n][j] - s * mu * gv4[n] + bv4[n];
    }
  }
  __syncthreads();
  float o0[4] = {}, o1[4] = {};
  #pragma unroll
  for (int n = 0; n < 4; ++n){
    int cg = nBase + wn * 64 + n * 16 + cl;
    int h2 = ((cg >> 5) << 1);
    #pragma unroll
    for (int m = 0; m < 2; ++m){
      #pragma unroll
      for (int j = 0; j < 4; ++j){
        int rl = wm * 32 + m * 16 + q * 4 + j;
        float vv = acc[m][n][j];
        o0[n] = fmaf(attn_lds[rl * 33 + h2 + 0], vv, o0[n]);
        o1[n] = fmaf(attn_lds[rl * 33 + h2 + 1], vv, o1[n]);
      }
    }
  }
  #pragma unroll
  for (int n = 0; n < 4; ++n){
    o0[n] += __shfl_xor(o0[n], 16, 64);
    o0[n] += __shfl_xor(o0[n], 32, 64);
    o1[n] += __shfl_xor(o1[n], 16, 64);
    o1[n] += __shfl_xor(o1[n], 32, 64);
  }
  if (q == 0){
    #pragma unroll
    for (int n = 0; n < 4; ++n){
      int c = wn * 64 + n * 16 + cl;
      o_red[(0 * 4 + wm) * 128 + c] = o0[n];
      o_red[(1 * 4 + wm) * 128 + c] = o1[n];
    }
  }
  __syncthreads();
  if (tid < 256){
    int nn = tid >> 7, c = tid & 127;
    float v = o_red[(nn * 4 + 0) * 128 + c] + o_red[(nn * 4 + 1) * 128 + c]
            + o_red[(nn * 4 + 2) * 128 + c] + o_red[(nn * 4 + 3) * 128 + c];
    o_part[((size_t)mb * 2 + nn) * 512 + nBase + c] = v;
  }
}

// ---------------- Head ----------------
__global__ __launch_bounds__(256) void head_kernel(const float* __restrict__ o_part,
    const float* __restrict__ Wproj, const float* __restrict__ bproj,
    const float* __restrict__ g2, const float* __restrict__ b2v,
    const float* __restrict__ Wc1, const float* __restrict__ bc1,
    const float* __restrict__ Wc2, const float* __restrict__ bc2,
    float* __restrict__ logits){
  __shared__ float orow[512];
  __shared__ float hrow[512];
  __shared__ float wred[8];
  __shared__ float wred2[4];
  int tid = threadIdx.x;
  int row = blockIdx.x;
  int b = row >> 1, nn = row & 1;
  for (int i = tid; i < 512; i += 256){
    float s = 0.f;
    const float* op = o_part + (((size_t)b * 16) * 2 + nn) * 512 + i;
    #pragma unroll
    for (int sc = 0; sc < 16; ++sc) s += op[(size_t)sc * 1024];
    orow[i] = s;
  }
  __syncthreads();
  int c0 = tid * 2;
  float a0 = 0.f, a1 = 0.f;
  for (int dd = 0; dd < DIM; ++dd){
    float ov = orow[dd];
    const float* wr = Wproj + (size_t)dd * DIM + c0;
    a0 = fmaf(ov, wr[0], a0);
    a1 = fmaf(ov, wr[1], a1);
  }
  a0 += bproj[c0]; a1 += bproj[c0 + 1];
  float sm = a0 + a1, sq = a0 * a0 + a1 * a1;
  #pragma unroll
  for (int off = 32; off; off >>= 1){
    sm += __shfl_xor(sm, off, 64);
    sq += __shfl_xor(sq, off, 64);
  }
  int w = tid >> 6, lane = tid & 63;
  if (lane == 0){ wred[w * 2] = sm; wred[w * 2 + 1] = sq; }
  __syncthreads();
  sm = wred[0] + wred[2] + wred[4] + wred[6];
  sq = wred[1] + wred[3] + wred[5] + wred[7];
  float mean = sm * (1.f / 512.f);
  float var = sq * (1.f / 512.f) - mean * mean;
  float rstd = rsqrtf(var + 1e-5f);
  hrow[c0]     = (a0 - mean) * rstd * g2[c0]     + b2v[c0];
  hrow[c0 + 1] = (a1 - mean) * rstd * g2[c0 + 1] + b2v[c0 + 1];
  __syncthreads();
  float h0 = 0.f, h1 = 0.f;
  for (int dd = 0; dd < DIM; ++dd){
    float lv = hrow[dd];
    const float* wr = Wc1 + (size_t)dd * DIM + c0;
    h0 = fmaf(lv, wr[0], h0);
    h1 = fmaf(lv, wr[1], h1);
  }
  h0 += bc1[c0]; h1 += bc1[c0 + 1];
  h0 = h0 > 0.f ? h0 : 0.f;
  h1 = h1 > 0.f ? h1 : 0.f;
  float p = h0 * Wc2[c0] + h1 * Wc2[c0 + 1];
  #pragma unroll
  for (int off = 32; off; off >>= 1) p += __shfl_xor(p, off, 64);
  if (lane == 0) wred2[w] = p;
  __syncthreads();
  if (tid == 0) logits[row] = wred2[0] + wred2[1] + wred2[2] + wred2[3] + bc2[0];
}

extern "C" void kernel_launch(void* const* d_in, const int* in_sizes, int n_in,
                              void* d_out, int out_size, void* d_ws, size_t ws_size,
                              hipStream_t stream) {
  const float* x     = (const float*)d_in[0];
  const float* wave1 = (const float*)d_in[1];
  const float* wave2 = (const float*)d_in[2];
  const float* wave3 = (const float*)d_in[3];
  const float* Wp1   = (const float*)d_in[4];
  const float* bp1   = (const float*)d_in[5];
  const float* cls   = (const float*)d_in[6];
  const float* ln1g  = (const float*)d_in[7];
  const float* ln1b  = (const float*)d_in[8];
  const float* Wq    = (const float*)d_in[9];
  const float* Wkv   = (const float*)d_in[10];
  const float* Wproj = (const float*)d_in[11];
  const float* bproj = (const float*)d_in[12];
  const float* ln2g  = (const float*)d_in[13];
  const float* ln2b  = (const float*)d_in[14];
  const float* Wc1   = (const float*)d_in[15];
  const float* bc1   = (const float*)d_in[16];
  const float* Wc2   = (const float*)d_in[17];
  const float* bc2   = (const float*)d_in[18];

  float* out = (float*)d_out;
  float* logits = out;
  float* attn   = out + 64;

  unsigned char* ws = (unsigned char*)d_ws;
  float* ksum           = (float*)(ws);
  float* qws            = (float*)(ws + (64u << 10));
  unsigned short* Wp1T  = (unsigned short*)(ws + (128u << 10));
  unsigned short* GvT   = (unsigned short*)(ws + (640u << 10));
  unsigned short* AqT   = (unsigned short*)(ws + (1152u << 10));
  float* gv             = (float*)(ws + (1248u << 10));
  float* bv             = (float*)(ws + (1252u << 10));
  float* ga             = (float*)(ws + (1256u << 10));
  float* ba             = (float*)(ws + (1260u << 10));
  float* o_part         = (float*)(ws + (1776u << 10));
  float* stat_part      = (float*)(ws + (4096u << 10));
  unsigned short* pos   = (unsigned short*)(ws + (8ull << 20));
  unsigned short* yb    = (unsigned short*)(ws + (72ull << 20));

  prep1_kernel<<<dim3(134), dim3(256), 0, stream>>>(wave1, wave2, wave3, ksum,
                                                    cls, Wq, qws, Wp1, Wp1T, Wkv, ln1g, GvT);
  prep2_kernel<<<dim3(98), dim3(256), 0, stream>>>(Wkv, qws, ln1g, ln1b, AqT, gv, bv, ga, ba);
  conv_kernel<<<dim3(4096), dim3(256), 0, stream>>>(x, ksum, pos);
  gemm1_kernel<<<dim3(2048), dim3(512), 0, stream>>>(pos, Wp1T, x, bp1, yb, stat_part);
  stage2_kernel<<<dim3(2048), dim3(512), 0, stream>>>(yb, GvT, AqT, stat_part,
                                                      gv, bv, ga, ba, attn, o_part);
  head_kernel<<<dim3(64), dim3(256), 0, stream>>>(o_part, Wproj, bproj, ln2g, ln2b,
                                                  Wc1, bc1, Wc2, bc2, logits);
}

// Round 10
// 273.353 us; speedup vs baseline: 1.7127x; 1.0128x over previous
//
#include <hip/hip_runtime.h>

#define SEQ 2048
#define DIM 512
#define NBATCH 32
#define NH 16
#define HDIM 32
#define NCLS 2

typedef __attribute__((ext_vector_type(8))) short short8;
typedef __attribute__((ext_vector_type(8))) unsigned short ushort8;
typedef __attribute__((ext_vector_type(4))) float f32x4;

__device__ __forceinline__ float b2f(unsigned short u){
  union { unsigned int i; float f; } v; v.i = ((unsigned int)u) << 16; return v.f;
}
__device__ __forceinline__ unsigned short f2b(float f){
  unsigned int x = __float_as_uint(f);
  unsigned int r = (x + 0x7fffu + ((x >> 16) & 1u)) >> 16;
  return (unsigned short)r;
}
__device__ __forceinline__ void gload16(const void* g, void* l){
  __builtin_amdgcn_global_load_lds((const __attribute__((address_space(1))) void*)g,
                                   (__attribute__((address_space(3))) void*)l, 16, 0, 0);
}

// ---------------- prep1: wavelet ksum | q = cls@Wq | Wp1T | GvT ----------------
__global__ __launch_bounds__(256) void prep1_kernel(
    const float* __restrict__ w1, const float* __restrict__ w2, const float* __restrict__ w3,
    float* __restrict__ ksum,
    const float* __restrict__ cls, const float* __restrict__ Wq, float* __restrict__ qws,
    const float* __restrict__ Wp1, unsigned short* __restrict__ Wp1T,
    const float* __restrict__ Wkv, const float* __restrict__ g1, unsigned short* __restrict__ GvT){
  __shared__ unsigned short t[64][65];
  int bid = blockIdx.x;
  int tid = threadIdx.x;
  if (bid < 2){
    int d = bid * 256 + tid;
    const float C = 0.86732501f;
    float acc[19];
    #pragma unroll
    for (int i = 0; i < 19; ++i) acc[i] = 0.f;
    const float* waves[3] = { w1, w2, w3 };
    for (int tt = 0; tt < 3; ++tt){
      float scale = waves[tt][d];
      float shift = waves[tt][DIM + d];
      float inv = 1.f / scale;
      float amp = C * rsqrtf(fabsf(scale));
      #pragma unroll
      for (int i = 0; i < 19; ++i){
        float u = ((float)(i - 9) - shift) * inv;
        acc[i] += amp * (1.f - u * u) * expf(-0.5f * u * u);
      }
    }
    #pragma unroll
    for (int i = 0; i < 19; ++i) ksum[i * DIM + d] = acc[i];
  } else if (bid < 6){
    int idx = (bid - 2) * 256 + tid;
    int n = idx >> 9, c = idx & 511;
    float s = 0.f;
    for (int kd = 0; kd < DIM; ++kd)
      s = fmaf(cls[n * DIM + kd], Wq[(size_t)kd * DIM + c], s);
    qws[n * DIM + c] = s;
  } else if (bid < 70){
    int bx = bid - 6;
    int c0 = (bx & 7) * 64, r0 = (bx >> 3) * 64;
    #pragma unroll
    for (int i = 0; i < 16; ++i){
      int idx = i * 256 + tid;
      int r = idx >> 6, c = idx & 63;
      t[c][r] = f2b(Wp1[(size_t)(r0 + r) * 512 + c0 + c]);
    }
    __syncthreads();
    #pragma unroll
    for (int i = 0; i < 16; ++i){
      int idx = i * 256 + tid;
      int r = idx >> 6, c = idx & 63;
      Wp1T[(size_t)(c0 + r) * 512 + r0 + c] = t[r][c];
    }
  } else {
    int bx = bid - 70;
    int c0 = (bx & 7) * 64, r0 = (bx >> 3) * 64;
    #pragma unroll
    for (int i = 0; i < 16; ++i){
      int idx = i * 256 + tid;
      int r = idx >> 6, c = idx & 63;
      t[c][r] = f2b(Wkv[(size_t)(r0 + r) * 1024 + 512 + c0 + c] * g1[r0 + r]);
    }
    __syncthreads();
    #pragma unroll
    for (int i = 0; i < 16; ++i){
      int idx = i * 256 + tid;
      int r = idx >> 6, c = idx & 63;
      GvT[(size_t)(c0 + r) * 512 + r0 + c] = t[r][c];
    }
  }
}

// ---------------- prep2: AqT direct | ga/ba | gv/bv ----------------
__global__ __launch_bounds__(256) void prep2_kernel(const float* __restrict__ Wkv,
    const float* __restrict__ qws, const float* __restrict__ g1, const float* __restrict__ b1,
    unsigned short* __restrict__ AqT, float* __restrict__ gv, float* __restrict__ bv,
    float* __restrict__ ga, float* __restrict__ ba){
  const float SCALE = 0.17677669529663687f;
  const float LOGS  = 7.6246189861593985f;
  int bid = blockIdx.x;
  int tid = threadIdx.x;
  if (bid < 64){
    int idx = bid * 256 + tid;           // 16384
    int hn = idx >> 9, d = idx & 511;
    int h = hn >> 1, n = hn & 1;
    float s = 0.f;
    #pragma unroll
    for (int hd = 0; hd < 32; ++hd)
      s = fmaf(Wkv[(size_t)d * 1024 + h * 32 + hd], qws[n * 512 + h * 32 + hd], s);
    AqT[hn * 512 + d] = f2b(SCALE * g1[d] * s);
  } else if (bid < 96){
    __shared__ float red[64];
    int hn = bid - 64;
    int h = hn >> 1, n = hn & 1;
    float s1 = 0.f, s2 = 0.f;
    #pragma unroll
    for (int dd = 0; dd < 2; ++dd){
      int d = tid + dd * 256;
      float inner = 0.f;
      #pragma unroll
      for (int hd = 0; hd < 32; ++hd)
        inner = fmaf(Wkv[(size_t)d * 1024 + h * 32 + hd], qws[n * 512 + h * 32 + hd], inner);
      s1 = fmaf(g1[d], inner, s1);
      s2 = fmaf(b1[d], inner, s2);
    }
    #pragma unroll
    for (int off = 32; off; off >>= 1){
      s1 += __shfl_xor(s1, off, 64);
      s2 += __shfl_xor(s2, off, 64);
    }
    int w = tid >> 6, lane = tid & 63;
    if (lane == 0){ red[w * 2] = s1; red[w * 2 + 1] = s2; }
    __syncthreads();
    if (tid == 0){
      float t1 = red[0] + red[2] + red[4] + red[6];
      float t2 = red[1] + red[3] + red[5] + red[7];
      ga[hn] = SCALE * t1;
      ba[hn] = SCALE * t2 - LOGS;
    }
  } else {
    int c = (bid - 96) * 256 + tid;      // 0..511
    float s1 = 0.f, s2 = 0.f;
    for (int d = 0; d < 512; ++d){
      float wv = Wkv[(size_t)d * 1024 + 512 + c];
      s1 = fmaf(g1[d], wv, s1);
      s2 = fmaf(b1[d], wv, s2);
    }
    gv[c] = s1; bv[c] = s2;
  }
}

// ---------------- conv: LDS-staged FIR, 512 threads, 1 ch/thread ----------------
__global__ __launch_bounds__(512) void conv_kernel(const float* __restrict__ X,
    const float* __restrict__ ksum, unsigned short* __restrict__ Pos){
  __shared__ float xs[34 * 512];            // 68 KB: rows s0-9 .. s0+24
  int id = blockIdx.x;                      // 4096
  int id2 = (id & 7) * 512 + (id >> 3);     // XCD-grouped: same-XCD blocks share halo
  int b = id2 >> 7;
  int strip = id2 & 127;
  int s0 = strip * 16;
  int tid = threadIdx.x;
  const float* xb = X + ((size_t)b * SEQ) * DIM;
  // async stage 34 rows x 512 ch f32 (4352 16B-granules)
  #pragma unroll
  for (int i = 0; i < 9; ++i){
    int g = i * 512 + tid;
    if (g < 4352){
      int row = g >> 7;
      int col4 = (g & 127) * 4;
      int s = s0 - 9 + row;
      int sc = s < 0 ? 0 : (s > SEQ - 1 ? SEQ - 1 : s);
      gload16(xb + (size_t)sc * DIM + col4, &xs[row * 512 + col4]);
    }
  }
  __syncthreads();                          // drains vmcnt
  if (strip == 0){
    #pragma unroll
    for (int i = 0; i < 9; ++i) xs[i * 512 + tid] = 0.f;
    __syncthreads();
  } else if (strip == 127){
    #pragma unroll
    for (int i = 25; i < 34; ++i) xs[i * 512 + tid] = 0.f;
    __syncthreads();
  }
  int d = tid;
  float kx[19];
  #pragma unroll
  for (int t = 0; t < 19; ++t) kx[t] = ksum[t * DIM + d];
  float ox[16];
  #pragma unroll
  for (int o = 0; o < 16; ++o) ox[o] = 0.f;
  #pragma unroll
  for (int w = 0; w < 34; ++w){
    float xv = xs[w * 512 + d];
    #pragma unroll
    for (int o = 0; o < 16; ++o){
      int t2 = w - o;
      if (t2 >= 0 && t2 < 19) ox[o] = fmaf(xv, kx[t2], ox[o]);
    }
  }
  #pragma unroll
  for (int o = 0; o < 16; ++o)
    Pos[((size_t)(b * SEQ + s0 + o)) * DIM + d] = f2b(ox[o]);
}

// ---------------- GEMM1: 128x128, 8 waves, low-reg; dbuf + counted vmcnt + swizzle -----
__global__ __launch_bounds__(512, 4) void gemm1_kernel(const unsigned short* __restrict__ A,
    const unsigned short* __restrict__ Bt, const float* __restrict__ Xres,
    const float* __restrict__ bias, unsigned short* __restrict__ Out,
    float* __restrict__ stat_part){
  __shared__ unsigned short lA[2 * 8192];    // 32 KB
  __shared__ unsigned short lB[2 * 8192];    // 32 KB
  __shared__ float sred[128][2][2];
  int tid = threadIdx.x;
  int w = tid >> 6, lane = tid & 63;
  int wm = w >> 1, wn = w & 1;               // wm 0..3 (32-row stripes), wn 0..1 (64-col)
  int q = lane >> 4, cl = lane & 15;
  int id = blockIdx.x;                        // 2048
  int xcd = id & 7;
  int nch = (id >> 3) & 3;
  int mb  = ((id >> 5) << 3) | xcd;           // 0..511
  size_t mBase = (size_t)mb * 128;
  int nBase = nch * 128;

  auto stage = [&](int buf, int k0){          // 4 gload_lds per thread (uniform)
    #pragma unroll
    for (int p = 0; p < 2; ++p){
      int G = p * 512 + tid;                  // linear LDS granule
      int row = G >> 3;
      int c8 = (G & 7) ^ (row & 7);           // inverse-swizzled source
      gload16(A + (mBase + row) * 512 + k0 + c8 * 8, &lA[buf * 8192 + G * 8]);
      gload16(Bt + (size_t)(nBase + row) * 512 + k0 + c8 * 8, &lB[buf * 8192 + G * 8]);
    }
  };

  f32x4 acc[2][4] = {};
  stage(0, 0);
  __syncthreads();                            // prologue full drain (once)
  int cur = 0;
  #pragma unroll
  for (int t = 0; t < 8; ++t){
    if (t < 7){
      stage(cur ^ 1, (t + 1) * 64);
      asm volatile("s_waitcnt vmcnt(4)" ::: "memory");
    } else {
      asm volatile("s_waitcnt vmcnt(0)" ::: "memory");
    }
    __builtin_amdgcn_s_barrier();
    const unsigned short* cA = &lA[cur * 8192];
    const unsigned short* cB = &lB[cur * 8192];
    #pragma unroll
    for (int kk = 0; kk < 2; ++kk){
      short8 af[2], bfr[4];
      #pragma unroll
      for (int m = 0; m < 2; ++m){
        int row = wm * 32 + m * 16 + cl;
        af[m] = *(const short8*)&cA[row * 64 + (((kk * 4 + q) ^ (row & 7)) * 8)];
      }
      #pragma unroll
      for (int n = 0; n < 4; ++n){
        int row = wn * 64 + n * 16 + cl;
        bfr[n] = *(const short8*)&cB[row * 64 + (((kk * 4 + q) ^ (row & 7)) * 8)];
      }
      #pragma unroll
      for (int m = 0; m < 2; ++m){
        #pragma unroll
        for (int n = 0; n < 4; ++n)
          acc[m][n] = __builtin_amdgcn_mfma_f32_16x16x32_bf16(af[m], bfr[n], acc[m][n], 0, 0, 0);
      }
    }
    asm volatile("s_waitcnt lgkmcnt(0)" ::: "memory");
    __builtin_amdgcn_s_barrier();
    cur ^= 1;
  }
  #pragma unroll
  for (int m = 0; m < 2; ++m){
    #pragma unroll
    for (int j = 0; j < 4; ++j){
      int rl = wm * 32 + m * 16 + q * 4 + j;
      size_t row = mBase + rl;
      float sm = 0.f, sq = 0.f;
      #pragma unroll
      for (int n = 0; n < 4; ++n){
        int col = nBase + wn * 64 + n * 16 + cl;
        float v = acc[m][n][j] + Xres[row * DIM + col] + bias[col];
        Out[row * DIM + col] = f2b(v);
        sm += v; sq += v * v;
      }
      #pragma unroll
      for (int off = 1; off < 16; off <<= 1){
        sm += __shfl_xor(sm, off, 64);
        sq += __shfl_xor(sq, off, 64);
      }
      if (cl == 0){ sred[rl][wn][0] = sm; sred[rl][wn][1] = sq; }
    }
  }
  __syncthreads();
  if (tid < 128){
    float sm = sred[tid][0][0] + sred[tid][1][0];
    float sq = sred[tid][0][1] + sred[tid][1][1];
    stat_part[((mBase + tid) * 4 + nch) * 2 + 0] = sm;
    stat_part[((mBase + tid) * 4 + nch) * 2 + 1] = sq;
  }
}

// ---------------- stage2: 8 waves, low-reg; AqT in B-tile (dup-write padding) ----------
__global__ __launch_bounds__(512, 4) void stage2_kernel(
    const unsigned short* __restrict__ Y, const unsigned short* __restrict__ GvT,
    const unsigned short* __restrict__ AqT, const float* __restrict__ stat_part,
    const float* __restrict__ gv, const float* __restrict__ bv,
    const float* __restrict__ ga, const float* __restrict__ ba,
    float* __restrict__ aout, float* __restrict__ o_part){
  __shared__ __align__(16) char smem[74752];
  unsigned short* lA = (unsigned short*)smem;               // 2 x 16 KB
  unsigned short* lB = (unsigned short*)(smem + 32768);     // 2 x 20 KB (128 GvT + 32 AqT rows)
  float* stats = (float*)(smem + 73728);                    // 1 KB
  float* attn_lds = (float*)smem;                           // overlay (post-loop) 16896 B
  float* o_red = (float*)(smem + 16896);                    // overlay 2*4*128*4 = 4096 B
  int tid = threadIdx.x;
  int w = tid >> 6, lane = tid & 63;
  int wm = w >> 1, wn = w & 1;
  int q = lane >> 4, cl = lane & 15;
  int id = blockIdx.x;                        // 2048
  int xcd = id & 7;
  int nch = (id >> 3) & 3;
  int mb  = ((id >> 5) << 3) | xcd;
  size_t mBase = (size_t)mb * 128;
  int nBase = nch * 128;

  auto stage = [&](int buf, int k0){          // 5 gload_lds per thread (uniform)
    #pragma unroll
    for (int p = 0; p < 2; ++p){
      int G = p * 512 + tid;
      int row = G >> 3;
      int c8 = (G & 7) ^ (row & 7);
      gload16(Y + (mBase + row) * 512 + k0 + c8 * 8, &lA[buf * 8192 + G * 8]);
      gload16(GvT + (size_t)(nBase + row) * 512 + k0 + c8 * 8, &lB[buf * 10240 + G * 8]);
    }
    {
      // AqT rows 128..159; threads 256..511 duplicate threads 0..255 (same dest, same data)
      int g = tid & 255;
      int row = 128 + (g >> 3);
      int c8 = (g & 7) ^ (row & 7);
      gload16(AqT + (size_t)(row - 128) * 512 + k0 + c8 * 8, &lB[buf * 10240 + (1024 + g) * 8]);
    }
  };

  stage(0, 0);
  if (tid < 128){
    float sm = 0.f, sq = 0.f;
    #pragma unroll
    for (int i = 0; i < 4; ++i){
      sm += stat_part[((mBase + tid) * 4 + i) * 2 + 0];
      sq += stat_part[((mBase + tid) * 4 + i) * 2 + 1];
    }
    float mean = sm * (1.f / 512.f);
    float var = sq * (1.f / 512.f) - mean * mean;
    stats[tid * 2 + 0] = mean;
    stats[tid * 2 + 1] = rsqrtf(var + 1e-5f);
  }
  __syncthreads();                            // prologue full drain (once)

  int hn = wn * 16 + cl;
  f32x4 acc[2][4] = {};
  f32x4 accs[2] = {};
  int cur = 0;
  #pragma unroll
  for (int t = 0; t < 8; ++t){
    if (t < 7){
      stage(cur ^ 1, (t + 1) * 64);
      asm volatile("s_waitcnt vmcnt(5)" ::: "memory");
    } else {
      asm volatile("s_waitcnt vmcnt(0)" ::: "memory");
    }
    __builtin_amdgcn_s_barrier();
    const unsigned short* cA = &lA[cur * 8192];
    const unsigned short* cB = &lB[cur * 10240];
    #pragma unroll
    for (int kk = 0; kk < 2; ++kk){
      short8 af[2], bfr[4], bq;
      {
        int row = 128 + hn;
        bq = *(const short8*)&cB[row * 64 + (((kk * 4 + q) ^ (row & 7)) * 8)];
      }
      #pragma unroll
      for (int m = 0; m < 2; ++m){
        int row = wm * 32 + m * 16 + cl;
        af[m] = *(const short8*)&cA[row * 64 + (((kk * 4 + q) ^ (row & 7)) * 8)];
      }
      #pragma unroll
      for (int n = 0; n < 4; ++n){
        int row = wn * 64 + n * 16 + cl;
        bfr[n] = *(const short8*)&cB[row * 64 + (((kk * 4 + q) ^ (row & 7)) * 8)];
      }
      #pragma unroll
      for (int m = 0; m < 2; ++m){
        #pragma unroll
        for (int n = 0; n < 4; ++n)
          acc[m][n] = __builtin_amdgcn_mfma_f32_16x16x32_bf16(af[m], bfr[n], acc[m][n], 0, 0, 0);
        accs[m] = __builtin_amdgcn_mfma_f32_16x16x32_bf16(af[m], bq, accs[m], 0, 0, 0);
      }
    }
    asm volatile("s_waitcnt lgkmcnt(0)" ::: "memory");
    __builtin_amdgcn_s_barrier();
    cur ^= 1;
  }
  // epilogue
  float gav = ga[hn], bav = ba[hn];
  float gv4[4], bv4[4];
  #pragma unroll
  for (int n = 0; n < 4; ++n){
    int cg = nBase + wn * 64 + n * 16 + cl;
    gv4[n] = gv[cg]; bv4[n] = bv[cg];
  }
  int b = mb >> 4;
  int scb = (mb & 15) * 128;
  #pragma unroll
  for (int m = 0; m < 2; ++m){
    #pragma unroll
    for (int j = 0; j < 4; ++j){
      int rl = wm * 32 + m * 16 + q * 4 + j;
      float mu = stats[rl * 2 + 0], s = stats[rl * 2 + 1];
      float sc = s * accs[m][j] - s * mu * gav + bav;
      float at = 1.f / (1.f + expf(-sc));
      attn_lds[rl * 33 + hn] = at;
      if (nch == 0)
        aout[((size_t)(b * NH + (hn >> 1)) * NCLS + (hn & 1)) * SEQ + scb + rl] = at;
      #pragma unroll
      for (int n = 0; n < 4; ++n)
        acc[m][n][j] = s * acc[m][n][j] - s * mu * gv4[n] + bv4[n];
    }
  }
  __syncthreads();
  float o0[4] = {}, o1[4] = {};
  #pragma unroll
  for (int n = 0; n < 4; ++n){
    int cg = nBase + wn * 64 + n * 16 + cl;
    int h2 = ((cg >> 5) << 1);
    #pragma unroll
    for (int m = 0; m < 2; ++m){
      #pragma unroll
      for (int j = 0; j < 4; ++j){
        int rl = wm * 32 + m * 16 + q * 4 + j;
        float vv = acc[m][n][j];
        o0[n] = fmaf(attn_lds[rl * 33 + h2 + 0], vv, o0[n]);
        o1[n] = fmaf(attn_lds[rl * 33 + h2 + 1], vv, o1[n]);
      }
    }
  }
  #pragma unroll
  for (int n = 0; n < 4; ++n){
    o0[n] += __shfl_xor(o0[n], 16, 64);
    o0[n] += __shfl_xor(o0[n], 32, 64);
    o1[n] += __shfl_xor(o1[n], 16, 64);
    o1[n] += __shfl_xor(o1[n], 32, 64);
  }
  if (q == 0){
    #pragma unroll
    for (int n = 0; n < 4; ++n){
      int c = wn * 64 + n * 16 + cl;
      o_red[(0 * 4 + wm) * 128 + c] = o0[n];
      o_red[(1 * 4 + wm) * 128 + c] = o1[n];
    }
  }
  __syncthreads();
  if (tid < 256){
    int nn = tid >> 7, c = tid & 127;
    float v = o_red[(nn * 4 + 0) * 128 + c] + o_red[(nn * 4 + 1) * 128 + c]
            + o_red[(nn * 4 + 2) * 128 + c] + o_red[(nn * 4 + 3) * 128 + c];
    o_part[((size_t)mb * 2 + nn) * 512 + nBase + c] = v;
  }
}

// ---------------- Head ----------------
__global__ __launch_bounds__(256) void head_kernel(const float* __restrict__ o_part,
    const float* __restrict__ Wproj, const float* __restrict__ bproj,
    const float* __restrict__ g2, const float* __restrict__ b2v,
    const float* __restrict__ Wc1, const float* __restrict__ bc1,
    const float* __restrict__ Wc2, const float* __restrict__ bc2,
    float* __restrict__ logits){
  __shared__ float orow[512];
  __shared__ float hrow[512];
  __shared__ float wred[8];
  __shared__ float wred2[4];
  int tid = threadIdx.x;
  int row = blockIdx.x;
  int b = row >> 1, nn = row & 1;
  for (int i = tid; i < 512; i += 256){
    float s = 0.f;
    const float* op = o_part + (((size_t)b * 16) * 2 + nn) * 512 + i;
    #pragma unroll
    for (int sc = 0; sc < 16; ++sc) s += op[(size_t)sc * 1024];
    orow[i] = s;
  }
  __syncthreads();
  int c0 = tid * 2;
  float a0 = 0.f, a1 = 0.f;
  for (int dd = 0; dd < DIM; ++dd){
    float ov = orow[dd];
    const float* wr = Wproj + (size_t)dd * DIM + c0;
    a0 = fmaf(ov, wr[0], a0);
    a1 = fmaf(ov, wr[1], a1);
  }
  a0 += bproj[c0]; a1 += bproj[c0 + 1];
  float sm = a0 + a1, sq = a0 * a0 + a1 * a1;
  #pragma unroll
  for (int off = 32; off; off >>= 1){
    sm += __shfl_xor(sm, off, 64);
    sq += __shfl_xor(sq, off, 64);
  }
  int w = tid >> 6, lane = tid & 63;
  if (lane == 0){ wred[w * 2] = sm; wred[w * 2 + 1] = sq; }
  __syncthreads();
  sm = wred[0] + wred[2] + wred[4] + wred[6];
  sq = wred[1] + wred[3] + wred[5] + wred[7];
  float mean = sm * (1.f / 512.f);
  float var = sq * (1.f / 512.f) - mean * mean;
  float rstd = rsqrtf(var + 1e-5f);
  hrow[c0]     = (a0 - mean) * rstd * g2[c0]     + b2v[c0];
  hrow[c0 + 1] = (a1 - mean) * rstd * g2[c0 + 1] + b2v[c0 + 1];
  __syncthreads();
  float h0 = 0.f, h1 = 0.f;
  for (int dd = 0; dd < DIM; ++dd){
    float lv = hrow[dd];
    const float* wr = Wc1 + (size_t)dd * DIM + c0;
    h0 = fmaf(lv, wr[0], h0);
    h1 = fmaf(lv, wr[1], h1);
  }
  h0 += bc1[c0]; h1 += bc1[c0 + 1];
  h0 = h0 > 0.f ? h0 : 0.f;
  h1 = h1 > 0.f ? h1 : 0.f;
  float p = h0 * Wc2[c0] + h1 * Wc2[c0 + 1];
  #pragma unroll
  for (int off = 32; off; off >>= 1) p += __shfl_xor(p, off, 64);
  if (lane == 0) wred2[w] = p;
  __syncthreads();
  if (tid == 0) logits[row] = wred2[0] + wred2[1] + wred2[2] + wred2[3] + bc2[0];
}

extern "C" void kernel_launch(void* const* d_in, const int* in_sizes, int n_in,
                              void* d_out, int out_size, void* d_ws, size_t ws_size,
                              hipStream_t stream) {
  const float* x     = (const float*)d_in[0];
  const float* wave1 = (const float*)d_in[1];
  const float* wave2 = (const float*)d_in[2];
  const float* wave3 = (const float*)d_in[3];
  const float* Wp1   = (const float*)d_in[4];
  const float* bp1   = (const float*)d_in[5];
  const float* cls   = (const float*)d_in[6];
  const float* ln1g  = (const float*)d_in[7];
  const float* ln1b  = (const float*)d_in[8];
  const float* Wq    = (const float*)d_in[9];
  const float* Wkv   = (const float*)d_in[10];
  const float* Wproj = (const float*)d_in[11];
  const float* bproj = (const float*)d_in[12];
  const float* ln2g  = (const float*)d_in[13];
  const float* ln2b  = (const float*)d_in[14];
  const float* Wc1   = (const float*)d_in[15];
  const float* bc1   = (const float*)d_in[16];
  const float* Wc2   = (const float*)d_in[17];
  const float* bc2   = (const float*)d_in[18];

  float* out = (float*)d_out;
  float* logits = out;
  float* attn   = out + 64;

  unsigned char* ws = (unsigned char*)d_ws;
  float* ksum           = (float*)(ws);
  float* qws            = (float*)(ws + (64u << 10));
  unsigned short* Wp1T  = (unsigned short*)(ws + (128u << 10));
  unsigned short* GvT   = (unsigned short*)(ws + (640u << 10));
  unsigned short* AqT   = (unsigned short*)(ws + (1152u << 10));
  float* gv             = (float*)(ws + (1248u << 10));
  float* bv             = (float*)(ws + (1252u << 10));
  float* ga             = (float*)(ws + (1256u << 10));
  float* ba             = (float*)(ws + (1260u << 10));
  float* o_part         = (float*)(ws + (1776u << 10));
  float* stat_part      = (float*)(ws + (4096u << 10));
  unsigned short* pos   = (unsigned short*)(ws + (8ull << 20));
  unsigned short* yb    = (unsigned short*)(ws + (72ull << 20));

  prep1_kernel<<<dim3(134), dim3(256), 0, stream>>>(wave1, wave2, wave3, ksum,
                                                    cls, Wq, qws, Wp1, Wp1T, Wkv, ln1g, GvT);
  prep2_kernel<<<dim3(98), dim3(256), 0, stream>>>(Wkv, qws, ln1g, ln1b, AqT, gv, bv, ga, ba);
  conv_kernel<<<dim3(4096), dim3(512), 0, stream>>>(x, ksum, pos);
  gemm1_kernel<<<dim3(2048), dim3(512), 0, stream>>>(pos, Wp1T, x, bp1, yb, stat_part);
  stage2_kernel<<<dim3(2048), dim3(512), 0, stream>>>(yb, GvT, AqT, stat_part,
                                                      gv, bv, ga, ba, attn, o_part);
  head_kernel<<<dim3(64), dim3(256), 0, stream>>>(o_part, Wproj, bproj, ln2g, ln2b,
                                                  Wc1, bc1, Wc2, bc2, logits);
}